// Round 1
// baseline (748.066 us; speedup 1.0000x reference)
//
#include <hip/hip_runtime.h>
#include <cstdint>
#include <cstddef>

// Problem constants
#define NB 2
#define TT 1024
#define MMEM 1024
#define SS 2048   // M + T
#define FF 1024
#define NHD 16    // heads
#define HD 64     // head dim

typedef __attribute__((ext_vector_type(8))) short bf16x8;
typedef __attribute__((ext_vector_type(4))) float f32x4;

__device__ __forceinline__ float bf2f(short s){
  unsigned u = ((unsigned)(unsigned short)s) << 16;
  float f; __builtin_memcpy(&f, &u, 4); return f;
}
__device__ __forceinline__ short f2bf(float f){
  unsigned u; __builtin_memcpy(&u, &f, 4);
  u += 0x7fffu + ((u >> 16) & 1u);   // RNE
  return (short)(u >> 16);
}

// ---------------- pack / cast kernels ----------------

__global__ void cast_kernel(const float* __restrict__ in, short* __restrict__ out, int n4){
  int i = blockIdx.x * blockDim.x + threadIdx.x;
  if (i >= n4) return;
  float4 v = ((const float4*)in)[i];
  short4 o; o.x = f2bf(v.x); o.y = f2bf(v.y); o.z = f2bf(v.z); o.w = f2bf(v.w);
  ((short4*)out)[i] = o;
}

// kv_in = concat(memory, x) along seq, cast to bf16. layout [B*SS, FF]
__global__ void build_kv(const float* __restrict__ mem, const float* __restrict__ x,
                         short* __restrict__ out){
  int i = blockIdx.x * blockDim.x + threadIdx.x;  // element/4 index
  int idx = i * 4;
  int row = idx >> 10;          // b*SS + s
  int col = idx & 1023;
  int b = row >> 11, s = row & 2047;
  const float* src = (s < MMEM) ? (mem + ((size_t)b*MMEM + s)*FF + col)
                                : (x   + ((size_t)b*TT + (s - MMEM))*FF + col);
  float4 v = *(const float4*)src;
  short4 o; o.x = f2bf(v.x); o.y = f2bf(v.y); o.z = f2bf(v.z); o.w = f2bf(v.w);
  ((short4*)out)[i] = o;
}

// out[c][r] = in[r][c], 1024x1024, f32 -> bf16
__global__ void transpose_cast(const float* __restrict__ in, short* __restrict__ out){
  __shared__ float tile[32][33];
  int bx = blockIdx.x * 32, by = blockIdx.y * 32;
  int tx = threadIdx.x, ty = threadIdx.y;
  for (int j = ty; j < 32; j += 8)
    tile[j][tx] = in[(size_t)(by + j)*1024 + bx + tx];
  __syncthreads();
  for (int j = ty; j < 32; j += 8)
    out[(size_t)(bx + j)*1024 + by + tx] = f2bf(tile[tx][j]);
}

// ki[b, 0:M] = episode_idx[b,:]; ki[b, M+t] = episode_idx[b,M-1] + cumsum(dones)[t]
__global__ void scan_kernel(const int* __restrict__ episode_idx, const int* __restrict__ dones,
                            int* __restrict__ ki){
  __shared__ int buf[TT];
  int b = blockIdx.x, t = threadIdx.x;
  buf[t] = dones[b*TT + t];
  __syncthreads();
  for (int off = 1; off < TT; off <<= 1){
    int v = (t >= off) ? buf[t - off] : 0;
    __syncthreads();
    buf[t] += v;
    __syncthreads();
  }
  int base = episode_idx[b*MMEM + (MMEM - 1)];
  ki[b*SS + t] = episode_idx[b*MMEM + t];
  ki[b*SS + MMEM + t] = base + buf[t];
}

// ---------------- GEMM: C[i,j] = sum_k A[i,k] * BT[j,k]  (bf16 in, f32 acc) ------
// MODE 0: bf16 out C0.   MODE 1: C0 = acc+add0[j], C1 = acc+add1[j] (bf16).
// MODE 2: f32 out Cf = acc + add0[j].
// MODE 3: bf16 out transposed per-head: C0[((b*16+n)*64+h)*2048 + s], row=(b,s), col=(n,h)
template<int MODE>
__global__ __launch_bounds__(256) void gemm_nt(const short* __restrict__ A, const short* __restrict__ BT,
                        int K, short* __restrict__ C0, short* __restrict__ C1,
                        const float* __restrict__ add0, const float* __restrict__ add1,
                        float* __restrict__ Cf){
  const int row0 = blockIdx.x * 64, col0 = blockIdx.y * 64;
  const int wave = threadIdx.x >> 6, lane = threadIdx.x & 63;
  const int quad = lane >> 4, lcol = lane & 15;
  const int r0 = row0 + wave * 16;
  f32x4 acc[4];
  #pragma unroll
  for (int c = 0; c < 4; c++) acc[c] = (f32x4){0.f, 0.f, 0.f, 0.f};
  const short* ap = A  + (size_t)(r0 + lcol) * K + quad * 8;
  const short* bp = BT + (size_t)(col0 + lcol) * K + quad * 8;
  #pragma unroll 4
  for (int k0 = 0; k0 < K; k0 += 32){
    bf16x8 a = *(const bf16x8*)(ap + k0);
    #pragma unroll
    for (int c = 0; c < 4; c++){
      bf16x8 bb = *(const bf16x8*)(bp + (size_t)c * 16 * K + k0);
      acc[c] = __builtin_amdgcn_mfma_f32_16x16x32_bf16(a, bb, acc[c], 0, 0, 0);
    }
  }
  #pragma unroll
  for (int c = 0; c < 4; c++){
    int cc = col0 + c * 16 + lcol;
    #pragma unroll
    for (int r = 0; r < 4; r++){
      int rr = r0 + quad * 4 + r;
      float v = acc[c][r];
      if (MODE == 0){
        C0[(size_t)rr * 1024 + cc] = f2bf(v);
      } else if (MODE == 1){
        C0[(size_t)rr * 1024 + cc] = f2bf(v + add0[cc]);
        C1[(size_t)rr * 1024 + cc] = f2bf(v + add1[cc]);
      } else if (MODE == 2){
        Cf[(size_t)rr * 1024 + cc] = v + add0[cc];
      } else { // MODE 3: transposed per-head V:  [(b*16+n)*64+h][s]
        int bb2 = rr >> 11, ss = rr & 2047;
        C0[(size_t)(((bb2 << 4) + (cc >> 6)) * 64 + (cc & 63)) * 2048 + ss] = f2bf(v);
      }
    }
  }
}

// BD[b,n,t,m] = sum_h qv[b,t,n,h] * r[m,n,h]   (K=64)
__global__ __launch_bounds__(256) void bd_gemm(const short* __restrict__ qv, const short* __restrict__ rbf,
                        short* __restrict__ BD){
  const int m0 = blockIdx.x * 64, t0 = blockIdx.y * 64;
  const int bn = blockIdx.z; const int b = bn >> 4, n = bn & 15;
  // band skip: needed m >= 1023 - t; min over tile = 960 - t0
  if (m0 + 63 < 960 - t0) return;
  const int wave = threadIdx.x >> 6, lane = threadIdx.x & 63;
  const int quad = lane >> 4, lcol = lane & 15;
  const int tw = t0 + wave * 16;
  const short* ap = qv + (size_t)(b * TT + tw + lcol) * 1024 + n * 64 + quad * 8;
  bf16x8 a0 = *(const bf16x8*)(ap);
  bf16x8 a1 = *(const bf16x8*)(ap + 32);
  #pragma unroll
  for (int c = 0; c < 4; c++){
    const short* bp = rbf + (size_t)(m0 + 16 * c + lcol) * 1024 + n * 64 + quad * 8;
    bf16x8 b0 = *(const bf16x8*)(bp);
    bf16x8 b1 = *(const bf16x8*)(bp + 32);
    f32x4 z = (f32x4){0.f, 0.f, 0.f, 0.f};
    z = __builtin_amdgcn_mfma_f32_16x16x32_bf16(a0, b0, z, 0, 0, 0);
    z = __builtin_amdgcn_mfma_f32_16x16x32_bf16(a1, b1, z, 0, 0, 0);
    #pragma unroll
    for (int r = 0; r < 4; r++)
      BD[((size_t)((b * NHD + n) * TT + tw + quad * 4 + r)) * SS + m0 + 16 * c + lcol] = f2bf(z[r]);
  }
}

// ---------------- flash attention ----------------
// grid: 512 = B * N * (T/64).  4 waves/block, each wave owns 16 query rows.
__global__ __launch_bounds__(256) void attn_kernel(const short* __restrict__ qu, const short* __restrict__ BD,
                            const short* __restrict__ kk, const short* __restrict__ vT,
                            const int* __restrict__ ki, short* __restrict__ attn_out){
  const int blk = blockIdx.x;
  const int tq0 = (blk & 15) * 64;
  const int n = (blk >> 4) & 15;
  const int b = blk >> 8;
  const int wave = threadIdx.x >> 6, lane = threadIdx.x & 63;
  const int quad = lane >> 4, lcol = lane & 15;
  const int tw = tq0 + wave * 16;

  const short* qp = qu + (size_t)(b * TT + tw + lcol) * 1024 + n * 64 + quad * 8;
  bf16x8 aq0 = *(const bf16x8*)(qp);
  bf16x8 aq1 = *(const bf16x8*)(qp + 32);

  int trow[4], qi_r[4];
  #pragma unroll
  for (int r = 0; r < 4; r++){
    trow[r] = tw + quad * 4 + r;
    qi_r[r] = ki[b * SS + MMEM + trow[r]];
  }

  float m_run[4], l_run[4];
  f32x4 o[4];
  #pragma unroll
  for (int r = 0; r < 4; r++){ m_run[r] = -1e30f; l_run[r] = 0.f; }
  #pragma unroll
  for (int c = 0; c < 4; c++) o[c] = (f32x4){0.f, 0.f, 0.f, 0.f};

  __shared__ __align__(16) short pbuf[4][16][72];  // P tile, padded rows (bank spread)
  const float scale = 0.125f;
  const size_t bd_base = (size_t)((b * NHD + n) * TT);
  const size_t vt_base = (size_t)((b * NHD + n) * HD);

  const int ntiles = (tq0 >> 6) + 17;   // covers s <= t + M for all rows in tile
  for (int kt = 0; kt < ntiles; kt++){
    const int s0 = kt * 64;
    // ---- S = Qu . K^T ----
    f32x4 sacc[4];
    #pragma unroll
    for (int c = 0; c < 4; c++){
      const short* kp = kk + (size_t)(b * SS + s0 + 16 * c + lcol) * 1024 + n * 64 + quad * 8;
      bf16x8 b0 = *(const bf16x8*)(kp);
      bf16x8 b1 = *(const bf16x8*)(kp + 32);
      f32x4 z = (f32x4){0.f, 0.f, 0.f, 0.f};
      z = __builtin_amdgcn_mfma_f32_16x16x32_bf16(aq0, b0, z, 0, 0, 0);
      z = __builtin_amdgcn_mfma_f32_16x16x32_bf16(aq1, b1, z, 0, 0, 0);
      sacc[c] = z;
    }
    int ki_c[4];
    #pragma unroll
    for (int c = 0; c < 4; c++) ki_c[c] = ki[b * SS + s0 + 16 * c + lcol];

    // ---- bias gather + mask + logits ----
    float p[4][4];
    float rowmax[4];
    #pragma unroll
    for (int r = 0; r < 4; r++) rowmax[r] = -1e30f;
    #pragma unroll
    for (int c = 0; c < 4; c++){
      const int s = s0 + 16 * c + lcol;
      #pragma unroll
      for (int r = 0; r < 4; r++){
        const int t = trow[r];
        int m = s - t + (TT - 1);          // >= 0 always
        m = (m > SS - 1) ? (SS - 1) : m;   // clamp; clamped entries are causally masked
        float bd = bf2f(BD[(bd_base + t) * SS + m]);
        float lg = (sacc[c][r] + bd) * scale;
        const bool valid = (s <= t + MMEM) && (ki_c[c] == qi_r[r]);
        lg = valid ? lg : -1e30f;
        p[c][r] = lg;
        rowmax[r] = fmaxf(rowmax[r], lg);
      }
    }
    // ---- online softmax ----
    #pragma unroll
    for (int r = 0; r < 4; r++){
      float vmx = rowmax[r];
      #pragma unroll
      for (int off = 1; off < 16; off <<= 1) vmx = fmaxf(vmx, __shfl_xor(vmx, off, 64));
      float mnew = fmaxf(m_run[r], vmx);
      float alpha = __expf(m_run[r] - mnew);
      m_run[r] = mnew;
      l_run[r] *= alpha;
      #pragma unroll
      for (int c = 0; c < 4; c++) o[c][r] *= alpha;
    }
    float psum[4] = {0.f, 0.f, 0.f, 0.f};
    #pragma unroll
    for (int c = 0; c < 4; c++)
      #pragma unroll
      for (int r = 0; r < 4; r++){
        float pv = __expf(p[c][r] - m_run[r]);
        p[c][r] = pv;
        psum[r] += pv;
      }
    #pragma unroll
    for (int r = 0; r < 4; r++){
      float vs = psum[r];
      #pragma unroll
      for (int off = 1; off < 16; off <<= 1) vs += __shfl_xor(vs, off, 64);
      l_run[r] += vs;
    }
    // ---- P: C-layout -> A-layout via per-wave LDS (wave-synchronous) ----
    #pragma unroll
    for (int c = 0; c < 4; c++)
      #pragma unroll
      for (int r = 0; r < 4; r++)
        pbuf[wave][quad * 4 + r][16 * c + lcol] = f2bf(p[c][r]);
    bf16x8 pa0 = *(const bf16x8*)(&pbuf[wave][lcol][quad * 8]);
    bf16x8 pa1 = *(const bf16x8*)(&pbuf[wave][lcol][32 + quad * 8]);
    // ---- O += P . V  (V pre-transposed per head: dot-of-rows pattern) ----
    #pragma unroll
    for (int c = 0; c < 4; c++){
      const short* vtp = vT + (vt_base + c * 16 + lcol) * (size_t)SS + s0 + quad * 8;
      bf16x8 bv0 = *(const bf16x8*)(vtp);
      bf16x8 bv1 = *(const bf16x8*)(vtp + 32);
      o[c] = __builtin_amdgcn_mfma_f32_16x16x32_bf16(pa0, bv0, o[c], 0, 0, 0);
      o[c] = __builtin_amdgcn_mfma_f32_16x16x32_bf16(pa1, bv1, o[c], 0, 0, 0);
    }
  }
  // ---- epilogue: normalize, store bf16 attn [B*T, N*H] ----
  #pragma unroll
  for (int r = 0; r < 4; r++){
    const float inv = 1.f / l_run[r];
    const int t = trow[r];
    #pragma unroll
    for (int c = 0; c < 4; c++)
      attn_out[(size_t)(b * TT + t) * 1024 + n * 64 + c * 16 + lcol] = f2bf(o[c][r] * inv);
  }
}

// ---------------- launcher ----------------
extern "C" void kernel_launch(void* const* d_in, const int* in_sizes, int n_in,
                              void* d_out, int out_size, void* d_ws, size_t ws_size,
                              hipStream_t stream){
  const float* x      = (const float*)d_in[0];
  const float* rel    = (const float*)d_in[1];
  const float* memory = (const float*)d_in[2];
  const int*   episode_idx = (const int*)d_in[3];
  const int*   dones  = (const int*)d_in[4];
  const float* Wq  = (const float*)d_in[5];
  const float* Wk  = (const float*)d_in[6];
  const float* Wv  = (const float*)d_in[7];
  const float* Wr  = (const float*)d_in[8];
  const float* u   = (const float*)d_in[9];
  const float* v   = (const float*)d_in[10];
  const float* Wout  = (const float*)d_in[11];
  const float* b_out = (const float*)d_in[12];
  float* out = (float*)d_out;

  char* ws = (char*)d_ws;
  size_t off = 0;
  auto alloc = [&](size_t bytes) -> char* {
    char* p = ws + off;
    off += (bytes + 255) & ~(size_t)255;
    return p;
  };
  short* x_bf   = (short*)alloc((size_t)NB * TT * FF * 2);
  short* kv_bf  = (short*)alloc((size_t)NB * SS * FF * 2);
  short* rel_bf = (short*)alloc((size_t)SS * FF * 2);
  short* WqT    = (short*)alloc((size_t)FF * 1024 * 2);
  short* WkT    = (short*)alloc((size_t)FF * 1024 * 2);
  short* WvT    = (short*)alloc((size_t)FF * 1024 * 2);
  short* WrT    = (short*)alloc((size_t)FF * 1024 * 2);
  short* WoT    = (short*)alloc((size_t)FF * 1024 * 2);
  short* qu     = (short*)alloc((size_t)NB * TT * 1024 * 2);
  short* qv     = (short*)alloc((size_t)NB * TT * 1024 * 2);
  short* kbf    = (short*)alloc((size_t)NB * SS * 1024 * 2);
  short* vTb    = (short*)alloc((size_t)NB * SS * 1024 * 2);
  short* rbf    = (short*)alloc((size_t)SS * 1024 * 2);
  short* BD     = (short*)alloc((size_t)NB * NHD * TT * SS * 2);   // 128 MB
  int*   ki     = (int*)  alloc((size_t)NB * SS * 4);
  short* attn   = (short*)alloc((size_t)NB * TT * 1024 * 2);
  (void)ws_size; (void)in_sizes; (void)n_in; (void)out_size;

  // pack
  cast_kernel<<<(NB*TT*FF/4 + 255)/256, 256, 0, stream>>>(x, x_bf, NB*TT*FF/4);
  cast_kernel<<<(SS*FF/4 + 255)/256, 256, 0, stream>>>(rel, rel_bf, SS*FF/4);
  build_kv<<<(NB*SS*FF/4)/256, 256, 0, stream>>>(memory, x, kv_bf);
  dim3 tb(32, 8), tg(32, 32);
  transpose_cast<<<tg, tb, 0, stream>>>(Wq, WqT);
  transpose_cast<<<tg, tb, 0, stream>>>(Wk, WkT);
  transpose_cast<<<tg, tb, 0, stream>>>(Wv, WvT);
  transpose_cast<<<tg, tb, 0, stream>>>(Wr, WrT);
  transpose_cast<<<tg, tb, 0, stream>>>(Wout, WoT);
  scan_kernel<<<NB, TT, 0, stream>>>(episode_idx, dones, ki);

  // projections
  gemm_nt<1><<<dim3(32, 16), 256, 0, stream>>>(x_bf, WqT, FF, qu, qv, u, v, nullptr);
  gemm_nt<0><<<dim3(64, 16), 256, 0, stream>>>(kv_bf, WkT, FF, kbf, nullptr, nullptr, nullptr, nullptr);
  gemm_nt<3><<<dim3(64, 16), 256, 0, stream>>>(kv_bf, WvT, FF, vTb, nullptr, nullptr, nullptr, nullptr);
  gemm_nt<0><<<dim3(32, 16), 256, 0, stream>>>(rel_bf, WrT, FF, rbf, nullptr, nullptr, nullptr, nullptr);

  // relative-position bias table
  bd_gemm<<<dim3(32, 16, 32), 256, 0, stream>>>(qv, rbf, BD);

  // attention
  attn_kernel<<<512, 256, 0, stream>>>(qu, BD, kbf, vTb, ki, attn);

  // output projection
  gemm_nt<2><<<dim3(32, 16), 256, 0, stream>>>(attn, WoT, 1024, nullptr, nullptr, b_out, nullptr, out);
}

// Round 2
// 703.378 us; speedup vs baseline: 1.0635x; 1.0635x over previous
//
#include <hip/hip_runtime.h>
#include <cstdint>
#include <cstddef>

// Problem constants
#define NB 2
#define TT 1024
#define MMEM 1024
#define SS 2048   // M + T
#define FF 1024
#define NHD 16    // heads
#define HD 64     // head dim

typedef __attribute__((ext_vector_type(8))) short bf16x8;
typedef __attribute__((ext_vector_type(4))) float f32x4;

__device__ __forceinline__ float bf2f(short s){
  unsigned u = ((unsigned)(unsigned short)s) << 16;
  float f; __builtin_memcpy(&f, &u, 4); return f;
}
__device__ __forceinline__ short f2bf(float f){
  unsigned u; __builtin_memcpy(&u, &f, 4);
  u += 0x7fffu + ((u >> 16) & 1u);   // RNE
  return (short)(u >> 16);
}

// ---------------- pack / cast kernels ----------------

__global__ void cast_kernel(const float* __restrict__ in, short* __restrict__ out, int n4){
  int i = blockIdx.x * blockDim.x + threadIdx.x;
  if (i >= n4) return;
  float4 v = ((const float4*)in)[i];
  short4 o; o.x = f2bf(v.x); o.y = f2bf(v.y); o.z = f2bf(v.z); o.w = f2bf(v.w);
  ((short4*)out)[i] = o;
}

// kv_in = concat(memory, x) along seq, cast to bf16. layout [B*SS, FF]
__global__ void build_kv(const float* __restrict__ mem, const float* __restrict__ x,
                         short* __restrict__ out){
  int i = blockIdx.x * blockDim.x + threadIdx.x;  // element/4 index
  int idx = i * 4;
  int row = idx >> 10;          // b*SS + s
  int col = idx & 1023;
  int b = row >> 11, s = row & 2047;
  const float* src = (s < MMEM) ? (mem + ((size_t)b*MMEM + s)*FF + col)
                                : (x   + ((size_t)b*TT + (s - MMEM))*FF + col);
  float4 v = *(const float4*)src;
  short4 o; o.x = f2bf(v.x); o.y = f2bf(v.y); o.z = f2bf(v.z); o.w = f2bf(v.w);
  ((short4*)out)[i] = o;
}

// out[c][r] = in[r][c], 1024x1024, f32 -> bf16
__global__ void transpose_cast(const float* __restrict__ in, short* __restrict__ out){
  __shared__ float tile[32][33];
  int bx = blockIdx.x * 32, by = blockIdx.y * 32;
  int tx = threadIdx.x, ty = threadIdx.y;
  for (int j = ty; j < 32; j += 8)
    tile[j][tx] = in[(size_t)(by + j)*1024 + bx + tx];
  __syncthreads();
  for (int j = ty; j < 32; j += 8)
    out[(size_t)(bx + j)*1024 + by + tx] = f2bf(tile[tx][j]);
}

// ki[b, 0:M] = episode_idx[b,:]; ki[b, M+t] = episode_idx[b,M-1] + cumsum(dones)[t]
__global__ void scan_kernel(const int* __restrict__ episode_idx, const int* __restrict__ dones,
                            int* __restrict__ ki){
  __shared__ int buf[TT];
  int b = blockIdx.x, t = threadIdx.x;
  buf[t] = dones[b*TT + t];
  __syncthreads();
  for (int off = 1; off < TT; off <<= 1){
    int v = (t >= off) ? buf[t - off] : 0;
    __syncthreads();
    buf[t] += v;
    __syncthreads();
  }
  int base = episode_idx[b*MMEM + (MMEM - 1)];
  ki[b*SS + t] = episode_idx[b*MMEM + t];
  ki[b*SS + MMEM + t] = base + buf[t];
}

// ---------------- GEMM: C[i,j] = sum_k A[i,k] * BT[j,k]  (bf16 in, f32 acc) ------
// MODE 0: bf16 out C0.   MODE 1: C0 = acc+add0[j], C1 = acc+add1[j] (bf16).
// MODE 2: f32 out Cf = acc + add0[j].
// MODE 3: bf16 out transposed per-head: C0[((b*16+n)*64+h)*2048 + s], row=(b,s), col=(n,h)
template<int MODE>
__global__ __launch_bounds__(256) void gemm_nt(const short* __restrict__ A, const short* __restrict__ BT,
                        int K, short* __restrict__ C0, short* __restrict__ C1,
                        const float* __restrict__ add0, const float* __restrict__ add1,
                        float* __restrict__ Cf){
  const int row0 = blockIdx.x * 64, col0 = blockIdx.y * 64;
  const int wave = threadIdx.x >> 6, lane = threadIdx.x & 63;
  const int quad = lane >> 4, lcol = lane & 15;
  const int r0 = row0 + wave * 16;
  f32x4 acc[4];
  #pragma unroll
  for (int c = 0; c < 4; c++) acc[c] = (f32x4){0.f, 0.f, 0.f, 0.f};
  const short* ap = A  + (size_t)(r0 + lcol) * K + quad * 8;
  const short* bp = BT + (size_t)(col0 + lcol) * K + quad * 8;
  #pragma unroll 4
  for (int k0 = 0; k0 < K; k0 += 32){
    bf16x8 a = *(const bf16x8*)(ap + k0);
    #pragma unroll
    for (int c = 0; c < 4; c++){
      bf16x8 bb = *(const bf16x8*)(bp + (size_t)c * 16 * K + k0);
      acc[c] = __builtin_amdgcn_mfma_f32_16x16x32_bf16(a, bb, acc[c], 0, 0, 0);
    }
  }
  #pragma unroll
  for (int c = 0; c < 4; c++){
    int cc = col0 + c * 16 + lcol;
    #pragma unroll
    for (int r = 0; r < 4; r++){
      int rr = r0 + quad * 4 + r;
      float v = acc[c][r];
      if (MODE == 0){
        C0[(size_t)rr * 1024 + cc] = f2bf(v);
      } else if (MODE == 1){
        C0[(size_t)rr * 1024 + cc] = f2bf(v + add0[cc]);
        C1[(size_t)rr * 1024 + cc] = f2bf(v + add1[cc]);
      } else if (MODE == 2){
        Cf[(size_t)rr * 1024 + cc] = v + add0[cc];
      } else { // MODE 3: transposed per-head V:  [(b*16+n)*64+h][s]
        int bb2 = rr >> 11, ss = rr & 2047;
        C0[(size_t)(((bb2 << 4) + (cc >> 6)) * 64 + (cc & 63)) * 2048 + ss] = f2bf(v);
      }
    }
  }
}

// BD[b,n,t,m] = sum_h qv[b,t,n,h] * r[m,n,h]   (K=64)
__global__ __launch_bounds__(256) void bd_gemm(const short* __restrict__ qv, const short* __restrict__ rbf,
                        short* __restrict__ BD){
  const int m0 = blockIdx.x * 64, t0 = blockIdx.y * 64;
  const int bn = blockIdx.z; const int b = bn >> 4, n = bn & 15;
  // band skip: needed m >= 1023 - t; min over tile = 960 - t0
  if (m0 + 63 < 960 - t0) return;
  const int wave = threadIdx.x >> 6, lane = threadIdx.x & 63;
  const int quad = lane >> 4, lcol = lane & 15;
  const int tw = t0 + wave * 16;
  const short* ap = qv + (size_t)(b * TT + tw + lcol) * 1024 + n * 64 + quad * 8;
  bf16x8 a0 = *(const bf16x8*)(ap);
  bf16x8 a1 = *(const bf16x8*)(ap + 32);
  #pragma unroll
  for (int c = 0; c < 4; c++){
    const short* bp = rbf + (size_t)(m0 + 16 * c + lcol) * 1024 + n * 64 + quad * 8;
    bf16x8 b0 = *(const bf16x8*)(bp);
    bf16x8 b1 = *(const bf16x8*)(bp + 32);
    f32x4 z = (f32x4){0.f, 0.f, 0.f, 0.f};
    z = __builtin_amdgcn_mfma_f32_16x16x32_bf16(a0, b0, z, 0, 0, 0);
    z = __builtin_amdgcn_mfma_f32_16x16x32_bf16(a1, b1, z, 0, 0, 0);
    #pragma unroll
    for (int r = 0; r < 4; r++)
      BD[((size_t)((b * NHD + n) * TT + tw + quad * 4 + r)) * SS + m0 + 16 * c + lcol] = f2bf(z[r]);
  }
}

// ---------------- flash attention, split-K across waves ----------------
// grid: 2048 = B * N * (T/16). Block = 4 waves; all waves share the same 16
// query rows; wave w processes k-tiles w, w+4, w+8, ... with private online
// softmax state; states merge through LDS at the end (softmax-merge).
__global__ __launch_bounds__(256, 8) void attn_kernel(const short* __restrict__ qu, const short* __restrict__ BD,
                            const short* __restrict__ kk, const short* __restrict__ vT,
                            const int* __restrict__ ki, short* __restrict__ attn_out){
  const int blk = blockIdx.x;
  const int t16 = (blk & 63) * 16;
  const int n = (blk >> 6) & 15;
  const int b = blk >> 10;
  const int wave = threadIdx.x >> 6, lane = threadIdx.x & 63;
  const int quad = lane >> 4, lcol = lane & 15;

  // union LDS: phase 1 = per-wave P tiles (4*16*72*2 = 9216 B)
  //            phase 2 = partial O (4*16*68*4 = 17408 B) + m,l (512 B)
  __shared__ __align__(16) char smem[17920];
  short* pb = (short*)smem + wave * (16 * 72);

  const short* qp = qu + (size_t)(b * TT + t16 + lcol) * 1024 + n * 64 + quad * 8;
  bf16x8 aq0 = *(const bf16x8*)(qp);
  bf16x8 aq1 = *(const bf16x8*)(qp + 32);

  int trow[4], qi_r[4];
  #pragma unroll
  for (int r = 0; r < 4; r++){
    trow[r] = t16 + quad * 4 + r;
    qi_r[r] = ki[b * SS + MMEM + trow[r]];
  }

  float m_run[4], l_run[4];
  f32x4 o[4];
  #pragma unroll
  for (int r = 0; r < 4; r++){ m_run[r] = -1e30f; l_run[r] = 0.f; }
  #pragma unroll
  for (int c = 0; c < 4; c++) o[c] = (f32x4){0.f, 0.f, 0.f, 0.f};

  const float scale = 0.125f;
  const size_t bd_base = (size_t)((b * NHD + n) * TT);
  const size_t vt_base = (size_t)((b * NHD + n) * HD);

  const int ntiles = ((t16 + 1039) >> 6) + 1;   // covers s <= t + M for all 16 rows
  for (int kt = wave; kt < ntiles; kt += 4){
    const int s0 = kt * 64;
    // ---- S = Qu . K^T ----
    f32x4 sacc[4];
    #pragma unroll
    for (int c = 0; c < 4; c++){
      const short* kp = kk + (size_t)(b * SS + s0 + 16 * c + lcol) * 1024 + n * 64 + quad * 8;
      bf16x8 b0 = *(const bf16x8*)(kp);
      bf16x8 b1 = *(const bf16x8*)(kp + 32);
      f32x4 z = (f32x4){0.f, 0.f, 0.f, 0.f};
      z = __builtin_amdgcn_mfma_f32_16x16x32_bf16(aq0, b0, z, 0, 0, 0);
      z = __builtin_amdgcn_mfma_f32_16x16x32_bf16(aq1, b1, z, 0, 0, 0);
      sacc[c] = z;
    }
    int ki_c[4];
    #pragma unroll
    for (int c = 0; c < 4; c++) ki_c[c] = ki[b * SS + s0 + 16 * c + lcol];

    // ---- bias gather + mask + logits ----
    float p[4][4];
    float rowmax[4];
    #pragma unroll
    for (int r = 0; r < 4; r++) rowmax[r] = -1e30f;
    #pragma unroll
    for (int c = 0; c < 4; c++){
      const int s = s0 + 16 * c + lcol;
      #pragma unroll
      for (int r = 0; r < 4; r++){
        const int t = trow[r];
        int m = s - t + (TT - 1);          // >= 0 always
        m = (m > SS - 1) ? (SS - 1) : m;   // clamp; clamped entries are causally masked
        float bd = bf2f(BD[(bd_base + t) * SS + m]);
        float lg = (sacc[c][r] + bd) * scale;
        const bool valid = (s <= t + MMEM) && (ki_c[c] == qi_r[r]);
        lg = valid ? lg : -1e30f;
        p[c][r] = lg;
        rowmax[r] = fmaxf(rowmax[r], lg);
      }
    }
    // ---- online softmax (per-wave private state) ----
    #pragma unroll
    for (int r = 0; r < 4; r++){
      float vmx = rowmax[r];
      #pragma unroll
      for (int off = 1; off < 16; off <<= 1) vmx = fmaxf(vmx, __shfl_xor(vmx, off, 64));
      float mnew = fmaxf(m_run[r], vmx);
      float alpha = __expf(m_run[r] - mnew);
      m_run[r] = mnew;
      l_run[r] *= alpha;
      #pragma unroll
      for (int c = 0; c < 4; c++) o[c][r] *= alpha;
    }
    float psum[4] = {0.f, 0.f, 0.f, 0.f};
    #pragma unroll
    for (int c = 0; c < 4; c++)
      #pragma unroll
      for (int r = 0; r < 4; r++){
        float pv = __expf(p[c][r] - m_run[r]);
        p[c][r] = pv;
        psum[r] += pv;
      }
    #pragma unroll
    for (int r = 0; r < 4; r++){
      float vs = psum[r];
      #pragma unroll
      for (int off = 1; off < 16; off <<= 1) vs += __shfl_xor(vs, off, 64);
      l_run[r] += vs;
    }
    // ---- P: C-layout -> A-layout via per-wave LDS (wave-synchronous) ----
    #pragma unroll
    for (int c = 0; c < 4; c++)
      #pragma unroll
      for (int r = 0; r < 4; r++)
        pb[(quad * 4 + r) * 72 + 16 * c + lcol] = f2bf(p[c][r]);
    bf16x8 pa0 = *(const bf16x8*)(&pb[lcol * 72 + quad * 8]);
    bf16x8 pa1 = *(const bf16x8*)(&pb[lcol * 72 + 32 + quad * 8]);
    // ---- O += P . V  (V pre-transposed per head: dot-of-rows pattern) ----
    #pragma unroll
    for (int c = 0; c < 4; c++){
      const short* vtp = vT + (vt_base + c * 16 + lcol) * (size_t)SS + s0 + quad * 8;
      bf16x8 bv0 = *(const bf16x8*)(vtp);
      bf16x8 bv1 = *(const bf16x8*)(vtp + 32);
      o[c] = __builtin_amdgcn_mfma_f32_16x16x32_bf16(pa0, bv0, o[c], 0, 0, 0);
      o[c] = __builtin_amdgcn_mfma_f32_16x16x32_bf16(pa1, bv1, o[c], 0, 0, 0);
    }
  }

  // ---- merge the 4 per-wave partial states ----
  __syncthreads();  // all waves done with pbuf region before sO overwrites it
  float* sO = (float*)smem;                       // [4][16][68]
  float* sM = (float*)(smem + 4 * 16 * 68 * 4);   // [4][16]
  float* sL = sM + 64;                            // [4][16]
  #pragma unroll
  for (int c = 0; c < 4; c++)
    #pragma unroll
    for (int r = 0; r < 4; r++)
      sO[(wave * 16 + quad * 4 + r) * 68 + c * 16 + lcol] = o[c][r];
  if (lcol == 0){
    #pragma unroll
    for (int r = 0; r < 4; r++){
      sM[wave * 16 + quad * 4 + r] = m_run[r];
      sL[wave * 16 + quad * 4 + r] = l_run[r];
    }
  }
  __syncthreads();
  // wave w combines + writes column group w (16 cols)
  const int cg = wave;
  #pragma unroll
  for (int r = 0; r < 4; r++){
    const int row = quad * 4 + r;
    float m0 = sM[row], m1 = sM[16 + row], m2 = sM[32 + row], m3 = sM[48 + row];
    float ms = fmaxf(fmaxf(m0, m1), fmaxf(m2, m3));
    float e0 = __expf(m0 - ms), e1 = __expf(m1 - ms), e2 = __expf(m2 - ms), e3 = __expf(m3 - ms);
    float L = sL[row] * e0 + sL[16 + row] * e1 + sL[32 + row] * e2 + sL[48 + row] * e3;
    const int col = cg * 16 + lcol;
    float O = sO[row * 68 + col] * e0 + sO[(16 + row) * 68 + col] * e1
            + sO[(32 + row) * 68 + col] * e2 + sO[(48 + row) * 68 + col] * e3;
    attn_out[(size_t)(b * TT + t16 + row) * 1024 + n * 64 + col] = f2bf(O / L);
  }
}

// ---------------- launcher ----------------
extern "C" void kernel_launch(void* const* d_in, const int* in_sizes, int n_in,
                              void* d_out, int out_size, void* d_ws, size_t ws_size,
                              hipStream_t stream){
  const float* x      = (const float*)d_in[0];
  const float* rel    = (const float*)d_in[1];
  const float* memory = (const float*)d_in[2];
  const int*   episode_idx = (const int*)d_in[3];
  const int*   dones  = (const int*)d_in[4];
  const float* Wq  = (const float*)d_in[5];
  const float* Wk  = (const float*)d_in[6];
  const float* Wv  = (const float*)d_in[7];
  const float* Wr  = (const float*)d_in[8];
  const float* u   = (const float*)d_in[9];
  const float* v   = (const float*)d_in[10];
  const float* Wout  = (const float*)d_in[11];
  const float* b_out = (const float*)d_in[12];
  float* out = (float*)d_out;

  char* ws = (char*)d_ws;
  size_t off = 0;
  auto alloc = [&](size_t bytes) -> char* {
    char* p = ws + off;
    off += (bytes + 255) & ~(size_t)255;
    return p;
  };
  short* x_bf   = (short*)alloc((size_t)NB * TT * FF * 2);
  short* kv_bf  = (short*)alloc((size_t)NB * SS * FF * 2);
  short* rel_bf = (short*)alloc((size_t)SS * FF * 2);
  short* WqT    = (short*)alloc((size_t)FF * 1024 * 2);
  short* WkT    = (short*)alloc((size_t)FF * 1024 * 2);
  short* WvT    = (short*)alloc((size_t)FF * 1024 * 2);
  short* WrT    = (short*)alloc((size_t)FF * 1024 * 2);
  short* WoT    = (short*)alloc((size_t)FF * 1024 * 2);
  short* qu     = (short*)alloc((size_t)NB * TT * 1024 * 2);
  short* qv     = (short*)alloc((size_t)NB * TT * 1024 * 2);
  short* kbf    = (short*)alloc((size_t)NB * SS * 1024 * 2);
  short* vTb    = (short*)alloc((size_t)NB * SS * 1024 * 2);
  short* rbf    = (short*)alloc((size_t)SS * 1024 * 2);
  short* BD     = (short*)alloc((size_t)NB * NHD * TT * SS * 2);   // 128 MB
  int*   ki     = (int*)  alloc((size_t)NB * SS * 4);
  short* attn   = (short*)alloc((size_t)NB * TT * 1024 * 2);
  (void)ws_size; (void)in_sizes; (void)n_in; (void)out_size;

  // pack
  cast_kernel<<<(NB*TT*FF/4 + 255)/256, 256, 0, stream>>>(x, x_bf, NB*TT*FF/4);
  cast_kernel<<<(SS*FF/4 + 255)/256, 256, 0, stream>>>(rel, rel_bf, SS*FF/4);
  build_kv<<<(NB*SS*FF/4)/256, 256, 0, stream>>>(memory, x, kv_bf);
  dim3 tb(32, 8), tg(32, 32);
  transpose_cast<<<tg, tb, 0, stream>>>(Wq, WqT);
  transpose_cast<<<tg, tb, 0, stream>>>(Wk, WkT);
  transpose_cast<<<tg, tb, 0, stream>>>(Wv, WvT);
  transpose_cast<<<tg, tb, 0, stream>>>(Wr, WrT);
  transpose_cast<<<tg, tb, 0, stream>>>(Wout, WoT);
  scan_kernel<<<NB, TT, 0, stream>>>(episode_idx, dones, ki);

  // projections
  gemm_nt<1><<<dim3(32, 16), 256, 0, stream>>>(x_bf, WqT, FF, qu, qv, u, v, nullptr);
  gemm_nt<0><<<dim3(64, 16), 256, 0, stream>>>(kv_bf, WkT, FF, kbf, nullptr, nullptr, nullptr, nullptr);
  gemm_nt<3><<<dim3(64, 16), 256, 0, stream>>>(kv_bf, WvT, FF, vTb, nullptr, nullptr, nullptr, nullptr);
  gemm_nt<0><<<dim3(32, 16), 256, 0, stream>>>(rel_bf, WrT, FF, rbf, nullptr, nullptr, nullptr, nullptr);

  // relative-position bias table
  bd_gemm<<<dim3(32, 16, 32), 256, 0, stream>>>(qv, rbf, BD);

  // attention (split-K across the 4 waves of each block)
  attn_kernel<<<2048, 256, 0, stream>>>(qu, BD, kbf, vTb, ki, attn);

  // output projection
  gemm_nt<2><<<dim3(32, 16), 256, 0, stream>>>(attn, WoT, 1024, nullptr, nullptr, b_out, nullptr, out);
}

// Round 3
// 656.172 us; speedup vs baseline: 1.1400x; 1.0719x over previous
//
#include <hip/hip_runtime.h>
#include <cstdint>
#include <cstddef>

// Problem constants
#define NB 2
#define TT 1024
#define MMEM 1024
#define SS 2048   // M + T
#define FF 1024
#define NHD 16    // heads
#define HD 64     // head dim

typedef __attribute__((ext_vector_type(8))) short bf16x8;
typedef __attribute__((ext_vector_type(4))) float f32x4;

__device__ __forceinline__ float bf2f(short s){
  unsigned u = ((unsigned)(unsigned short)s) << 16;
  float f; __builtin_memcpy(&f, &u, 4); return f;
}
__device__ __forceinline__ short f2bf(float f){
  unsigned u; __builtin_memcpy(&u, &f, 4);
  u += 0x7fffu + ((u >> 16) & 1u);   // RNE
  return (short)(u >> 16);
}

// ---------------- pack / cast kernels ----------------

__global__ void cast_kernel(const float* __restrict__ in, short* __restrict__ out, int n4){
  int i = blockIdx.x * blockDim.x + threadIdx.x;
  if (i >= n4) return;
  float4 v = ((const float4*)in)[i];
  short4 o; o.x = f2bf(v.x); o.y = f2bf(v.y); o.z = f2bf(v.z); o.w = f2bf(v.w);
  ((short4*)out)[i] = o;
}

// kv_in = concat(memory, x) along seq, cast to bf16. layout [B*SS, FF]
__global__ void build_kv(const float* __restrict__ mem, const float* __restrict__ x,
                         short* __restrict__ out){
  int i = blockIdx.x * blockDim.x + threadIdx.x;  // element/4 index
  int idx = i * 4;
  int row = idx >> 10;          // b*SS + s
  int col = idx & 1023;
  int b = row >> 11, s = row & 2047;
  const float* src = (s < MMEM) ? (mem + ((size_t)b*MMEM + s)*FF + col)
                                : (x   + ((size_t)b*TT + (s - MMEM))*FF + col);
  float4 v = *(const float4*)src;
  short4 o; o.x = f2bf(v.x); o.y = f2bf(v.y); o.z = f2bf(v.z); o.w = f2bf(v.w);
  ((short4*)out)[i] = o;
}

// out[c][r] = in[r][c], 1024x1024, f32 -> bf16
__global__ void transpose_cast(const float* __restrict__ in, short* __restrict__ out){
  __shared__ float tile[32][33];
  int bx = blockIdx.x * 32, by = blockIdx.y * 32;
  int tx = threadIdx.x, ty = threadIdx.y;
  for (int j = ty; j < 32; j += 8)
    tile[j][tx] = in[(size_t)(by + j)*1024 + bx + tx];
  __syncthreads();
  for (int j = ty; j < 32; j += 8)
    out[(size_t)(bx + j)*1024 + by + tx] = f2bf(tile[tx][j]);
}

// ki[b, 0:M] = episode_idx[b,:]; ki[b, M+t] = episode_idx[b,M-1] + cumsum(dones)[t]
__global__ void scan_kernel(const int* __restrict__ episode_idx, const int* __restrict__ dones,
                            int* __restrict__ ki){
  __shared__ int buf[TT];
  int b = blockIdx.x, t = threadIdx.x;
  buf[t] = dones[b*TT + t];
  __syncthreads();
  for (int off = 1; off < TT; off <<= 1){
    int v = (t >= off) ? buf[t - off] : 0;
    __syncthreads();
    buf[t] += v;
    __syncthreads();
  }
  int base = episode_idx[b*MMEM + (MMEM - 1)];
  ki[b*SS + t] = episode_idx[b*MMEM + t];
  ki[b*SS + MMEM + t] = base + buf[t];
}

// ---------------- GEMM: C[i,j] = sum_k A[i,k] * BT[j,k]  (bf16 in, f32 acc) ------
// MODE 0: bf16 out C0.   MODE 1: C0 = acc+add0[j], C1 = acc+add1[j] (bf16).
// MODE 2: f32 out Cf = acc + add0[j].
// MODE 3: bf16 out transposed per-head: C0[((b*16+n)*64+h)*2048 + s], row=(b,s), col=(n,h)
template<int MODE>
__global__ __launch_bounds__(256) void gemm_nt(const short* __restrict__ A, const short* __restrict__ BT,
                        int K, short* __restrict__ C0, short* __restrict__ C1,
                        const float* __restrict__ add0, const float* __restrict__ add1,
                        float* __restrict__ Cf){
  const int row0 = blockIdx.x * 64, col0 = blockIdx.y * 64;
  const int wave = threadIdx.x >> 6, lane = threadIdx.x & 63;
  const int quad = lane >> 4, lcol = lane & 15;
  const int r0 = row0 + wave * 16;
  f32x4 acc[4];
  #pragma unroll
  for (int c = 0; c < 4; c++) acc[c] = (f32x4){0.f, 0.f, 0.f, 0.f};
  const short* ap = A  + (size_t)(r0 + lcol) * K + quad * 8;
  const short* bp = BT + (size_t)(col0 + lcol) * K + quad * 8;
  #pragma unroll 4
  for (int k0 = 0; k0 < K; k0 += 32){
    bf16x8 a = *(const bf16x8*)(ap + k0);
    #pragma unroll
    for (int c = 0; c < 4; c++){
      bf16x8 bb = *(const bf16x8*)(bp + (size_t)c * 16 * K + k0);
      acc[c] = __builtin_amdgcn_mfma_f32_16x16x32_bf16(a, bb, acc[c], 0, 0, 0);
    }
  }
  #pragma unroll
  for (int c = 0; c < 4; c++){
    int cc = col0 + c * 16 + lcol;
    #pragma unroll
    for (int r = 0; r < 4; r++){
      int rr = r0 + quad * 4 + r;
      float v = acc[c][r];
      if (MODE == 0){
        C0[(size_t)rr * 1024 + cc] = f2bf(v);
      } else if (MODE == 1){
        C0[(size_t)rr * 1024 + cc] = f2bf(v + add0[cc]);
        C1[(size_t)rr * 1024 + cc] = f2bf(v + add1[cc]);
      } else if (MODE == 2){
        Cf[(size_t)rr * 1024 + cc] = v + add0[cc];
      } else { // MODE 3: transposed per-head V:  [(b*16+n)*64+h][s]
        int bb2 = rr >> 11, ss = rr & 2047;
        C0[(size_t)(((bb2 << 4) + (cc >> 6)) * 64 + (cc & 63)) * 2048 + ss] = f2bf(v);
      }
    }
  }
}

// BD[b,n,t,m] = sum_h qv[b,t,n,h] * r[m,n,h]   (K=64)
__global__ __launch_bounds__(256) void bd_gemm(const short* __restrict__ qv, const short* __restrict__ rbf,
                        short* __restrict__ BD){
  const int m0 = blockIdx.x * 64, t0 = blockIdx.y * 64;
  const int bn = blockIdx.z; const int b = bn >> 4, n = bn & 15;
  // band skip: needed m >= 1023 - t; min over tile = 960 - t0
  if (m0 + 63 < 960 - t0) return;
  const int wave = threadIdx.x >> 6, lane = threadIdx.x & 63;
  const int quad = lane >> 4, lcol = lane & 15;
  const int tw = t0 + wave * 16;
  const short* ap = qv + (size_t)(b * TT + tw + lcol) * 1024 + n * 64 + quad * 8;
  bf16x8 a0 = *(const bf16x8*)(ap);
  bf16x8 a1 = *(const bf16x8*)(ap + 32);
  #pragma unroll
  for (int c = 0; c < 4; c++){
    const short* bp = rbf + (size_t)(m0 + 16 * c + lcol) * 1024 + n * 64 + quad * 8;
    bf16x8 b0 = *(const bf16x8*)(bp);
    bf16x8 b1 = *(const bf16x8*)(bp + 32);
    f32x4 z = (f32x4){0.f, 0.f, 0.f, 0.f};
    z = __builtin_amdgcn_mfma_f32_16x16x32_bf16(a0, b0, z, 0, 0, 0);
    z = __builtin_amdgcn_mfma_f32_16x16x32_bf16(a1, b1, z, 0, 0, 0);
    #pragma unroll
    for (int r = 0; r < 4; r++)
      BD[((size_t)((b * NHD + n) * TT + tw + quad * 4 + r)) * SS + m0 + 16 * c + lcol] = f2bf(z[r]);
  }
}

// ---------------- flash attention, split-K across waves ----------------
// grid: 2048 = B * N * (T/16). Block = 4 waves; all waves share the same 16
// query rows; wave w processes k-tiles w, w+4, w+8, ... with private online
// softmax state; states merge through LDS at the end (softmax-merge).
// NOTE: plain __launch_bounds__(256) — the (256,8) variant capped VGPRs at 32
// and spilled ~300 MB/dispatch to scratch (R2: WRITE_SIZE 4->160 MB). The body
// needs ~60-80 VGPRs; let the allocator pick.
__global__ __launch_bounds__(256) void attn_kernel(const short* __restrict__ qu, const short* __restrict__ BD,
                            const short* __restrict__ kk, const short* __restrict__ vT,
                            const int* __restrict__ ki, short* __restrict__ attn_out){
  const int blk = blockIdx.x;
  const int t16 = (blk & 63) * 16;
  const int n = (blk >> 6) & 15;
  const int b = blk >> 10;
  const int wave = threadIdx.x >> 6, lane = threadIdx.x & 63;
  const int quad = lane >> 4, lcol = lane & 15;

  // union LDS: phase 1 = per-wave P tiles (4*16*72*2 = 9216 B)
  //            phase 2 = partial O (4*16*68*4 = 17408 B) + m,l (512 B)
  __shared__ __align__(16) char smem[17920];
  short* pb = (short*)smem + wave * (16 * 72);

  const short* qp = qu + (size_t)(b * TT + t16 + lcol) * 1024 + n * 64 + quad * 8;
  bf16x8 aq0 = *(const bf16x8*)(qp);
  bf16x8 aq1 = *(const bf16x8*)(qp + 32);

  int trow[4], qi_r[4];
  #pragma unroll
  for (int r = 0; r < 4; r++){
    trow[r] = t16 + quad * 4 + r;
    qi_r[r] = ki[b * SS + MMEM + trow[r]];
  }

  float m_run[4], l_run[4];
  f32x4 o[4];
  #pragma unroll
  for (int r = 0; r < 4; r++){ m_run[r] = -1e30f; l_run[r] = 0.f; }
  #pragma unroll
  for (int c = 0; c < 4; c++) o[c] = (f32x4){0.f, 0.f, 0.f, 0.f};

  const float scale = 0.125f;
  const size_t bd_base = (size_t)((b * NHD + n) * TT);
  const size_t vt_base = (size_t)((b * NHD + n) * HD);

  const int ntiles = ((t16 + 1039) >> 6) + 1;   // covers s <= t + M for all 16 rows
  for (int kt = wave; kt < ntiles; kt += 4){
    const int s0 = kt * 64;
    // ---- S = Qu . K^T ----
    f32x4 sacc[4];
    #pragma unroll
    for (int c = 0; c < 4; c++){
      const short* kp = kk + (size_t)(b * SS + s0 + 16 * c + lcol) * 1024 + n * 64 + quad * 8;
      bf16x8 b0 = *(const bf16x8*)(kp);
      bf16x8 b1 = *(const bf16x8*)(kp + 32);
      f32x4 z = (f32x4){0.f, 0.f, 0.f, 0.f};
      z = __builtin_amdgcn_mfma_f32_16x16x32_bf16(aq0, b0, z, 0, 0, 0);
      z = __builtin_amdgcn_mfma_f32_16x16x32_bf16(aq1, b1, z, 0, 0, 0);
      sacc[c] = z;
    }
    int ki_c[4];
    #pragma unroll
    for (int c = 0; c < 4; c++) ki_c[c] = ki[b * SS + s0 + 16 * c + lcol];

    // ---- bias gather + mask + logits ----
    float p[4][4];
    float rowmax[4];
    #pragma unroll
    for (int r = 0; r < 4; r++) rowmax[r] = -1e30f;
    #pragma unroll
    for (int c = 0; c < 4; c++){
      const int s = s0 + 16 * c + lcol;
      #pragma unroll
      for (int r = 0; r < 4; r++){
        const int t = trow[r];
        int m = s - t + (TT - 1);          // >= 0 always
        m = (m > SS - 1) ? (SS - 1) : m;   // clamp; clamped entries are causally masked
        float bd = bf2f(BD[(bd_base + t) * SS + m]);
        float lg = (sacc[c][r] + bd) * scale;
        const bool valid = (s <= t + MMEM) && (ki_c[c] == qi_r[r]);
        lg = valid ? lg : -1e30f;
        p[c][r] = lg;
        rowmax[r] = fmaxf(rowmax[r], lg);
      }
    }
    // ---- online softmax (per-wave private state) ----
    #pragma unroll
    for (int r = 0; r < 4; r++){
      float vmx = rowmax[r];
      #pragma unroll
      for (int off = 1; off < 16; off <<= 1) vmx = fmaxf(vmx, __shfl_xor(vmx, off, 64));
      float mnew = fmaxf(m_run[r], vmx);
      float alpha = __expf(m_run[r] - mnew);
      m_run[r] = mnew;
      l_run[r] *= alpha;
      #pragma unroll
      for (int c = 0; c < 4; c++) o[c][r] *= alpha;
    }
    float psum[4] = {0.f, 0.f, 0.f, 0.f};
    #pragma unroll
    for (int c = 0; c < 4; c++)
      #pragma unroll
      for (int r = 0; r < 4; r++){
        float pv = __expf(p[c][r] - m_run[r]);
        p[c][r] = pv;
        psum[r] += pv;
      }
    #pragma unroll
    for (int r = 0; r < 4; r++){
      float vs = psum[r];
      #pragma unroll
      for (int off = 1; off < 16; off <<= 1) vs += __shfl_xor(vs, off, 64);
      l_run[r] += vs;
    }
    // ---- P: C-layout -> A-layout via per-wave LDS (wave-synchronous) ----
    #pragma unroll
    for (int c = 0; c < 4; c++)
      #pragma unroll
      for (int r = 0; r < 4; r++)
        pb[(quad * 4 + r) * 72 + 16 * c + lcol] = f2bf(p[c][r]);
    bf16x8 pa0 = *(const bf16x8*)(&pb[lcol * 72 + quad * 8]);
    bf16x8 pa1 = *(const bf16x8*)(&pb[lcol * 72 + 32 + quad * 8]);
    // ---- O += P . V  (V pre-transposed per head: dot-of-rows pattern) ----
    #pragma unroll
    for (int c = 0; c < 4; c++){
      const short* vtp = vT + (vt_base + c * 16 + lcol) * (size_t)SS + s0 + quad * 8;
      bf16x8 bv0 = *(const bf16x8*)(vtp);
      bf16x8 bv1 = *(const bf16x8*)(vtp + 32);
      o[c] = __builtin_amdgcn_mfma_f32_16x16x32_bf16(pa0, bv0, o[c], 0, 0, 0);
      o[c] = __builtin_amdgcn_mfma_f32_16x16x32_bf16(pa1, bv1, o[c], 0, 0, 0);
    }
  }

  // ---- merge the 4 per-wave partial states ----
  __syncthreads();  // all waves done with pbuf region before sO overwrites it
  float* sO = (float*)smem;                       // [4][16][68]
  float* sM = (float*)(smem + 4 * 16 * 68 * 4);   // [4][16]
  float* sL = sM + 64;                            // [4][16]
  #pragma unroll
  for (int c = 0; c < 4; c++)
    #pragma unroll
    for (int r = 0; r < 4; r++)
      sO[(wave * 16 + quad * 4 + r) * 68 + c * 16 + lcol] = o[c][r];
  if (lcol == 0){
    #pragma unroll
    for (int r = 0; r < 4; r++){
      sM[wave * 16 + quad * 4 + r] = m_run[r];
      sL[wave * 16 + quad * 4 + r] = l_run[r];
    }
  }
  __syncthreads();
  // wave w combines + writes column group w (16 cols)
  const int cg = wave;
  #pragma unroll
  for (int r = 0; r < 4; r++){
    const int row = quad * 4 + r;
    float m0 = sM[row], m1 = sM[16 + row], m2 = sM[32 + row], m3 = sM[48 + row];
    float ms = fmaxf(fmaxf(m0, m1), fmaxf(m2, m3));
    float e0 = __expf(m0 - ms), e1 = __expf(m1 - ms), e2 = __expf(m2 - ms), e3 = __expf(m3 - ms);
    float L = sL[row] * e0 + sL[16 + row] * e1 + sL[32 + row] * e2 + sL[48 + row] * e3;
    const int col = cg * 16 + lcol;
    float O = sO[row * 68 + col] * e0 + sO[(16 + row) * 68 + col] * e1
            + sO[(32 + row) * 68 + col] * e2 + sO[(48 + row) * 68 + col] * e3;
    attn_out[(size_t)(b * TT + t16 + row) * 1024 + n * 64 + col] = f2bf(O / L);
  }
}

// ---------------- launcher ----------------
extern "C" void kernel_launch(void* const* d_in, const int* in_sizes, int n_in,
                              void* d_out, int out_size, void* d_ws, size_t ws_size,
                              hipStream_t stream){
  const float* x      = (const float*)d_in[0];
  const float* rel    = (const float*)d_in[1];
  const float* memory = (const float*)d_in[2];
  const int*   episode_idx = (const int*)d_in[3];
  const int*   dones  = (const int*)d_in[4];
  const float* Wq  = (const float*)d_in[5];
  const float* Wk  = (const float*)d_in[6];
  const float* Wv  = (const float*)d_in[7];
  const float* Wr  = (const float*)d_in[8];
  const float* u   = (const float*)d_in[9];
  const float* v   = (const float*)d_in[10];
  const float* Wout  = (const float*)d_in[11];
  const float* b_out = (const float*)d_in[12];
  float* out = (float*)d_out;

  char* ws = (char*)d_ws;
  size_t off = 0;
  auto alloc = [&](size_t bytes) -> char* {
    char* p = ws + off;
    off += (bytes + 255) & ~(size_t)255;
    return p;
  };
  short* x_bf   = (short*)alloc((size_t)NB * TT * FF * 2);
  short* kv_bf  = (short*)alloc((size_t)NB * SS * FF * 2);
  short* rel_bf = (short*)alloc((size_t)SS * FF * 2);
  short* WqT    = (short*)alloc((size_t)FF * 1024 * 2);
  short* WkT    = (short*)alloc((size_t)FF * 1024 * 2);
  short* WvT    = (short*)alloc((size_t)FF * 1024 * 2);
  short* WrT    = (short*)alloc((size_t)FF * 1024 * 2);
  short* WoT    = (short*)alloc((size_t)FF * 1024 * 2);
  short* qu     = (short*)alloc((size_t)NB * TT * 1024 * 2);
  short* qv     = (short*)alloc((size_t)NB * TT * 1024 * 2);
  short* kbf    = (short*)alloc((size_t)NB * SS * 1024 * 2);
  short* vTb    = (short*)alloc((size_t)NB * SS * 1024 * 2);
  short* rbf    = (short*)alloc((size_t)SS * 1024 * 2);
  short* BD     = (short*)alloc((size_t)NB * NHD * TT * SS * 2);   // 128 MB
  int*   ki     = (int*)  alloc((size_t)NB * SS * 4);
  short* attn   = (short*)alloc((size_t)NB * TT * 1024 * 2);
  (void)ws_size; (void)in_sizes; (void)n_in; (void)out_size;

  // pack
  cast_kernel<<<(NB*TT*FF/4 + 255)/256, 256, 0, stream>>>(x, x_bf, NB*TT*FF/4);
  cast_kernel<<<(SS*FF/4 + 255)/256, 256, 0, stream>>>(rel, rel_bf, SS*FF/4);
  build_kv<<<(NB*SS*FF/4)/256, 256, 0, stream>>>(memory, x, kv_bf);
  dim3 tb(32, 8), tg(32, 32);
  transpose_cast<<<tg, tb, 0, stream>>>(Wq, WqT);
  transpose_cast<<<tg, tb, 0, stream>>>(Wk, WkT);
  transpose_cast<<<tg, tb, 0, stream>>>(Wv, WvT);
  transpose_cast<<<tg, tb, 0, stream>>>(Wr, WrT);
  transpose_cast<<<tg, tb, 0, stream>>>(Wout, WoT);
  scan_kernel<<<NB, TT, 0, stream>>>(episode_idx, dones, ki);

  // projections
  gemm_nt<1><<<dim3(32, 16), 256, 0, stream>>>(x_bf, WqT, FF, qu, qv, u, v, nullptr);
  gemm_nt<0><<<dim3(64, 16), 256, 0, stream>>>(kv_bf, WkT, FF, kbf, nullptr, nullptr, nullptr, nullptr);
  gemm_nt<3><<<dim3(64, 16), 256, 0, stream>>>(kv_bf, WvT, FF, vTb, nullptr, nullptr, nullptr, nullptr);
  gemm_nt<0><<<dim3(32, 16), 256, 0, stream>>>(rel_bf, WrT, FF, rbf, nullptr, nullptr, nullptr, nullptr);

  // relative-position bias table
  bd_gemm<<<dim3(32, 16, 32), 256, 0, stream>>>(qv, rbf, BD);

  // attention (split-K across the 4 waves of each block)
  attn_kernel<<<2048, 256, 0, stream>>>(qu, BD, kbf, vTb, ki, attn);

  // output projection
  gemm_nt<2><<<dim3(32, 16), 256, 0, stream>>>(attn, WoT, 1024, nullptr, nullptr, b_out, nullptr, out);
}

// Round 4
// 465.408 us; speedup vs baseline: 1.6073x; 1.4099x over previous
//
#include <hip/hip_runtime.h>
#include <cstdint>
#include <cstddef>

// Problem constants
#define NB 2
#define TT 1024
#define MMEM 1024
#define SS 2048   // M + T
#define FF 1024
#define NHD 16    // heads
#define HD 64     // head dim

typedef __attribute__((ext_vector_type(8))) short bf16x8;
typedef __attribute__((ext_vector_type(4))) float f32x4;

__device__ __forceinline__ float bf2f(short s){
  unsigned u = ((unsigned)(unsigned short)s) << 16;
  float f; __builtin_memcpy(&f, &u, 4); return f;
}
__device__ __forceinline__ short f2bf(float f){
  unsigned u; __builtin_memcpy(&u, &f, 4);
  u += 0x7fffu + ((u >> 16) & 1u);   // RNE
  return (short)(u >> 16);
}

// async global->LDS, 16 B per lane; LDS dest = wave-uniform base + lane*16
typedef const __attribute__((address_space(1))) void gv_t;
typedef __attribute__((address_space(3))) void lv_t;
__device__ __forceinline__ void stage16(const void* g, void* l){
  __builtin_amdgcn_global_load_lds((gv_t*)g, (lv_t*)l, 16, 0, 0);
}

// ---------------- pack / cast kernels ----------------

__global__ void cast_kernel(const float* __restrict__ in, short* __restrict__ out, int n4){
  int i = blockIdx.x * blockDim.x + threadIdx.x;
  if (i >= n4) return;
  float4 v = ((const float4*)in)[i];
  short4 o; o.x = f2bf(v.x); o.y = f2bf(v.y); o.z = f2bf(v.z); o.w = f2bf(v.w);
  ((short4*)out)[i] = o;
}

// kv_in = concat(memory, x) along seq, cast to bf16. layout [B*SS, FF]
__global__ void build_kv(const float* __restrict__ mem, const float* __restrict__ x,
                         short* __restrict__ out){
  int i = blockIdx.x * blockDim.x + threadIdx.x;  // element/4 index
  int idx = i * 4;
  int row = idx >> 10;          // b*SS + s
  int col = idx & 1023;
  int b = row >> 11, s = row & 2047;
  const float* src = (s < MMEM) ? (mem + ((size_t)b*MMEM + s)*FF + col)
                                : (x   + ((size_t)b*TT + (s - MMEM))*FF + col);
  float4 v = *(const float4*)src;
  short4 o; o.x = f2bf(v.x); o.y = f2bf(v.y); o.z = f2bf(v.z); o.w = f2bf(v.w);
  ((short4*)out)[i] = o;
}

// out[c][r] = in[r][c], 1024x1024, f32 -> bf16
__global__ void transpose_cast(const float* __restrict__ in, short* __restrict__ out){
  __shared__ float tile[32][33];
  int bx = blockIdx.x * 32, by = blockIdx.y * 32;
  int tx = threadIdx.x, ty = threadIdx.y;
  for (int j = ty; j < 32; j += 8)
    tile[j][tx] = in[(size_t)(by + j)*1024 + bx + tx];
  __syncthreads();
  for (int j = ty; j < 32; j += 8)
    out[(size_t)(bx + j)*1024 + by + tx] = f2bf(tile[tx][j]);
}

// ki[b, 0:M] = episode_idx[b,:]; ki[b, M+t] = episode_idx[b,M-1] + cumsum(dones)[t]
__global__ void scan_kernel(const int* __restrict__ episode_idx, const int* __restrict__ dones,
                            int* __restrict__ ki){
  __shared__ int buf[TT];
  int b = blockIdx.x, t = threadIdx.x;
  buf[t] = dones[b*TT + t];
  __syncthreads();
  for (int off = 1; off < TT; off <<= 1){
    int v = (t >= off) ? buf[t - off] : 0;
    __syncthreads();
    buf[t] += v;
    __syncthreads();
  }
  int base = episode_idx[b*MMEM + (MMEM - 1)];
  ki[b*SS + t] = episode_idx[b*MMEM + t];
  ki[b*SS + MMEM + t] = base + buf[t];
}

// ---------------- m97-style 128x128 GEMM core (K=1024, BK=32) ----------------
// C[i,j] = sum_k A[i,k] * BT[j,k]; A,BT row-major bf16.
// 4 waves in 2x2; each wave owns a 64x64 quadrant (4x4 frags of 16x16x32 MFMA).
// Staging: global_load_lds 16B/lane; LDS tiles As/Bs [128][32] contiguous
// (no padding — global_load_lds dest is wave-uniform base + lane*16).
__device__ __forceinline__ void gemm128_core(const short* __restrict__ A,
                                             const short* __restrict__ BT,
                                             int row0, int col0,
                                             short* As, short* Bs,
                                             f32x4 (&acc)[4][4]){
  const int lane = threadIdx.x & 63, wv = threadIdx.x >> 6;
  const int lcol = lane & 15, quad = lane >> 4;
  const int wr = (wv >> 1) * 64, wc = (wv & 1) * 64;

  #pragma unroll
  for (int r = 0; r < 4; r++)
    #pragma unroll
    for (int c = 0; c < 4; c++) acc[r][c] = (f32x4){0.f, 0.f, 0.f, 0.f};

  // per-lane global srcs: seg = wv (+4); row = seg*16 + lane/4; col bytes (lane&3)*16
  const short* gA = A  + (size_t)(row0 + wv*16 + (lane>>2)) * 1024 + (lane&3)*8;
  const short* gB = BT + (size_t)(col0 + wv*16 + (lane>>2)) * 1024 + (lane&3)*8;
  short* lA0 = As + wv*512;  short* lA1 = As + (wv+4)*512;
  short* lB0 = Bs + wv*512;  short* lB1 = Bs + (wv+4)*512;

  for (int k0 = 0; k0 < 1024; k0 += 32){
    __syncthreads();                       // prev iter's ds_reads done
    stage16(gA + k0,            lA0);
    stage16(gA + 64*1024 + k0,  lA1);
    stage16(gB + k0,            lB0);
    stage16(gB + 64*1024 + k0,  lB1);
    __syncthreads();                       // drains vmcnt(0) -> LDS tiles ready
    bf16x8 af[4], bfr[4];
    #pragma unroll
    for (int r = 0; r < 4; r++)
      af[r] = *(const bf16x8*)&As[(wr + r*16 + lcol)*32 + quad*8];
    #pragma unroll
    for (int c = 0; c < 4; c++)
      bfr[c] = *(const bf16x8*)&Bs[(wc + c*16 + lcol)*32 + quad*8];
    #pragma unroll
    for (int c = 0; c < 4; c++)
      #pragma unroll
      for (int r = 0; r < 4; r++)
        acc[r][c] = __builtin_amdgcn_mfma_f32_16x16x32_bf16(af[r], bfr[c], acc[r][c], 0, 0, 0);
  }
}

// Fused projection GEMM: blockIdx.z selects job (keeps ~3 blocks/CU resident):
//   z=0: kbf = kv @ WkT        (4096 rows)
//   z=1: vT  = kv @ WvT, stored per-head transposed  (4096 rows)
//   z=2: qu/qv = x @ WqT + u/v (2048 rows; bx<16)
//   z=3: rbf = rel @ WrT       (2048 rows; bx<16)
__global__ __launch_bounds__(256) void proj_gemm(
    const short* __restrict__ kv, const short* __restrict__ xb,
    const short* __restrict__ relb,
    const short* __restrict__ WkT, const short* __restrict__ WvT,
    const short* __restrict__ WqT, const short* __restrict__ WrT,
    short* __restrict__ kbf, short* __restrict__ vT,
    short* __restrict__ qu, short* __restrict__ qv,
    short* __restrict__ rbf,
    const float* __restrict__ ubias, const float* __restrict__ vbias){
  const int z = blockIdx.z;
  const int bx = blockIdx.x;
  const short* A; const short* BT;
  if (z == 0){ A = kv; BT = WkT; }
  else if (z == 1){ A = kv; BT = WvT; }
  else if (z == 2){ if (bx >= 16) return; A = xb; BT = WqT; }
  else { if (bx >= 16) return; A = relb; BT = WrT; }
  const int row0 = bx * 128, col0 = blockIdx.y * 128;

  __shared__ __align__(16) short As[128*32];
  __shared__ __align__(16) short Bs[128*32];
  f32x4 acc[4][4];
  gemm128_core(A, BT, row0, col0, As, Bs, acc);

  const int lane = threadIdx.x & 63, wv = threadIdx.x >> 6;
  const int lcol = lane & 15, quad = lane >> 4;
  const int wr = (wv >> 1) * 64, wc = (wv & 1) * 64;
  #pragma unroll
  for (int c = 0; c < 4; c++){
    const int cc = col0 + wc + c*16 + lcol;
    #pragma unroll
    for (int r = 0; r < 4; r++){
      #pragma unroll
      for (int ri = 0; ri < 4; ri++){
        const int rr = row0 + wr + r*16 + quad*4 + ri;
        float val = acc[r][c][ri];
        if (z == 0){
          kbf[(size_t)rr * 1024 + cc] = f2bf(val);
        } else if (z == 1){
          int b = rr >> 11, s = rr & 2047;
          vT[(size_t)(((b << 4) + (cc >> 6)) * 64 + (cc & 63)) * 2048 + s] = f2bf(val);
        } else if (z == 2){
          qu[(size_t)rr * 1024 + cc] = f2bf(val + ubias[cc]);
          qv[(size_t)rr * 1024 + cc] = f2bf(val + vbias[cc]);
        } else {
          rbf[(size_t)rr * 1024 + cc] = f2bf(val);
        }
      }
    }
  }
}

// Output projection: out = attn @ WoT + b_out (f32 out, 2048 rows)
__global__ __launch_bounds__(256) void out_gemm(const short* __restrict__ A,
                                                const short* __restrict__ BT,
                                                const float* __restrict__ bias,
                                                float* __restrict__ C){
  const int row0 = blockIdx.x * 128, col0 = blockIdx.y * 128;
  __shared__ __align__(16) short As[128*32];
  __shared__ __align__(16) short Bs[128*32];
  f32x4 acc[4][4];
  gemm128_core(A, BT, row0, col0, As, Bs, acc);

  const int lane = threadIdx.x & 63, wv = threadIdx.x >> 6;
  const int lcol = lane & 15, quad = lane >> 4;
  const int wr = (wv >> 1) * 64, wc = (wv & 1) * 64;
  #pragma unroll
  for (int c = 0; c < 4; c++){
    const int cc = col0 + wc + c*16 + lcol;
    const float bb = bias[cc];
    #pragma unroll
    for (int r = 0; r < 4; r++)
      #pragma unroll
      for (int ri = 0; ri < 4; ri++){
        const int rr = row0 + wr + r*16 + quad*4 + ri;
        C[(size_t)rr * 1024 + cc] = acc[r][c][ri] + bb;
      }
  }
}

// BD[b,n,t,m] = sum_h qv[b,t,n,h] * r[m,n,h]   (K=64)
__global__ __launch_bounds__(256) void bd_gemm(const short* __restrict__ qv, const short* __restrict__ rbf,
                        short* __restrict__ BD){
  const int m0 = blockIdx.x * 64, t0 = blockIdx.y * 64;
  const int bn = blockIdx.z; const int b = bn >> 4, n = bn & 15;
  // band skip: needed m >= 1023 - t; min over tile = 960 - t0
  if (m0 + 63 < 960 - t0) return;
  const int wave = threadIdx.x >> 6, lane = threadIdx.x & 63;
  const int quad = lane >> 4, lcol = lane & 15;
  const int tw = t0 + wave * 16;
  const short* ap = qv + (size_t)(b * TT + tw + lcol) * 1024 + n * 64 + quad * 8;
  bf16x8 a0 = *(const bf16x8*)(ap);
  bf16x8 a1 = *(const bf16x8*)(ap + 32);
  #pragma unroll
  for (int c = 0; c < 4; c++){
    const short* bp = rbf + (size_t)(m0 + 16 * c + lcol) * 1024 + n * 64 + quad * 8;
    bf16x8 b0 = *(const bf16x8*)(bp);
    bf16x8 b1 = *(const bf16x8*)(bp + 32);
    f32x4 z = (f32x4){0.f, 0.f, 0.f, 0.f};
    z = __builtin_amdgcn_mfma_f32_16x16x32_bf16(a0, b0, z, 0, 0, 0);
    z = __builtin_amdgcn_mfma_f32_16x16x32_bf16(a1, b1, z, 0, 0, 0);
    #pragma unroll
    for (int r = 0; r < 4; r++)
      BD[((size_t)((b * NHD + n) * TT + tw + quad * 4 + r)) * SS + m0 + 16 * c + lcol] = f2bf(z[r]);
  }
}

// ---------------- flash attention, split-K across waves ----------------
// grid: 2048 = B * N * (T/16). Block = 4 waves; all waves share the same 16
// query rows; wave w processes k-tiles w, w+4, w+8, ... with private online
// softmax state; states merge through LDS at the end (softmax-merge).
// NOTE: plain __launch_bounds__(256) — the (256,8) variant capped VGPRs at 32
// and spilled ~300 MB/dispatch to scratch (R2: WRITE_SIZE 4->160 MB). The body
// needs ~60-80 VGPRs; let the allocator pick.
__global__ __launch_bounds__(256) void attn_kernel(const short* __restrict__ qu, const short* __restrict__ BD,
                            const short* __restrict__ kk, const short* __restrict__ vT,
                            const int* __restrict__ ki, short* __restrict__ attn_out){
  const int blk = blockIdx.x;
  const int t16 = (blk & 63) * 16;
  const int n = (blk >> 6) & 15;
  const int b = blk >> 10;
  const int wave = threadIdx.x >> 6, lane = threadIdx.x & 63;
  const int quad = lane >> 4, lcol = lane & 15;

  // union LDS: phase 1 = per-wave P tiles (4*16*72*2 = 9216 B)
  //            phase 2 = partial O (4*16*68*4 = 17408 B) + m,l (512 B)
  __shared__ __align__(16) char smem[17920];
  short* pb = (short*)smem + wave * (16 * 72);

  const short* qp = qu + (size_t)(b * TT + t16 + lcol) * 1024 + n * 64 + quad * 8;
  bf16x8 aq0 = *(const bf16x8*)(qp);
  bf16x8 aq1 = *(const bf16x8*)(qp + 32);

  int trow[4], qi_r[4];
  #pragma unroll
  for (int r = 0; r < 4; r++){
    trow[r] = t16 + quad * 4 + r;
    qi_r[r] = ki[b * SS + MMEM + trow[r]];
  }

  float m_run[4], l_run[4];
  f32x4 o[4];
  #pragma unroll
  for (int r = 0; r < 4; r++){ m_run[r] = -1e30f; l_run[r] = 0.f; }
  #pragma unroll
  for (int c = 0; c < 4; c++) o[c] = (f32x4){0.f, 0.f, 0.f, 0.f};

  const float scale = 0.125f;
  const size_t bd_base = (size_t)((b * NHD + n) * TT);
  const size_t vt_base = (size_t)((b * NHD + n) * HD);

  const int ntiles = ((t16 + 1039) >> 6) + 1;   // covers s <= t + M for all 16 rows
  for (int kt = wave; kt < ntiles; kt += 4){
    const int s0 = kt * 64;
    // ---- S = Qu . K^T ----
    f32x4 sacc[4];
    #pragma unroll
    for (int c = 0; c < 4; c++){
      const short* kp = kk + (size_t)(b * SS + s0 + 16 * c + lcol) * 1024 + n * 64 + quad * 8;
      bf16x8 b0 = *(const bf16x8*)(kp);
      bf16x8 b1 = *(const bf16x8*)(kp + 32);
      f32x4 z = (f32x4){0.f, 0.f, 0.f, 0.f};
      z = __builtin_amdgcn_mfma_f32_16x16x32_bf16(aq0, b0, z, 0, 0, 0);
      z = __builtin_amdgcn_mfma_f32_16x16x32_bf16(aq1, b1, z, 0, 0, 0);
      sacc[c] = z;
    }
    int ki_c[4];
    #pragma unroll
    for (int c = 0; c < 4; c++) ki_c[c] = ki[b * SS + s0 + 16 * c + lcol];

    // ---- bias gather + mask + logits ----
    float p[4][4];
    float rowmax[4];
    #pragma unroll
    for (int r = 0; r < 4; r++) rowmax[r] = -1e30f;
    #pragma unroll
    for (int c = 0; c < 4; c++){
      const int s = s0 + 16 * c + lcol;
      #pragma unroll
      for (int r = 0; r < 4; r++){
        const int t = trow[r];
        int m = s - t + (TT - 1);          // >= 0 always
        m = (m > SS - 1) ? (SS - 1) : m;   // clamp; clamped entries are causally masked
        float bd = bf2f(BD[(bd_base + t) * SS + m]);
        float lg = (sacc[c][r] + bd) * scale;
        const bool valid = (s <= t + MMEM) && (ki_c[c] == qi_r[r]);
        lg = valid ? lg : -1e30f;
        p[c][r] = lg;
        rowmax[r] = fmaxf(rowmax[r], lg);
      }
    }
    // ---- online softmax (per-wave private state) ----
    #pragma unroll
    for (int r = 0; r < 4; r++){
      float vmx = rowmax[r];
      #pragma unroll
      for (int off = 1; off < 16; off <<= 1) vmx = fmaxf(vmx, __shfl_xor(vmx, off, 64));
      float mnew = fmaxf(m_run[r], vmx);
      float alpha = __expf(m_run[r] - mnew);
      m_run[r] = mnew;
      l_run[r] *= alpha;
      #pragma unroll
      for (int c = 0; c < 4; c++) o[c][r] *= alpha;
    }
    float psum[4] = {0.f, 0.f, 0.f, 0.f};
    #pragma unroll
    for (int c = 0; c < 4; c++)
      #pragma unroll
      for (int r = 0; r < 4; r++){
        float pv = __expf(p[c][r] - m_run[r]);
        p[c][r] = pv;
        psum[r] += pv;
      }
    #pragma unroll
    for (int r = 0; r < 4; r++){
      float vs = psum[r];
      #pragma unroll
      for (int off = 1; off < 16; off <<= 1) vs += __shfl_xor(vs, off, 64);
      l_run[r] += vs;
    }
    // ---- P: C-layout -> A-layout via per-wave LDS (wave-synchronous) ----
    #pragma unroll
    for (int c = 0; c < 4; c++)
      #pragma unroll
      for (int r = 0; r < 4; r++)
        pb[(quad * 4 + r) * 72 + 16 * c + lcol] = f2bf(p[c][r]);
    bf16x8 pa0 = *(const bf16x8*)(&pb[lcol * 72 + quad * 8]);
    bf16x8 pa1 = *(const bf16x8*)(&pb[lcol * 72 + 32 + quad * 8]);
    // ---- O += P . V  (V pre-transposed per head: dot-of-rows pattern) ----
    #pragma unroll
    for (int c = 0; c < 4; c++){
      const short* vtp = vT + (vt_base + c * 16 + lcol) * (size_t)SS + s0 + quad * 8;
      bf16x8 bv0 = *(const bf16x8*)(vtp);
      bf16x8 bv1 = *(const bf16x8*)(vtp + 32);
      o[c] = __builtin_amdgcn_mfma_f32_16x16x32_bf16(pa0, bv0, o[c], 0, 0, 0);
      o[c] = __builtin_amdgcn_mfma_f32_16x16x32_bf16(pa1, bv1, o[c], 0, 0, 0);
    }
  }

  // ---- merge the 4 per-wave partial states ----
  __syncthreads();  // all waves done with pbuf region before sO overwrites it
  float* sO = (float*)smem;                       // [4][16][68]
  float* sM = (float*)(smem + 4 * 16 * 68 * 4);   // [4][16]
  float* sL = sM + 64;                            // [4][16]
  #pragma unroll
  for (int c = 0; c < 4; c++)
    #pragma unroll
    for (int r = 0; r < 4; r++)
      sO[(wave * 16 + quad * 4 + r) * 68 + c * 16 + lcol] = o[c][r];
  if (lcol == 0){
    #pragma unroll
    for (int r = 0; r < 4; r++){
      sM[wave * 16 + quad * 4 + r] = m_run[r];
      sL[wave * 16 + quad * 4 + r] = l_run[r];
    }
  }
  __syncthreads();
  // wave w combines + writes column group w (16 cols)
  const int cg = wave;
  #pragma unroll
  for (int r = 0; r < 4; r++){
    const int row = quad * 4 + r;
    float m0 = sM[row], m1 = sM[16 + row], m2 = sM[32 + row], m3 = sM[48 + row];
    float ms = fmaxf(fmaxf(m0, m1), fmaxf(m2, m3));
    float e0 = __expf(m0 - ms), e1 = __expf(m1 - ms), e2 = __expf(m2 - ms), e3 = __expf(m3 - ms);
    float L = sL[row] * e0 + sL[16 + row] * e1 + sL[32 + row] * e2 + sL[48 + row] * e3;
    const int col = cg * 16 + lcol;
    float O = sO[row * 68 + col] * e0 + sO[(16 + row) * 68 + col] * e1
            + sO[(32 + row) * 68 + col] * e2 + sO[(48 + row) * 68 + col] * e3;
    attn_out[(size_t)(b * TT + t16 + row) * 1024 + n * 64 + col] = f2bf(O / L);
  }
}

// ---------------- launcher ----------------
extern "C" void kernel_launch(void* const* d_in, const int* in_sizes, int n_in,
                              void* d_out, int out_size, void* d_ws, size_t ws_size,
                              hipStream_t stream){
  const float* x      = (const float*)d_in[0];
  const float* rel    = (const float*)d_in[1];
  const float* memory = (const float*)d_in[2];
  const int*   episode_idx = (const int*)d_in[3];
  const int*   dones  = (const int*)d_in[4];
  const float* Wq  = (const float*)d_in[5];
  const float* Wk  = (const float*)d_in[6];
  const float* Wv  = (const float*)d_in[7];
  const float* Wr  = (const float*)d_in[8];
  const float* u   = (const float*)d_in[9];
  const float* v   = (const float*)d_in[10];
  const float* Wout  = (const float*)d_in[11];
  const float* b_out = (const float*)d_in[12];
  float* out = (float*)d_out;

  char* ws = (char*)d_ws;
  size_t off = 0;
  auto alloc = [&](size_t bytes) -> char* {
    char* p = ws + off;
    off += (bytes + 255) & ~(size_t)255;
    return p;
  };
  short* x_bf   = (short*)alloc((size_t)NB * TT * FF * 2);
  short* kv_bf  = (short*)alloc((size_t)NB * SS * FF * 2);
  short* rel_bf = (short*)alloc((size_t)SS * FF * 2);
  short* WqT    = (short*)alloc((size_t)FF * 1024 * 2);
  short* WkT    = (short*)alloc((size_t)FF * 1024 * 2);
  short* WvT    = (short*)alloc((size_t)FF * 1024 * 2);
  short* WrT    = (short*)alloc((size_t)FF * 1024 * 2);
  short* WoT    = (short*)alloc((size_t)FF * 1024 * 2);
  short* qu     = (short*)alloc((size_t)NB * TT * 1024 * 2);
  short* qv     = (short*)alloc((size_t)NB * TT * 1024 * 2);
  short* kbf    = (short*)alloc((size_t)NB * SS * 1024 * 2);
  short* vTb    = (short*)alloc((size_t)NB * SS * 1024 * 2);
  short* rbf    = (short*)alloc((size_t)SS * 1024 * 2);
  short* BD     = (short*)alloc((size_t)NB * NHD * TT * SS * 2);   // 128 MB
  int*   ki     = (int*)  alloc((size_t)NB * SS * 4);
  short* attn   = (short*)alloc((size_t)NB * TT * 1024 * 2);
  (void)ws_size; (void)in_sizes; (void)n_in; (void)out_size;

  // pack
  cast_kernel<<<(NB*TT*FF/4 + 255)/256, 256, 0, stream>>>(x, x_bf, NB*TT*FF/4);
  cast_kernel<<<(SS*FF/4 + 255)/256, 256, 0, stream>>>(rel, rel_bf, SS*FF/4);
  build_kv<<<(NB*SS*FF/4)/256, 256, 0, stream>>>(memory, x, kv_bf);
  dim3 tb(32, 8), tg(32, 32);
  transpose_cast<<<tg, tb, 0, stream>>>(Wq, WqT);
  transpose_cast<<<tg, tb, 0, stream>>>(Wk, WkT);
  transpose_cast<<<tg, tb, 0, stream>>>(Wv, WvT);
  transpose_cast<<<tg, tb, 0, stream>>>(Wr, WrT);
  transpose_cast<<<tg, tb, 0, stream>>>(Wout, WoT);
  scan_kernel<<<NB, TT, 0, stream>>>(episode_idx, dones, ki);

  // fused projections: z=0 K, z=1 V(transposed), z=2 Q(dual +u/+v), z=3 R
  proj_gemm<<<dim3(32, 8, 4), 256, 0, stream>>>(kv_bf, x_bf, rel_bf,
                                                WkT, WvT, WqT, WrT,
                                                kbf, vTb, qu, qv, rbf, u, v);

  // relative-position bias table
  bd_gemm<<<dim3(32, 16, 32), 256, 0, stream>>>(qv, rbf, BD);

  // attention (split-K across the 4 waves of each block)
  attn_kernel<<<2048, 256, 0, stream>>>(qu, BD, kbf, vTb, ki, attn);

  // output projection
  out_gemm<<<dim3(16, 8), 256, 0, stream>>>(attn, WoT, b_out, out);
}

// Round 5
// 389.955 us; speedup vs baseline: 1.9183x; 1.1935x over previous
//
#include <hip/hip_runtime.h>
#include <cstdint>
#include <cstddef>

// Problem constants
#define NB 2
#define TT 1024
#define MMEM 1024
#define SS 2048   // M + T
#define FF 1024
#define NHD 16    // heads
#define HD 64     // head dim

typedef __attribute__((ext_vector_type(8))) short bf16x8;
typedef __attribute__((ext_vector_type(4))) float f32x4;

__device__ __forceinline__ float bf2f(short s){
  unsigned u = ((unsigned)(unsigned short)s) << 16;
  float f; __builtin_memcpy(&f, &u, 4); return f;
}
__device__ __forceinline__ short f2bf(float f){
  unsigned u; __builtin_memcpy(&u, &f, 4);
  u += 0x7fffu + ((u >> 16) & 1u);   // RNE
  return (short)(u >> 16);
}

// async global->LDS, 16 B per lane; LDS dest = wave-uniform base + lane*16
typedef const __attribute__((address_space(1))) void gv_t;
typedef __attribute__((address_space(3))) void lv_t;
__device__ __forceinline__ void stage16(const void* g, void* l){
  __builtin_amdgcn_global_load_lds((gv_t*)g, (lv_t*)l, 16, 0, 0);
}

// ---------------- pack / cast kernels ----------------

__global__ void cast_kernel(const float* __restrict__ in, short* __restrict__ out, int n4){
  int i = blockIdx.x * blockDim.x + threadIdx.x;
  if (i >= n4) return;
  float4 v = ((const float4*)in)[i];
  short4 o; o.x = f2bf(v.x); o.y = f2bf(v.y); o.z = f2bf(v.z); o.w = f2bf(v.w);
  ((short4*)out)[i] = o;
}

// kv_in = concat(memory, x) along seq, cast to bf16. layout [B*SS, FF]
__global__ void build_kv(const float* __restrict__ mem, const float* __restrict__ x,
                         short* __restrict__ out){
  int i = blockIdx.x * blockDim.x + threadIdx.x;  // element/4 index
  int idx = i * 4;
  int row = idx >> 10;          // b*SS + s
  int col = idx & 1023;
  int b = row >> 11, s = row & 2047;
  const float* src = (s < MMEM) ? (mem + ((size_t)b*MMEM + s)*FF + col)
                                : (x   + ((size_t)b*TT + (s - MMEM))*FF + col);
  float4 v = *(const float4*)src;
  short4 o; o.x = f2bf(v.x); o.y = f2bf(v.y); o.z = f2bf(v.z); o.w = f2bf(v.w);
  ((short4*)out)[i] = o;
}

// out[c][r] = in[r][c], 1024x1024, f32 -> bf16
__global__ void transpose_cast(const float* __restrict__ in, short* __restrict__ out){
  __shared__ float tile[32][33];
  int bx = blockIdx.x * 32, by = blockIdx.y * 32;
  int tx = threadIdx.x, ty = threadIdx.y;
  for (int j = ty; j < 32; j += 8)
    tile[j][tx] = in[(size_t)(by + j)*1024 + bx + tx];
  __syncthreads();
  for (int j = ty; j < 32; j += 8)
    out[(size_t)(bx + j)*1024 + by + tx] = f2bf(tile[tx][j]);
}

// ki[b, 0:M] = episode_idx[b,:]; ki[b, M+t] = episode_idx[b,M-1] + cumsum(dones)[t]
__global__ void scan_kernel(const int* __restrict__ episode_idx, const int* __restrict__ dones,
                            int* __restrict__ ki){
  __shared__ int buf[TT];
  int b = blockIdx.x, t = threadIdx.x;
  buf[t] = dones[b*TT + t];
  __syncthreads();
  for (int off = 1; off < TT; off <<= 1){
    int v = (t >= off) ? buf[t - off] : 0;
    __syncthreads();
    buf[t] += v;
    __syncthreads();
  }
  int base = episode_idx[b*MMEM + (MMEM - 1)];
  ki[b*SS + t] = episode_idx[b*MMEM + t];
  ki[b*SS + MMEM + t] = base + buf[t];
}

// ---------------- m97-style 128x128 GEMM core (K=1024, BK=32) ----------------
// C[i,j] = sum_k A[i,k] * BT[j,k]; A,BT row-major bf16.
// 4 waves in 2x2; each wave owns a 64x64 quadrant (4x4 frags of 16x16x32 MFMA).
// Staging: global_load_lds 16B/lane; LDS tiles As/Bs [128][32] contiguous
// (no padding — global_load_lds dest is wave-uniform base + lane*16).
__device__ __forceinline__ void gemm128_core(const short* __restrict__ A,
                                             const short* __restrict__ BT,
                                             int row0, int col0,
                                             short* As, short* Bs,
                                             f32x4 (&acc)[4][4]){
  const int lane = threadIdx.x & 63, wv = threadIdx.x >> 6;
  const int lcol = lane & 15, quad = lane >> 4;
  const int wr = (wv >> 1) * 64, wc = (wv & 1) * 64;

  #pragma unroll
  for (int r = 0; r < 4; r++)
    #pragma unroll
    for (int c = 0; c < 4; c++) acc[r][c] = (f32x4){0.f, 0.f, 0.f, 0.f};

  // per-lane global srcs: seg = wv (+4); row = seg*16 + lane/4; col bytes (lane&3)*16
  const short* gA = A  + (size_t)(row0 + wv*16 + (lane>>2)) * 1024 + (lane&3)*8;
  const short* gB = BT + (size_t)(col0 + wv*16 + (lane>>2)) * 1024 + (lane&3)*8;
  short* lA0 = As + wv*512;  short* lA1 = As + (wv+4)*512;
  short* lB0 = Bs + wv*512;  short* lB1 = Bs + (wv+4)*512;

  for (int k0 = 0; k0 < 1024; k0 += 32){
    __syncthreads();                       // prev iter's ds_reads done
    stage16(gA + k0,            lA0);
    stage16(gA + 64*1024 + k0,  lA1);
    stage16(gB + k0,            lB0);
    stage16(gB + 64*1024 + k0,  lB1);
    __syncthreads();                       // drains vmcnt(0) -> LDS tiles ready
    bf16x8 af[4], bfr[4];
    #pragma unroll
    for (int r = 0; r < 4; r++)
      af[r] = *(const bf16x8*)&As[(wr + r*16 + lcol)*32 + quad*8];
    #pragma unroll
    for (int c = 0; c < 4; c++)
      bfr[c] = *(const bf16x8*)&Bs[(wc + c*16 + lcol)*32 + quad*8];
    #pragma unroll
    for (int c = 0; c < 4; c++)
      #pragma unroll
      for (int r = 0; r < 4; r++)
        acc[r][c] = __builtin_amdgcn_mfma_f32_16x16x32_bf16(af[r], bfr[c], acc[r][c], 0, 0, 0);
  }
}

// Fused projection GEMM: blockIdx.z selects job (keeps ~3 blocks/CU resident):
//   z=0: kbf = kv @ WkT        (4096 rows)
//   z=1: vT  = kv @ WvT, stored per-head transposed  (4096 rows)
//   z=2: qu/qv = x @ WqT + u/v (2048 rows; bx<16)
//   z=3: rbf = rel @ WrT       (2048 rows; bx<16)
__global__ __launch_bounds__(256) void proj_gemm(
    const short* __restrict__ kv, const short* __restrict__ xb,
    const short* __restrict__ relb,
    const short* __restrict__ WkT, const short* __restrict__ WvT,
    const short* __restrict__ WqT, const short* __restrict__ WrT,
    short* __restrict__ kbf, short* __restrict__ vT,
    short* __restrict__ qu, short* __restrict__ qv,
    short* __restrict__ rbf,
    const float* __restrict__ ubias, const float* __restrict__ vbias){
  const int z = blockIdx.z;
  const int bx = blockIdx.x;
  const short* A; const short* BT;
  if (z == 0){ A = kv; BT = WkT; }
  else if (z == 1){ A = kv; BT = WvT; }
  else if (z == 2){ if (bx >= 16) return; A = xb; BT = WqT; }
  else { if (bx >= 16) return; A = relb; BT = WrT; }
  const int row0 = bx * 128, col0 = blockIdx.y * 128;

  __shared__ __align__(16) short As[128*32];
  __shared__ __align__(16) short Bs[128*32];
  f32x4 acc[4][4];
  gemm128_core(A, BT, row0, col0, As, Bs, acc);

  const int lane = threadIdx.x & 63, wv = threadIdx.x >> 6;
  const int lcol = lane & 15, quad = lane >> 4;
  const int wr = (wv >> 1) * 64, wc = (wv & 1) * 64;
  #pragma unroll
  for (int c = 0; c < 4; c++){
    const int cc = col0 + wc + c*16 + lcol;
    #pragma unroll
    for (int r = 0; r < 4; r++){
      #pragma unroll
      for (int ri = 0; ri < 4; ri++){
        const int rr = row0 + wr + r*16 + quad*4 + ri;
        float val = acc[r][c][ri];
        if (z == 0){
          kbf[(size_t)rr * 1024 + cc] = f2bf(val);
        } else if (z == 1){
          int b = rr >> 11, s = rr & 2047;
          vT[(size_t)(((b << 4) + (cc >> 6)) * 64 + (cc & 63)) * 2048 + s] = f2bf(val);
        } else if (z == 2){
          qu[(size_t)rr * 1024 + cc] = f2bf(val + ubias[cc]);
          qv[(size_t)rr * 1024 + cc] = f2bf(val + vbias[cc]);
        } else {
          rbf[(size_t)rr * 1024 + cc] = f2bf(val);
        }
      }
    }
  }
}

// Output projection: out = attn @ WoT + b_out (f32 out, 2048 rows)
__global__ __launch_bounds__(256) void out_gemm(const short* __restrict__ A,
                                                const short* __restrict__ BT,
                                                const float* __restrict__ bias,
                                                float* __restrict__ C){
  const int row0 = blockIdx.x * 128, col0 = blockIdx.y * 128;
  __shared__ __align__(16) short As[128*32];
  __shared__ __align__(16) short Bs[128*32];
  f32x4 acc[4][4];
  gemm128_core(A, BT, row0, col0, As, Bs, acc);

  const int lane = threadIdx.x & 63, wv = threadIdx.x >> 6;
  const int lcol = lane & 15, quad = lane >> 4;
  const int wr = (wv >> 1) * 64, wc = (wv & 1) * 64;
  #pragma unroll
  for (int c = 0; c < 4; c++){
    const int cc = col0 + wc + c*16 + lcol;
    const float bb = bias[cc];
    #pragma unroll
    for (int r = 0; r < 4; r++)
      #pragma unroll
      for (int ri = 0; ri < 4; ri++){
        const int rr = row0 + wr + r*16 + quad*4 + ri;
        C[(size_t)rr * 1024 + cc] = acc[r][c][ri] + bb;
      }
  }
}

// ---------------- flash attention, split-K across waves, fused rel-bias ------
// grid: 2048 = B * N * (T/16). Block = 4 waves; all waves share the same 16
// query rows; wave w processes k-tiles w, w+4, w+8, ... with private online
// softmax state; states merge through LDS at the end (softmax-merge).
//
// Rel-pos bias computed IN-KERNEL (no 128 MB BD table): for the 16x64 logit
// tile, bd[t][s] = qv[t]·rbf[s-t+1023]. Needed rbf rows span an 80-row window
// [j0, j0+79], j0 = s0-t16+1008. Compute D[t][j] = qv[t]·rbf[j0+j] via 5
// chunk-MFMAs (L2-resident rbf), then shift per-row via __shfl:
//   j = 16c + lcol + 15 - rt  ->  chunk c+(off>>4), src lane quad*16+(off&15).
// rbf row index clamped to 2047: clamped rows feed only causally-masked
// entries (m>2047 <=> s>t+M, masked to -1e30 before rowmax).
// NOTE: plain __launch_bounds__(256) — (256,8) capped VGPR at 32 and spilled
// ~300 MB/dispatch (R2). Watch WRITE_SIZE ~4 MB as the spill tripwire.
__global__ __launch_bounds__(256) void attn_kernel(const short* __restrict__ qu,
                            const short* __restrict__ qv,
                            const short* __restrict__ rbf,
                            const short* __restrict__ kk, const short* __restrict__ vT,
                            const int* __restrict__ ki, short* __restrict__ attn_out){
  const int blk = blockIdx.x;
  const int t16 = (blk & 63) * 16;
  const int n = (blk >> 6) & 15;
  const int b = blk >> 10;
  const int wave = threadIdx.x >> 6, lane = threadIdx.x & 63;
  const int quad = lane >> 4, lcol = lane & 15;

  // union LDS: phase 1 = per-wave P tiles (4*16*72*2 = 9216 B)
  //            phase 2 = partial O (4*16*68*4 = 17408 B) + m,l (512 B)
  __shared__ __align__(16) char smem[17920];
  short* pb = (short*)smem + wave * (16 * 72);

  const short* qp = qu + (size_t)(b * TT + t16 + lcol) * 1024 + n * 64 + quad * 8;
  bf16x8 aq0 = *(const bf16x8*)(qp);
  bf16x8 aq1 = *(const bf16x8*)(qp + 32);
  const short* qvp = qv + (size_t)(b * TT + t16 + lcol) * 1024 + n * 64 + quad * 8;
  bf16x8 av0 = *(const bf16x8*)(qvp);
  bf16x8 av1 = *(const bf16x8*)(qvp + 32);

  int trow[4], qi_r[4], sl[4];
  bool hi[4];
  #pragma unroll
  for (int r = 0; r < 4; r++){
    trow[r] = t16 + quad * 4 + r;
    qi_r[r] = ki[b * SS + MMEM + trow[r]];
    const int rt = quad * 4 + r;
    const int off = lcol + 15 - rt;
    sl[r] = quad * 16 + (off & 15);
    hi[r] = off >= 16;
  }

  float m_run[4], l_run[4];
  f32x4 o[4];
  #pragma unroll
  for (int r = 0; r < 4; r++){ m_run[r] = -1e30f; l_run[r] = 0.f; }
  #pragma unroll
  for (int c = 0; c < 4; c++) o[c] = (f32x4){0.f, 0.f, 0.f, 0.f};

  const float scale = 0.125f;
  const size_t vt_base = (size_t)((b * NHD + n) * HD);
  const short* rb_head = rbf + n * 64;

  const int ntiles = ((t16 + 1039) >> 6) + 1;   // covers s <= t + M for all 16 rows
  for (int kt = wave; kt < ntiles; kt += 4){
    const int s0 = kt * 64;
    // ---- S = Qu . K^T ----
    f32x4 sacc[4];
    #pragma unroll
    for (int c = 0; c < 4; c++){
      const short* kp = kk + (size_t)(b * SS + s0 + 16 * c + lcol) * 1024 + n * 64 + quad * 8;
      bf16x8 b0 = *(const bf16x8*)(kp);
      bf16x8 b1 = *(const bf16x8*)(kp + 32);
      f32x4 z = (f32x4){0.f, 0.f, 0.f, 0.f};
      z = __builtin_amdgcn_mfma_f32_16x16x32_bf16(aq0, b0, z, 0, 0, 0);
      z = __builtin_amdgcn_mfma_f32_16x16x32_bf16(aq1, b1, z, 0, 0, 0);
      sacc[c] = z;
    }
    int ki_c[4];
    #pragma unroll
    for (int c = 0; c < 4; c++) ki_c[c] = ki[b * SS + s0 + 16 * c + lcol];

    // ---- D = Qv . R^T over the 80-row window ----
    const int j0 = s0 - t16 + 1008;   // >= 0 always
    f32x4 Dw[5];
    #pragma unroll
    for (int c5 = 0; c5 < 5; c5++){
      int jr = j0 + 16 * c5 + lcol;
      jr = (jr > SS - 1) ? (SS - 1) : jr;   // clamped rows are causally masked
      const short* rp = rb_head + (size_t)jr * 1024 + quad * 8;
      bf16x8 r0 = *(const bf16x8*)(rp);
      bf16x8 r1 = *(const bf16x8*)(rp + 32);
      f32x4 z = (f32x4){0.f, 0.f, 0.f, 0.f};
      z = __builtin_amdgcn_mfma_f32_16x16x32_bf16(av0, r0, z, 0, 0, 0);
      z = __builtin_amdgcn_mfma_f32_16x16x32_bf16(av1, r1, z, 0, 0, 0);
      Dw[c5] = z;
    }

    // ---- bias shift (Toeplitz) + mask + logits ----
    float p[4][4];
    float rowmax[4];
    #pragma unroll
    for (int r = 0; r < 4; r++) rowmax[r] = -1e30f;
    #pragma unroll
    for (int c = 0; c < 4; c++){
      const int s = s0 + 16 * c + lcol;
      #pragma unroll
      for (int r = 0; r < 4; r++){
        const float v0 = __shfl(Dw[c][r], sl[r], 64);
        const float v1 = __shfl(Dw[c + 1][r], sl[r], 64);
        const float bd = hi[r] ? v1 : v0;
        float lg = (sacc[c][r] + bd) * scale;
        const bool valid = (s <= trow[r] + MMEM) && (ki_c[c] == qi_r[r]);
        lg = valid ? lg : -1e30f;
        p[c][r] = lg;
        rowmax[r] = fmaxf(rowmax[r], lg);
      }
    }
    // ---- online softmax (per-wave private state) ----
    #pragma unroll
    for (int r = 0; r < 4; r++){
      float vmx = rowmax[r];
      #pragma unroll
      for (int off = 1; off < 16; off <<= 1) vmx = fmaxf(vmx, __shfl_xor(vmx, off, 64));
      float mnew = fmaxf(m_run[r], vmx);
      float alpha = __expf(m_run[r] - mnew);
      m_run[r] = mnew;
      l_run[r] *= alpha;
      #pragma unroll
      for (int c = 0; c < 4; c++) o[c][r] *= alpha;
    }
    float psum[4] = {0.f, 0.f, 0.f, 0.f};
    #pragma unroll
    for (int c = 0; c < 4; c++)
      #pragma unroll
      for (int r = 0; r < 4; r++){
        float pv = __expf(p[c][r] - m_run[r]);
        p[c][r] = pv;
        psum[r] += pv;
      }
    #pragma unroll
    for (int r = 0; r < 4; r++){
      float vs = psum[r];
      #pragma unroll
      for (int off = 1; off < 16; off <<= 1) vs += __shfl_xor(vs, off, 64);
      l_run[r] += vs;
    }
    // ---- P: C-layout -> A-layout via per-wave LDS (wave-synchronous) ----
    #pragma unroll
    for (int c = 0; c < 4; c++)
      #pragma unroll
      for (int r = 0; r < 4; r++)
        pb[(quad * 4 + r) * 72 + 16 * c + lcol] = f2bf(p[c][r]);
    bf16x8 pa0 = *(const bf16x8*)(&pb[lcol * 72 + quad * 8]);
    bf16x8 pa1 = *(const bf16x8*)(&pb[lcol * 72 + 32 + quad * 8]);
    // ---- O += P . V  (V pre-transposed per head: dot-of-rows pattern) ----
    #pragma unroll
    for (int c = 0; c < 4; c++){
      const short* vtp = vT + (vt_base + c * 16 + lcol) * (size_t)SS + s0 + quad * 8;
      bf16x8 bv0 = *(const bf16x8*)(vtp);
      bf16x8 bv1 = *(const bf16x8*)(vtp + 32);
      o[c] = __builtin_amdgcn_mfma_f32_16x16x32_bf16(pa0, bv0, o[c], 0, 0, 0);
      o[c] = __builtin_amdgcn_mfma_f32_16x16x32_bf16(pa1, bv1, o[c], 0, 0, 0);
    }
  }

  // ---- merge the 4 per-wave partial states ----
  __syncthreads();  // all waves done with pbuf region before sO overwrites it
  float* sO = (float*)smem;                       // [4][16][68]
  float* sM = (float*)(smem + 4 * 16 * 68 * 4);   // [4][16]
  float* sL = sM + 64;                            // [4][16]
  #pragma unroll
  for (int c = 0; c < 4; c++)
    #pragma unroll
    for (int r = 0; r < 4; r++)
      sO[(wave * 16 + quad * 4 + r) * 68 + c * 16 + lcol] = o[c][r];
  if (lcol == 0){
    #pragma unroll
    for (int r = 0; r < 4; r++){
      sM[wave * 16 + quad * 4 + r] = m_run[r];
      sL[wave * 16 + quad * 4 + r] = l_run[r];
    }
  }
  __syncthreads();
  // wave w combines + writes column group w (16 cols)
  const int cg = wave;
  #pragma unroll
  for (int r = 0; r < 4; r++){
    const int row = quad * 4 + r;
    float m0 = sM[row], m1 = sM[16 + row], m2 = sM[32 + row], m3 = sM[48 + row];
    float ms = fmaxf(fmaxf(m0, m1), fmaxf(m2, m3));
    float e0 = __expf(m0 - ms), e1 = __expf(m1 - ms), e2 = __expf(m2 - ms), e3 = __expf(m3 - ms);
    float L = sL[row] * e0 + sL[16 + row] * e1 + sL[32 + row] * e2 + sL[48 + row] * e3;
    const int col = cg * 16 + lcol;
    float O = sO[row * 68 + col] * e0 + sO[(16 + row) * 68 + col] * e1
            + sO[(32 + row) * 68 + col] * e2 + sO[(48 + row) * 68 + col] * e3;
    attn_out[(size_t)(b * TT + t16 + row) * 1024 + n * 64 + col] = f2bf(O / L);
  }
}

// ---------------- launcher ----------------
extern "C" void kernel_launch(void* const* d_in, const int* in_sizes, int n_in,
                              void* d_out, int out_size, void* d_ws, size_t ws_size,
                              hipStream_t stream){
  const float* x      = (const float*)d_in[0];
  const float* rel    = (const float*)d_in[1];
  const float* memory = (const float*)d_in[2];
  const int*   episode_idx = (const int*)d_in[3];
  const int*   dones  = (const int*)d_in[4];
  const float* Wq  = (const float*)d_in[5];
  const float* Wk  = (const float*)d_in[6];
  const float* Wv  = (const float*)d_in[7];
  const float* Wr  = (const float*)d_in[8];
  const float* u   = (const float*)d_in[9];
  const float* v   = (const float*)d_in[10];
  const float* Wout  = (const float*)d_in[11];
  const float* b_out = (const float*)d_in[12];
  float* out = (float*)d_out;

  char* ws = (char*)d_ws;
  size_t off = 0;
  auto alloc = [&](size_t bytes) -> char* {
    char* p = ws + off;
    off += (bytes + 255) & ~(size_t)255;
    return p;
  };
  short* x_bf   = (short*)alloc((size_t)NB * TT * FF * 2);
  short* kv_bf  = (short*)alloc((size_t)NB * SS * FF * 2);
  short* rel_bf = (short*)alloc((size_t)SS * FF * 2);
  short* WqT    = (short*)alloc((size_t)FF * 1024 * 2);
  short* WkT    = (short*)alloc((size_t)FF * 1024 * 2);
  short* WvT    = (short*)alloc((size_t)FF * 1024 * 2);
  short* WrT    = (short*)alloc((size_t)FF * 1024 * 2);
  short* WoT    = (short*)alloc((size_t)FF * 1024 * 2);
  short* qu     = (short*)alloc((size_t)NB * TT * 1024 * 2);
  short* qv     = (short*)alloc((size_t)NB * TT * 1024 * 2);
  short* kbf    = (short*)alloc((size_t)NB * SS * 1024 * 2);
  short* vTb    = (short*)alloc((size_t)NB * SS * 1024 * 2);
  short* rbf    = (short*)alloc((size_t)SS * 1024 * 2);
  int*   ki     = (int*)  alloc((size_t)NB * SS * 4);
  short* attn   = (short*)alloc((size_t)NB * TT * 1024 * 2);
  (void)ws_size; (void)in_sizes; (void)n_in; (void)out_size;

  // pack
  cast_kernel<<<(NB*TT*FF/4 + 255)/256, 256, 0, stream>>>(x, x_bf, NB*TT*FF/4);
  cast_kernel<<<(SS*FF/4 + 255)/256, 256, 0, stream>>>(rel, rel_bf, SS*FF/4);
  build_kv<<<(NB*SS*FF/4)/256, 256, 0, stream>>>(memory, x, kv_bf);
  dim3 tb(32, 8), tg(32, 32);
  transpose_cast<<<tg, tb, 0, stream>>>(Wq, WqT);
  transpose_cast<<<tg, tb, 0, stream>>>(Wk, WkT);
  transpose_cast<<<tg, tb, 0, stream>>>(Wv, WvT);
  transpose_cast<<<tg, tb, 0, stream>>>(Wr, WrT);
  transpose_cast<<<tg, tb, 0, stream>>>(Wout, WoT);
  scan_kernel<<<NB, TT, 0, stream>>>(episode_idx, dones, ki);

  // fused projections: z=0 K, z=1 V(transposed), z=2 Q(dual +u/+v), z=3 R
  proj_gemm<<<dim3(32, 8, 4), 256, 0, stream>>>(kv_bf, x_bf, rel_bf,
                                                WkT, WvT, WqT, WrT,
                                                kbf, vTb, qu, qv, rbf, u, v);

  // attention (split-K across the 4 waves of each block; rel-bias fused)
  attn_kernel<<<2048, 256, 0, stream>>>(qu, qv, rbf, kbf, vTb, ki, attn);

  // output projection
  out_gemm<<<dim3(16, 8), 256, 0, stream>>>(attn, WoT, b_out, out);
}

// Round 6
// 373.413 us; speedup vs baseline: 2.0033x; 1.0443x over previous
//
#include <hip/hip_runtime.h>
#include <cstdint>
#include <cstddef>

// Problem constants
#define NB 2
#define TT 1024
#define MMEM 1024
#define SS 2048   // M + T
#define FF 1024
#define NHD 16    // heads
#define HD 64     // head dim

typedef __attribute__((ext_vector_type(8))) short bf16x8;
typedef __attribute__((ext_vector_type(4))) float f32x4;

__device__ __forceinline__ float bf2f(short s){
  unsigned u = ((unsigned)(unsigned short)s) << 16;
  float f; __builtin_memcpy(&f, &u, 4); return f;
}
__device__ __forceinline__ short f2bf(float f){
  unsigned u; __builtin_memcpy(&u, &f, 4);
  u += 0x7fffu + ((u >> 16) & 1u);   // RNE
  return (short)(u >> 16);
}

// async global->LDS, 16 B per lane; LDS dest = wave-uniform base + lane*16
typedef const __attribute__((address_space(1))) void gv_t;
typedef __attribute__((address_space(3))) void lv_t;
__device__ __forceinline__ void stage16(const void* g, void* l){
  __builtin_amdgcn_global_load_lds((gv_t*)g, (lv_t*)l, 16, 0, 0);
}

// ---------------- pack / cast kernels ----------------

__global__ void cast_kernel(const float* __restrict__ in, short* __restrict__ out, int n4){
  int i = blockIdx.x * blockDim.x + threadIdx.x;
  if (i >= n4) return;
  float4 v = ((const float4*)in)[i];
  short4 o; o.x = f2bf(v.x); o.y = f2bf(v.y); o.z = f2bf(v.z); o.w = f2bf(v.w);
  ((short4*)out)[i] = o;
}

// kv_in = concat(memory, x) along seq, cast to bf16. layout [B*SS, FF]
__global__ void build_kv(const float* __restrict__ mem, const float* __restrict__ x,
                         short* __restrict__ out){
  int i = blockIdx.x * blockDim.x + threadIdx.x;  // element/4 index
  int idx = i * 4;
  int row = idx >> 10;          // b*SS + s
  int col = idx & 1023;
  int b = row >> 11, s = row & 2047;
  const float* src = (s < MMEM) ? (mem + ((size_t)b*MMEM + s)*FF + col)
                                : (x   + ((size_t)b*TT + (s - MMEM))*FF + col);
  float4 v = *(const float4*)src;
  short4 o; o.x = f2bf(v.x); o.y = f2bf(v.y); o.z = f2bf(v.z); o.w = f2bf(v.w);
  ((short4*)out)[i] = o;
}

// batched: out_z[c][r] = in_z[r][c], 1024x1024, f32 -> bf16
__global__ void transpose_cast5(const float* __restrict__ i0, const float* __restrict__ i1,
                                const float* __restrict__ i2, const float* __restrict__ i3,
                                const float* __restrict__ i4,
                                short* __restrict__ o0, short* __restrict__ o1,
                                short* __restrict__ o2, short* __restrict__ o3,
                                short* __restrict__ o4){
  const float* in; short* out;
  switch (blockIdx.z){
    case 0: in = i0; out = o0; break;
    case 1: in = i1; out = o1; break;
    case 2: in = i2; out = o2; break;
    case 3: in = i3; out = o3; break;
    default: in = i4; out = o4; break;
  }
  __shared__ float tile[32][33];
  int bx = blockIdx.x * 32, by = blockIdx.y * 32;
  int tx = threadIdx.x, ty = threadIdx.y;
  for (int j = ty; j < 32; j += 8)
    tile[j][tx] = in[(size_t)(by + j)*1024 + bx + tx];
  __syncthreads();
  for (int j = ty; j < 32; j += 8)
    out[(size_t)(bx + j)*1024 + by + tx] = f2bf(tile[tx][j]);
}

// ki[b, 0:M] = episode_idx[b,:]; ki[b, M+t] = episode_idx[b,M-1] + cumsum(dones)[t]
__global__ void scan_kernel(const int* __restrict__ episode_idx, const int* __restrict__ dones,
                            int* __restrict__ ki){
  __shared__ int buf[TT];
  int b = blockIdx.x, t = threadIdx.x;
  buf[t] = dones[b*TT + t];
  __syncthreads();
  for (int off = 1; off < TT; off <<= 1){
    int v = (t >= off) ? buf[t - off] : 0;
    __syncthreads();
    buf[t] += v;
    __syncthreads();
  }
  int base = episode_idx[b*MMEM + (MMEM - 1)];
  ki[b*SS + t] = episode_idx[b*MMEM + t];
  ki[b*SS + MMEM + t] = base + buf[t];
}

// uk[b,n,s] = sum_h u[n,h]*k[b,s,n,h];  vr[n,j] = sum_h v[n,h]*r[j,n,h]
// (bias folded out of the Q stream: (q+u)·k = q·k + uk, (q+v)·r = q·r + vr)
__global__ void bias_tables(const short* __restrict__ kbf, const short* __restrict__ rbf,
                            const float* __restrict__ u, const float* __restrict__ v,
                            float* __restrict__ uk, float* __restrict__ vr){
  int i = blockIdx.x * blockDim.x + threadIdx.x;
  if (i < NB * NHD * SS){
    int s = i & 2047, n = (i >> 11) & 15, b = i >> 15;
    const short* kp = kbf + (size_t)(b * SS + s) * 1024 + n * 64;
    const float* up = u + n * 64;
    float acc = 0.f;
    #pragma unroll 8
    for (int h = 0; h < 64; h++) acc += bf2f(kp[h]) * up[h];
    uk[(size_t)(b * NHD + n) * SS + s] = acc;
  } else {
    int j = i - NB * NHD * SS;
    if (j >= NHD * SS) return;
    int jj = j & 2047, n = j >> 11;
    const short* rp = rbf + (size_t)jj * 1024 + n * 64;
    const float* vp = v + n * 64;
    float acc = 0.f;
    #pragma unroll 8
    for (int h = 0; h < 64; h++) acc += bf2f(rp[h]) * vp[h];
    vr[(size_t)n * SS + jj] = acc;
  }
}

// ---------------- m97-style 128x128 GEMM core (K=1024, BK=32) ----------------
__device__ __forceinline__ void gemm128_core(const short* __restrict__ A,
                                             const short* __restrict__ BT,
                                             int row0, int col0,
                                             short* As, short* Bs,
                                             f32x4 (&acc)[4][4]){
  const int lane = threadIdx.x & 63, wv = threadIdx.x >> 6;
  const int lcol = lane & 15, quad = lane >> 4;
  const int wr = (wv >> 1) * 64, wc = (wv & 1) * 64;

  #pragma unroll
  for (int r = 0; r < 4; r++)
    #pragma unroll
    for (int c = 0; c < 4; c++) acc[r][c] = (f32x4){0.f, 0.f, 0.f, 0.f};

  const short* gA = A  + (size_t)(row0 + wv*16 + (lane>>2)) * 1024 + (lane&3)*8;
  const short* gB = BT + (size_t)(col0 + wv*16 + (lane>>2)) * 1024 + (lane&3)*8;
  short* lA0 = As + wv*512;  short* lA1 = As + (wv+4)*512;
  short* lB0 = Bs + wv*512;  short* lB1 = Bs + (wv+4)*512;

  for (int k0 = 0; k0 < 1024; k0 += 32){
    __syncthreads();
    stage16(gA + k0,            lA0);
    stage16(gA + 64*1024 + k0,  lA1);
    stage16(gB + k0,            lB0);
    stage16(gB + 64*1024 + k0,  lB1);
    __syncthreads();
    bf16x8 af[4], bfr[4];
    #pragma unroll
    for (int r = 0; r < 4; r++)
      af[r] = *(const bf16x8*)&As[(wr + r*16 + lcol)*32 + quad*8];
    #pragma unroll
    for (int c = 0; c < 4; c++)
      bfr[c] = *(const bf16x8*)&Bs[(wc + c*16 + lcol)*32 + quad*8];
    #pragma unroll
    for (int c = 0; c < 4; c++)
      #pragma unroll
      for (int r = 0; r < 4; r++)
        acc[r][c] = __builtin_amdgcn_mfma_f32_16x16x32_bf16(af[r], bfr[c], acc[r][c], 0, 0, 0);
  }
}

// Fused projection GEMM: blockIdx.z selects job:
//   z=0: kbf = kv @ WkT                      (4096 rows)
//   z=1: vT  = kv @ WvT, per-head transposed (4096 rows)
//   z=2: qb  = x @ WqT   (x read in-place from kv_bf rows [M..S); bx<16)
//   z=3: rbf = rel @ WrT (2048 rows; bx<16)
__global__ __launch_bounds__(256) void proj_gemm(
    const short* __restrict__ kv, const short* __restrict__ relb,
    const short* __restrict__ WkT, const short* __restrict__ WvT,
    const short* __restrict__ WqT, const short* __restrict__ WrT,
    short* __restrict__ kbf, short* __restrict__ vT,
    short* __restrict__ qb, short* __restrict__ rbf){
  const int z = blockIdx.z;
  const int bx = blockIdx.x;
  const short* A; const short* BT;
  int row0 = bx * 128, qbb = 0;
  if (z == 0){ A = kv; BT = WkT; }
  else if (z == 1){ A = kv; BT = WvT; }
  else if (z == 2){
    if (bx >= 16) return;
    qbb = bx >> 3;                       // batch
    A = kv + (size_t)(qbb * SS + MMEM) * 1024;   // x rows live inside kv
    row0 = (bx & 7) * 128;
    BT = WqT;
  }
  else { if (bx >= 16) return; A = relb; BT = WrT; }
  const int col0 = blockIdx.y * 128;

  __shared__ __align__(16) short As[128*32];
  __shared__ __align__(16) short Bs[128*32];
  f32x4 acc[4][4];
  gemm128_core(A, BT, row0, col0, As, Bs, acc);

  const int lane = threadIdx.x & 63, wv = threadIdx.x >> 6;
  const int lcol = lane & 15, quad = lane >> 4;
  const int wr = (wv >> 1) * 64, wc = (wv & 1) * 64;
  #pragma unroll
  for (int c = 0; c < 4; c++){
    const int cc = col0 + wc + c*16 + lcol;
    #pragma unroll
    for (int r = 0; r < 4; r++){
      #pragma unroll
      for (int ri = 0; ri < 4; ri++){
        const int rr = row0 + wr + r*16 + quad*4 + ri;
        float val = acc[r][c][ri];
        if (z == 0){
          kbf[(size_t)rr * 1024 + cc] = f2bf(val);
        } else if (z == 1){
          int b = rr >> 11, s = rr & 2047;
          vT[(size_t)(((b << 4) + (cc >> 6)) * 64 + (cc & 63)) * 2048 + s] = f2bf(val);
        } else if (z == 2){
          qb[((size_t)(qbb * TT) + rr) * 1024 + cc] = f2bf(val);
        } else {
          rbf[(size_t)rr * 1024 + cc] = f2bf(val);
        }
      }
    }
  }
}

// Output projection: out = attn @ WoT + b_out (f32 out, 2048 rows)
__global__ __launch_bounds__(256) void out_gemm(const short* __restrict__ A,
                                                const short* __restrict__ BT,
                                                const float* __restrict__ bias,
                                                float* __restrict__ C){
  const int row0 = blockIdx.x * 128, col0 = blockIdx.y * 128;
  __shared__ __align__(16) short As[128*32];
  __shared__ __align__(16) short Bs[128*32];
  f32x4 acc[4][4];
  gemm128_core(A, BT, row0, col0, As, Bs, acc);

  const int lane = threadIdx.x & 63, wv = threadIdx.x >> 6;
  const int lcol = lane & 15, quad = lane >> 4;
  const int wr = (wv >> 1) * 64, wc = (wv & 1) * 64;
  #pragma unroll
  for (int c = 0; c < 4; c++){
    const int cc = col0 + wc + c*16 + lcol;
    const float bb = bias[cc];
    #pragma unroll
    for (int r = 0; r < 4; r++)
      #pragma unroll
      for (int ri = 0; ri < 4; ri++){
        const int rr = row0 + wr + r*16 + quad*4 + ri;
        C[(size_t)rr * 1024 + cc] = acc[r][c][ri] + bb;
      }
  }
}

// ---------------- flash attention, split-K waves, fused rel-bias ------------
// grid 2048; XCD-aware swizzle: xcd = blk&7 owns 4 (b,n) groups so each XCD's
// L2 working set (K/V/R/Q slices ~3.6 MB) fits its private 4 MB L2 (R5 showed
// 103 MB HBM FETCH = cross-XCD L2 thrash).
// Bias: logits = (q·k + uk[s])*scale + shifted(q·r + vr[j])*scale, with
// uk/vr precomputed column tables (u,v folded out of the Q stream).
// NOTE: plain __launch_bounds__(256) — (256,8) capped VGPR at 32 and spilled
// ~300 MB/dispatch (R2). Watch WRITE_SIZE ~4 MB as the spill tripwire.
__global__ __launch_bounds__(256) void attn_kernel(const short* __restrict__ qb,
                            const short* __restrict__ rbf,
                            const short* __restrict__ kk, const short* __restrict__ vT,
                            const int* __restrict__ ki,
                            const float* __restrict__ uk, const float* __restrict__ vr,
                            short* __restrict__ attn_out){
  const int blk = blockIdx.x;
  const int xcd = blk & 7;
  const int idx = blk >> 3;                 // [0,256)
  const int bn  = (xcd << 2) | (idx >> 6);  // 4 (b,n) groups per XCD
  const int t16 = (idx & 63) * 16;
  const int n = bn & 15;
  const int b = bn >> 4;
  const int wave = threadIdx.x >> 6, lane = threadIdx.x & 63;
  const int quad = lane >> 4, lcol = lane & 15;

  // union LDS: phase 1 = per-wave P tiles (4*16*72*2 = 9216 B)
  //            phase 2 = partial O (4*16*68*4 = 17408 B) + m,l (512 B)
  __shared__ __align__(16) char smem[17920];
  short* pb = (short*)smem + wave * (16 * 72);

  const short* qp = qb + (size_t)(b * TT + t16 + lcol) * 1024 + n * 64 + quad * 8;
  bf16x8 aq0 = *(const bf16x8*)(qp);
  bf16x8 aq1 = *(const bf16x8*)(qp + 32);

  int trow[4], qi_r[4], sl[4];
  bool hi[4];
  #pragma unroll
  for (int r = 0; r < 4; r++){
    trow[r] = t16 + quad * 4 + r;
    qi_r[r] = ki[b * SS + MMEM + trow[r]];
    const int rt = quad * 4 + r;
    const int off = lcol + 15 - rt;
    sl[r] = quad * 16 + (off & 15);
    hi[r] = off >= 16;
  }

  float m_run[4], l_run[4];
  f32x4 o[4];
  #pragma unroll
  for (int r = 0; r < 4; r++){ m_run[r] = -1e30f; l_run[r] = 0.f; }
  #pragma unroll
  for (int c = 0; c < 4; c++) o[c] = (f32x4){0.f, 0.f, 0.f, 0.f};

  const float scale = 0.125f;
  const size_t vt_base = (size_t)((b * NHD + n) * HD);
  const short* rb_head = rbf + n * 64;
  const float* uk_row = uk + (size_t)(b * NHD + n) * SS;
  const float* vr_row = vr + (size_t)n * SS;

  const int ntiles = ((t16 + 1039) >> 6) + 1;   // covers s <= t + M for all 16 rows
  for (int kt = wave; kt < ntiles; kt += 4){
    const int s0 = kt * 64;
    // ---- S = Q . K^T  (+ uk column bias) ----
    f32x4 sacc[4];
    float ukc[4];
    #pragma unroll
    for (int c = 0; c < 4; c++){
      const short* kp = kk + (size_t)(b * SS + s0 + 16 * c + lcol) * 1024 + n * 64 + quad * 8;
      bf16x8 b0 = *(const bf16x8*)(kp);
      bf16x8 b1 = *(const bf16x8*)(kp + 32);
      f32x4 z = (f32x4){0.f, 0.f, 0.f, 0.f};
      z = __builtin_amdgcn_mfma_f32_16x16x32_bf16(aq0, b0, z, 0, 0, 0);
      z = __builtin_amdgcn_mfma_f32_16x16x32_bf16(aq1, b1, z, 0, 0, 0);
      sacc[c] = z;
      ukc[c] = uk_row[s0 + 16 * c + lcol];
    }
    int ki_c[4];
    #pragma unroll
    for (int c = 0; c < 4; c++) ki_c[c] = ki[b * SS + s0 + 16 * c + lcol];

    // ---- D = Q . R^T (+ vr column bias) over the 80-row window ----
    const int j0 = s0 - t16 + 1008;   // >= 0 always
    f32x4 Dw[5];
    #pragma unroll
    for (int c5 = 0; c5 < 5; c5++){
      int jr = j0 + 16 * c5 + lcol;
      jr = (jr > SS - 1) ? (SS - 1) : jr;   // clamped rows are causally masked
      const short* rp = rb_head + (size_t)jr * 1024 + quad * 8;
      bf16x8 r0 = *(const bf16x8*)(rp);
      bf16x8 r1 = *(const bf16x8*)(rp + 32);
      f32x4 z = (f32x4){0.f, 0.f, 0.f, 0.f};
      z = __builtin_amdgcn_mfma_f32_16x16x32_bf16(aq0, r0, z, 0, 0, 0);
      z = __builtin_amdgcn_mfma_f32_16x16x32_bf16(aq1, r1, z, 0, 0, 0);
      const float vrj = vr_row[jr];
      #pragma unroll
      for (int r = 0; r < 4; r++) z[r] += vrj;
      Dw[c5] = z;
    }

    // ---- bias shift (Toeplitz) + mask + logits ----
    float p[4][4];
    float rowmax[4];
    #pragma unroll
    for (int r = 0; r < 4; r++) rowmax[r] = -1e30f;
    #pragma unroll
    for (int c = 0; c < 4; c++){
      const int s = s0 + 16 * c + lcol;
      #pragma unroll
      for (int r = 0; r < 4; r++){
        const float v0 = __shfl(Dw[c][r], sl[r], 64);
        const float v1 = __shfl(Dw[c + 1][r], sl[r], 64);
        const float bd = hi[r] ? v1 : v0;
        float lg = (sacc[c][r] + ukc[c] + bd) * scale;
        const bool valid = (s <= trow[r] + MMEM) && (ki_c[c] == qi_r[r]);
        lg = valid ? lg : -1e30f;
        p[c][r] = lg;
        rowmax[r] = fmaxf(rowmax[r], lg);
      }
    }
    // ---- online softmax (per-wave private state) ----
    #pragma unroll
    for (int r = 0; r < 4; r++){
      float vmx = rowmax[r];
      #pragma unroll
      for (int off = 1; off < 16; off <<= 1) vmx = fmaxf(vmx, __shfl_xor(vmx, off, 64));
      float mnew = fmaxf(m_run[r], vmx);
      float alpha = __expf(m_run[r] - mnew);
      m_run[r] = mnew;
      l_run[r] *= alpha;
      #pragma unroll
      for (int c = 0; c < 4; c++) o[c][r] *= alpha;
    }
    float psum[4] = {0.f, 0.f, 0.f, 0.f};
    #pragma unroll
    for (int c = 0; c < 4; c++)
      #pragma unroll
      for (int r = 0; r < 4; r++){
        float pv = __expf(p[c][r] - m_run[r]);
        p[c][r] = pv;
        psum[r] += pv;
      }
    #pragma unroll
    for (int r = 0; r < 4; r++){
      float vs = psum[r];
      #pragma unroll
      for (int off = 1; off < 16; off <<= 1) vs += __shfl_xor(vs, off, 64);
      l_run[r] += vs;
    }
    // ---- P: C-layout -> A-layout via per-wave LDS (wave-synchronous) ----
    #pragma unroll
    for (int c = 0; c < 4; c++)
      #pragma unroll
      for (int r = 0; r < 4; r++)
        pb[(quad * 4 + r) * 72 + 16 * c + lcol] = f2bf(p[c][r]);
    bf16x8 pa0 = *(const bf16x8*)(&pb[lcol * 72 + quad * 8]);
    bf16x8 pa1 = *(const bf16x8*)(&pb[lcol * 72 + 32 + quad * 8]);
    // ---- O += P . V ----
    #pragma unroll
    for (int c = 0; c < 4; c++){
      const short* vtp = vT + (vt_base + c * 16 + lcol) * (size_t)SS + s0 + quad * 8;
      bf16x8 bv0 = *(const bf16x8*)(vtp);
      bf16x8 bv1 = *(const bf16x8*)(vtp + 32);
      o[c] = __builtin_amdgcn_mfma_f32_16x16x32_bf16(pa0, bv0, o[c], 0, 0, 0);
      o[c] = __builtin_amdgcn_mfma_f32_16x16x32_bf16(pa1, bv1, o[c], 0, 0, 0);
    }
  }

  // ---- merge the 4 per-wave partial states ----
  __syncthreads();
  float* sO = (float*)smem;                       // [4][16][68]
  float* sM = (float*)(smem + 4 * 16 * 68 * 4);   // [4][16]
  float* sL = sM + 64;                            // [4][16]
  #pragma unroll
  for (int c = 0; c < 4; c++)
    #pragma unroll
    for (int r = 0; r < 4; r++)
      sO[(wave * 16 + quad * 4 + r) * 68 + c * 16 + lcol] = o[c][r];
  if (lcol == 0){
    #pragma unroll
    for (int r = 0; r < 4; r++){
      sM[wave * 16 + quad * 4 + r] = m_run[r];
      sL[wave * 16 + quad * 4 + r] = l_run[r];
    }
  }
  __syncthreads();
  const int cg = wave;
  #pragma unroll
  for (int r = 0; r < 4; r++){
    const int row = quad * 4 + r;
    float m0 = sM[row], m1 = sM[16 + row], m2 = sM[32 + row], m3 = sM[48 + row];
    float ms = fmaxf(fmaxf(m0, m1), fmaxf(m2, m3));
    float e0 = __expf(m0 - ms), e1 = __expf(m1 - ms), e2 = __expf(m2 - ms), e3 = __expf(m3 - ms);
    float L = sL[row] * e0 + sL[16 + row] * e1 + sL[32 + row] * e2 + sL[48 + row] * e3;
    const int col = cg * 16 + lcol;
    float O = sO[row * 68 + col] * e0 + sO[(16 + row) * 68 + col] * e1
            + sO[(32 + row) * 68 + col] * e2 + sO[(48 + row) * 68 + col] * e3;
    attn_out[(size_t)(b * TT + t16 + row) * 1024 + n * 64 + col] = f2bf(O / L);
  }
}

// ---------------- launcher ----------------
extern "C" void kernel_launch(void* const* d_in, const int* in_sizes, int n_in,
                              void* d_out, int out_size, void* d_ws, size_t ws_size,
                              hipStream_t stream){
  const float* x      = (const float*)d_in[0];
  const float* rel    = (const float*)d_in[1];
  const float* memory = (const float*)d_in[2];
  const int*   episode_idx = (const int*)d_in[3];
  const int*   dones  = (const int*)d_in[4];
  const float* Wq  = (const float*)d_in[5];
  const float* Wk  = (const float*)d_in[6];
  const float* Wv  = (const float*)d_in[7];
  const float* Wr  = (const float*)d_in[8];
  const float* u   = (const float*)d_in[9];
  const float* v   = (const float*)d_in[10];
  const float* Wout  = (const float*)d_in[11];
  const float* b_out = (const float*)d_in[12];
  float* out = (float*)d_out;

  char* ws = (char*)d_ws;
  size_t off = 0;
  auto alloc = [&](size_t bytes) -> char* {
    char* p = ws + off;
    off += (bytes + 255) & ~(size_t)255;
    return p;
  };
  short* kv_bf  = (short*)alloc((size_t)NB * SS * FF * 2);
  short* rel_bf = (short*)alloc((size_t)SS * FF * 2);
  short* WqT    = (short*)alloc((size_t)FF * 1024 * 2);
  short* WkT    = (short*)alloc((size_t)FF * 1024 * 2);
  short* WvT    = (short*)alloc((size_t)FF * 1024 * 2);
  short* WrT    = (short*)alloc((size_t)FF * 1024 * 2);
  short* WoT    = (short*)alloc((size_t)FF * 1024 * 2);
  short* qbuf   = (short*)alloc((size_t)NB * TT * 1024 * 2);
  short* kbf    = (short*)alloc((size_t)NB * SS * 1024 * 2);
  short* vTb    = (short*)alloc((size_t)NB * SS * 1024 * 2);
  short* rbf    = (short*)alloc((size_t)SS * 1024 * 2);
  int*   ki     = (int*)  alloc((size_t)NB * SS * 4);
  float* ukT    = (float*)alloc((size_t)NB * NHD * SS * 4);
  float* vrT    = (float*)alloc((size_t)NHD * SS * 4);
  short* attn   = (short*)alloc((size_t)NB * TT * 1024 * 2);
  (void)ws_size; (void)in_sizes; (void)n_in; (void)out_size;

  // pack
  cast_kernel<<<(SS*FF/4 + 255)/256, 256, 0, stream>>>(rel, rel_bf, SS*FF/4);
  build_kv<<<(NB*SS*FF/4)/256, 256, 0, stream>>>(memory, x, kv_bf);
  dim3 tb(32, 8), tg5(32, 32, 5);
  transpose_cast5<<<tg5, tb, 0, stream>>>(Wq, Wk, Wv, Wr, Wout, WqT, WkT, WvT, WrT, WoT);
  scan_kernel<<<NB, TT, 0, stream>>>(episode_idx, dones, ki);

  // fused projections: z=0 K, z=1 V(transposed), z=2 Q (from kv rows), z=3 R
  proj_gemm<<<dim3(32, 8, 4), 256, 0, stream>>>(kv_bf, rel_bf,
                                                WkT, WvT, WqT, WrT,
                                                kbf, vTb, qbuf, rbf);

  // u·k / v·r column-bias tables
  bias_tables<<<(NB*NHD*SS + NHD*SS + 255)/256, 256, 0, stream>>>(kbf, rbf, u, v, ukT, vrT);

  // attention (split-K across waves; XCD-swizzled; rel-bias fused)
  attn_kernel<<<2048, 256, 0, stream>>>(qbuf, rbf, kbf, vTb, ki, ukT, vrT, attn);

  // output projection
  out_gemm<<<dim3(16, 8), 256, 0, stream>>>(attn, WoT, b_out, out);
}

// Round 7
// 241.924 us; speedup vs baseline: 3.0922x; 1.5435x over previous
//
#include <hip/hip_runtime.h>
#include <cstdint>
#include <cstddef>

// Problem constants
#define NB 2
#define TT 1024
#define MMEM 1024
#define SS 2048   // M + T
#define FF 1024
#define NHD 16    // heads
#define HD 64     // head dim

typedef __attribute__((ext_vector_type(8))) short bf16x8;
typedef __attribute__((ext_vector_type(4))) float f32x4;

__device__ __forceinline__ float bf2f(short s){
  unsigned u = ((unsigned)(unsigned short)s) << 16;
  float f; __builtin_memcpy(&f, &u, 4); return f;
}
__device__ __forceinline__ short f2bf(float f){
  unsigned u; __builtin_memcpy(&u, &f, 4);
  u += 0x7fffu + ((u >> 16) & 1u);   // RNE
  return (short)(u >> 16);
}

// async global->LDS, 16 B per lane; LDS dest = wave-uniform base + lane*16
typedef const __attribute__((address_space(1))) void gv_t;
typedef __attribute__((address_space(3))) void lv_t;
__device__ __forceinline__ void stage16(const void* g, void* l){
  __builtin_amdgcn_global_load_lds((gv_t*)g, (lv_t*)l, 16, 0, 0);
}

// ---------------- pack / cast kernels ----------------

__global__ void cast_kernel(const float* __restrict__ in, short* __restrict__ out, int n4){
  int i = blockIdx.x * blockDim.x + threadIdx.x;
  if (i >= n4) return;
  float4 v = ((const float4*)in)[i];
  short4 o; o.x = f2bf(v.x); o.y = f2bf(v.y); o.z = f2bf(v.z); o.w = f2bf(v.w);
  ((short4*)out)[i] = o;
}

// kv_in = concat(memory, x) along seq, cast to bf16. layout [B*SS, FF]
__global__ void build_kv(const float* __restrict__ mem, const float* __restrict__ x,
                         short* __restrict__ out){
  int i = blockIdx.x * blockDim.x + threadIdx.x;  // element/4 index
  int idx = i * 4;
  int row = idx >> 10;          // b*SS + s
  int col = idx & 1023;
  int b = row >> 11, s = row & 2047;
  const float* src = (s < MMEM) ? (mem + ((size_t)b*MMEM + s)*FF + col)
                                : (x   + ((size_t)b*TT + (s - MMEM))*FF + col);
  float4 v = *(const float4*)src;
  short4 o; o.x = f2bf(v.x); o.y = f2bf(v.y); o.z = f2bf(v.z); o.w = f2bf(v.w);
  ((short4*)out)[i] = o;
}

// batched: out_z[c][r] = in_z[r][c], 1024x1024, f32 -> bf16
__global__ void transpose_cast5(const float* __restrict__ i0, const float* __restrict__ i1,
                                const float* __restrict__ i2, const float* __restrict__ i3,
                                const float* __restrict__ i4,
                                short* __restrict__ o0, short* __restrict__ o1,
                                short* __restrict__ o2, short* __restrict__ o3,
                                short* __restrict__ o4){
  const float* in; short* out;
  switch (blockIdx.z){
    case 0: in = i0; out = o0; break;
    case 1: in = i1; out = o1; break;
    case 2: in = i2; out = o2; break;
    case 3: in = i3; out = o3; break;
    default: in = i4; out = o4; break;
  }
  __shared__ float tile[32][33];
  int bx = blockIdx.x * 32, by = blockIdx.y * 32;
  int tx = threadIdx.x, ty = threadIdx.y;
  for (int j = ty; j < 32; j += 8)
    tile[j][tx] = in[(size_t)(by + j)*1024 + bx + tx];
  __syncthreads();
  for (int j = ty; j < 32; j += 8)
    out[(size_t)(bx + j)*1024 + by + tx] = f2bf(tile[tx][j]);
}

// ki[b, 0:M] = episode_idx; ki[b, M+t] = episode_idx[b,M-1] + cumsum(dones)[t]
// Also: per 16-row query group g, the valid-key interval [s_lo, s_hi):
// ki is globally nondecreasing (sorted episodes, then monotone qi), so the
// episode-match set {s : ki[s] in [qi[16g], qi[16g+15]]} is contiguous.
// Tiles outside it are fully masked -> exp underflows to exactly 0 -> skippable.
__global__ void scan_kernel(const int* __restrict__ episode_idx, const int* __restrict__ dones,
                            int* __restrict__ ki, int2* __restrict__ ranges){
  __shared__ int buf[TT];
  __shared__ int kis[SS];
  int b = blockIdx.x, t = threadIdx.x;
  buf[t] = dones[b*TT + t];
  kis[t] = episode_idx[b*MMEM + t];
  __syncthreads();
  for (int off = 1; off < TT; off <<= 1){
    int v = (t >= off) ? buf[t - off] : 0;
    __syncthreads();
    buf[t] += v;
    __syncthreads();
  }
  int base = kis[MMEM - 1];
  int q = base + buf[t];
  kis[MMEM + t] = q;
  ki[b*SS + t] = kis[t];
  ki[b*SS + MMEM + t] = q;
  __syncthreads();
  if (t < 64){
    const int qlo = kis[MMEM + t*16];
    const int qhi = kis[MMEM + t*16 + 15];
    int lo = 0, hi = SS;
    while (lo < hi){ int mid = (lo + hi) >> 1; if (kis[mid] < qlo) lo = mid + 1; else hi = mid; }
    const int s_lo = lo;
    lo = 0; hi = SS;
    const int tgt = qhi + 1;
    while (lo < hi){ int mid = (lo + hi) >> 1; if (kis[mid] < tgt) lo = mid + 1; else hi = mid; }
    int s_hi = lo;                              // exclusive
    const int cap = t*16 + 15 + MMEM + 1;       // causal cap (<= SS always)
    if (s_hi > cap) s_hi = cap;
    ranges[(b << 6) + t] = make_int2(s_lo, s_hi);
  }
}

// uk[b,n,s] = sum_h u[n,h]*k[b,s,n,h];  vr[n,j] = sum_h v[n,h]*r[j,n,h]
__global__ void bias_tables(const short* __restrict__ kbf, const short* __restrict__ rbf,
                            const float* __restrict__ u, const float* __restrict__ v,
                            float* __restrict__ uk, float* __restrict__ vr){
  int i = blockIdx.x * blockDim.x + threadIdx.x;
  if (i < NB * NHD * SS){
    int s = i & 2047, n = (i >> 11) & 15, b = i >> 15;
    const short* kp = kbf + (size_t)(b * SS + s) * 1024 + n * 64;
    const float* up = u + n * 64;
    float acc = 0.f;
    #pragma unroll 8
    for (int h = 0; h < 64; h++) acc += bf2f(kp[h]) * up[h];
    uk[(size_t)(b * NHD + n) * SS + s] = acc;
  } else {
    int j = i - NB * NHD * SS;
    if (j >= NHD * SS) return;
    int jj = j & 2047, n = j >> 11;
    const short* rp = rbf + (size_t)jj * 1024 + n * 64;
    const float* vp = v + n * 64;
    float acc = 0.f;
    #pragma unroll 8
    for (int h = 0; h < 64; h++) acc += bf2f(rp[h]) * vp[h];
    vr[(size_t)n * SS + jj] = acc;
  }
}

// ---------------- m97-style 128x128 GEMM core (K=1024, BK=32) ----------------
__device__ __forceinline__ void gemm128_core(const short* __restrict__ A,
                                             const short* __restrict__ BT,
                                             int row0, int col0,
                                             short* As, short* Bs,
                                             f32x4 (&acc)[4][4]){
  const int lane = threadIdx.x & 63, wv = threadIdx.x >> 6;
  const int lcol = lane & 15, quad = lane >> 4;
  const int wr = (wv >> 1) * 64, wc = (wv & 1) * 64;

  #pragma unroll
  for (int r = 0; r < 4; r++)
    #pragma unroll
    for (int c = 0; c < 4; c++) acc[r][c] = (f32x4){0.f, 0.f, 0.f, 0.f};

  const short* gA = A  + (size_t)(row0 + wv*16 + (lane>>2)) * 1024 + (lane&3)*8;
  const short* gB = BT + (size_t)(col0 + wv*16 + (lane>>2)) * 1024 + (lane&3)*8;
  short* lA0 = As + wv*512;  short* lA1 = As + (wv+4)*512;
  short* lB0 = Bs + wv*512;  short* lB1 = Bs + (wv+4)*512;

  for (int k0 = 0; k0 < 1024; k0 += 32){
    __syncthreads();
    stage16(gA + k0,            lA0);
    stage16(gA + 64*1024 + k0,  lA1);
    stage16(gB + k0,            lB0);
    stage16(gB + 64*1024 + k0,  lB1);
    __syncthreads();
    bf16x8 af[4], bfr[4];
    #pragma unroll
    for (int r = 0; r < 4; r++)
      af[r] = *(const bf16x8*)&As[(wr + r*16 + lcol)*32 + quad*8];
    #pragma unroll
    for (int c = 0; c < 4; c++)
      bfr[c] = *(const bf16x8*)&Bs[(wc + c*16 + lcol)*32 + quad*8];
    #pragma unroll
    for (int c = 0; c < 4; c++)
      #pragma unroll
      for (int r = 0; r < 4; r++)
        acc[r][c] = __builtin_amdgcn_mfma_f32_16x16x32_bf16(af[r], bfr[c], acc[r][c], 0, 0, 0);
  }
}

// Fused projection GEMM: blockIdx.z selects job:
//   z=0: kbf = kv @ WkT                      (4096 rows)
//   z=1: vT  = kv @ WvT, per-head transposed (4096 rows)
//   z=2: qb  = x @ WqT   (x read in-place from kv_bf rows [M..S); bx<16)
//   z=3: rbf = rel @ WrT (2048 rows; bx<16)
__global__ __launch_bounds__(256) void proj_gemm(
    const short* __restrict__ kv, const short* __restrict__ relb,
    const short* __restrict__ WkT, const short* __restrict__ WvT,
    const short* __restrict__ WqT, const short* __restrict__ WrT,
    short* __restrict__ kbf, short* __restrict__ vT,
    short* __restrict__ qb, short* __restrict__ rbf){
  const int z = blockIdx.z;
  const int bx = blockIdx.x;
  const short* A; const short* BT;
  int row0 = bx * 128, qbb = 0;
  if (z == 0){ A = kv; BT = WkT; }
  else if (z == 1){ A = kv; BT = WvT; }
  else if (z == 2){
    if (bx >= 16) return;
    qbb = bx >> 3;                       // batch
    A = kv + (size_t)(qbb * SS + MMEM) * 1024;   // x rows live inside kv
    row0 = (bx & 7) * 128;
    BT = WqT;
  }
  else { if (bx >= 16) return; A = relb; BT = WrT; }
  const int col0 = blockIdx.y * 128;

  __shared__ __align__(16) short As[128*32];
  __shared__ __align__(16) short Bs[128*32];
  f32x4 acc[4][4];
  gemm128_core(A, BT, row0, col0, As, Bs, acc);

  const int lane = threadIdx.x & 63, wv = threadIdx.x >> 6;
  const int lcol = lane & 15, quad = lane >> 4;
  const int wr = (wv >> 1) * 64, wc = (wv & 1) * 64;
  #pragma unroll
  for (int c = 0; c < 4; c++){
    const int cc = col0 + wc + c*16 + lcol;
    #pragma unroll
    for (int r = 0; r < 4; r++){
      #pragma unroll
      for (int ri = 0; ri < 4; ri++){
        const int rr = row0 + wr + r*16 + quad*4 + ri;
        float val = acc[r][c][ri];
        if (z == 0){
          kbf[(size_t)rr * 1024 + cc] = f2bf(val);
        } else if (z == 1){
          int b = rr >> 11, s = rr & 2047;
          vT[(size_t)(((b << 4) + (cc >> 6)) * 64 + (cc & 63)) * 2048 + s] = f2bf(val);
        } else if (z == 2){
          qb[((size_t)(qbb * TT) + rr) * 1024 + cc] = f2bf(val);
        } else {
          rbf[(size_t)rr * 1024 + cc] = f2bf(val);
        }
      }
    }
  }
}

// Output projection: out = attn @ WoT + b_out (f32 out, 2048 rows)
__global__ __launch_bounds__(256) void out_gemm(const short* __restrict__ A,
                                                const short* __restrict__ BT,
                                                const float* __restrict__ bias,
                                                float* __restrict__ C){
  const int row0 = blockIdx.x * 128, col0 = blockIdx.y * 128;
  __shared__ __align__(16) short As[128*32];
  __shared__ __align__(16) short Bs[128*32];
  f32x4 acc[4][4];
  gemm128_core(A, BT, row0, col0, As, Bs, acc);

  const int lane = threadIdx.x & 63, wv = threadIdx.x >> 6;
  const int lcol = lane & 15, quad = lane >> 4;
  const int wr = (wv >> 1) * 64, wc = (wv & 1) * 64;
  #pragma unroll
  for (int c = 0; c < 4; c++){
    const int cc = col0 + wc + c*16 + lcol;
    const float bb = bias[cc];
    #pragma unroll
    for (int r = 0; r < 4; r++)
      #pragma unroll
      for (int ri = 0; ri < 4; ri++){
        const int rr = row0 + wr + r*16 + quad*4 + ri;
        C[(size_t)rr * 1024 + cc] = acc[r][c][ri] + bb;
      }
  }
}

// ---------------- flash attention: one wave per 16-row q-group --------------
// grid 2048 x 64 threads. XCD swizzle as R6 (L2 working set per XCD ~3.6 MB).
// Each wave sweeps ONLY the valid k-tile interval from ranges[] (episode-mask
// interval + causal cap). Skipped tiles are fully masked -> exact (masked
// probs underflow to 0; every query attends at least its own diagonal).
// No split-K, no merge, no __syncthreads; P roundtrip is wave-synchronous.
__global__ __launch_bounds__(64) void attn_kernel(const short* __restrict__ qb,
                            const short* __restrict__ rbf,
                            const short* __restrict__ kk, const short* __restrict__ vT,
                            const int* __restrict__ ki,
                            const float* __restrict__ uk, const float* __restrict__ vr,
                            const int2* __restrict__ ranges,
                            short* __restrict__ attn_out){
  const int blk = blockIdx.x;
  const int xcd = blk & 7;
  const int idx = blk >> 3;                 // [0,256)
  const int bn  = (xcd << 2) | (idx >> 6);  // 4 (b,n) groups per XCD
  const int t16 = (idx & 63) * 16;
  const int n = bn & 15;
  const int b = bn >> 4;
  const int lane = threadIdx.x & 63;
  const int quad = lane >> 4, lcol = lane & 15;

  __shared__ __align__(16) short pb[16 * 72];

  const short* qp = qb + (size_t)(b * TT + t16 + lcol) * 1024 + n * 64 + quad * 8;
  bf16x8 aq0 = *(const bf16x8*)(qp);
  bf16x8 aq1 = *(const bf16x8*)(qp + 32);

  int trow[4], qi_r[4], sl[4];
  bool hi[4];
  #pragma unroll
  for (int r = 0; r < 4; r++){
    trow[r] = t16 + quad * 4 + r;
    qi_r[r] = ki[b * SS + MMEM + trow[r]];
    const int rt = quad * 4 + r;
    const int off = lcol + 15 - rt;
    sl[r] = quad * 16 + (off & 15);
    hi[r] = off >= 16;
  }

  float m_run[4], l_run[4];
  f32x4 o[4];
  #pragma unroll
  for (int r = 0; r < 4; r++){ m_run[r] = -1e30f; l_run[r] = 0.f; }
  #pragma unroll
  for (int c = 0; c < 4; c++) o[c] = (f32x4){0.f, 0.f, 0.f, 0.f};

  const float scale = 0.125f;
  const size_t vt_base = (size_t)((b * NHD + n) * HD);
  const short* rb_head = rbf + n * 64;
  const float* uk_row = uk + (size_t)(b * NHD + n) * SS;
  const float* vr_row = vr + (size_t)n * SS;

  const int2 rg = ranges[(b << 6) + (t16 >> 4)];
  const int kt0 = rg.x >> 6, kt1 = (rg.y - 1) >> 6;

  for (int kt = kt0; kt <= kt1; kt++){
    const int s0 = kt * 64;
    // ---- S = Q . K^T  (+ uk column bias) ----
    f32x4 sacc[4];
    float ukc[4];
    #pragma unroll
    for (int c = 0; c < 4; c++){
      const short* kp = kk + (size_t)(b * SS + s0 + 16 * c + lcol) * 1024 + n * 64 + quad * 8;
      bf16x8 b0 = *(const bf16x8*)(kp);
      bf16x8 b1 = *(const bf16x8*)(kp + 32);
      f32x4 z = (f32x4){0.f, 0.f, 0.f, 0.f};
      z = __builtin_amdgcn_mfma_f32_16x16x32_bf16(aq0, b0, z, 0, 0, 0);
      z = __builtin_amdgcn_mfma_f32_16x16x32_bf16(aq1, b1, z, 0, 0, 0);
      sacc[c] = z;
      ukc[c] = uk_row[s0 + 16 * c + lcol];
    }
    int ki_c[4];
    #pragma unroll
    for (int c = 0; c < 4; c++) ki_c[c] = ki[b * SS + s0 + 16 * c + lcol];

    // ---- D = Q . R^T (+ vr column bias) over the 80-row window ----
    const int j0 = s0 - t16 + 1008;   // >= 0 always
    f32x4 Dw[5];
    #pragma unroll
    for (int c5 = 0; c5 < 5; c5++){
      int jr = j0 + 16 * c5 + lcol;
      jr = (jr > SS - 1) ? (SS - 1) : jr;   // clamped rows are causally masked
      const short* rp = rb_head + (size_t)jr * 1024 + quad * 8;
      bf16x8 r0 = *(const bf16x8*)(rp);
      bf16x8 r1 = *(const bf16x8*)(rp + 32);
      f32x4 z = (f32x4){0.f, 0.f, 0.f, 0.f};
      z = __builtin_amdgcn_mfma_f32_16x16x32_bf16(aq0, r0, z, 0, 0, 0);
      z = __builtin_amdgcn_mfma_f32_16x16x32_bf16(aq1, r1, z, 0, 0, 0);
      const float vrj = vr_row[jr];
      #pragma unroll
      for (int r = 0; r < 4; r++) z[r] += vrj;
      Dw[c5] = z;
    }

    // ---- bias shift (Toeplitz) + mask + logits ----
    float p[4][4];
    float rowmax[4];
    #pragma unroll
    for (int r = 0; r < 4; r++) rowmax[r] = -1e30f;
    #pragma unroll
    for (int c = 0; c < 4; c++){
      const int s = s0 + 16 * c + lcol;
      #pragma unroll
      for (int r = 0; r < 4; r++){
        const float v0 = __shfl(Dw[c][r], sl[r], 64);
        const float v1 = __shfl(Dw[c + 1][r], sl[r], 64);
        const float bd = hi[r] ? v1 : v0;
        float lg = (sacc[c][r] + ukc[c] + bd) * scale;
        const bool valid = (s <= trow[r] + MMEM) && (ki_c[c] == qi_r[r]);
        lg = valid ? lg : -1e30f;
        p[c][r] = lg;
        rowmax[r] = fmaxf(rowmax[r], lg);
      }
    }
    // ---- online softmax ----
    #pragma unroll
    for (int r = 0; r < 4; r++){
      float vmx = rowmax[r];
      #pragma unroll
      for (int off = 1; off < 16; off <<= 1) vmx = fmaxf(vmx, __shfl_xor(vmx, off, 64));
      float mnew = fmaxf(m_run[r], vmx);
      float alpha = __expf(m_run[r] - mnew);
      m_run[r] = mnew;
      l_run[r] *= alpha;
      #pragma unroll
      for (int c = 0; c < 4; c++) o[c][r] *= alpha;
    }
    float psum[4] = {0.f, 0.f, 0.f, 0.f};
    #pragma unroll
    for (int c = 0; c < 4; c++)
      #pragma unroll
      for (int r = 0; r < 4; r++){
        float pv = __expf(p[c][r] - m_run[r]);
        p[c][r] = pv;
        psum[r] += pv;
      }
    #pragma unroll
    for (int r = 0; r < 4; r++){
      float vs = psum[r];
      #pragma unroll
      for (int off = 1; off < 16; off <<= 1) vs += __shfl_xor(vs, off, 64);
      l_run[r] += vs;
    }
    // ---- P: C-layout -> A-layout via LDS (wave-synchronous) ----
    #pragma unroll
    for (int c = 0; c < 4; c++)
      #pragma unroll
      for (int r = 0; r < 4; r++)
        pb[(quad * 4 + r) * 72 + 16 * c + lcol] = f2bf(p[c][r]);
    bf16x8 pa0 = *(const bf16x8*)(&pb[lcol * 72 + quad * 8]);
    bf16x8 pa1 = *(const bf16x8*)(&pb[lcol * 72 + 32 + quad * 8]);
    // ---- O += P . V ----
    #pragma unroll
    for (int c = 0; c < 4; c++){
      const short* vtp = vT + (vt_base + c * 16 + lcol) * (size_t)SS + s0 + quad * 8;
      bf16x8 bv0 = *(const bf16x8*)(vtp);
      bf16x8 bv1 = *(const bf16x8*)(vtp + 32);
      o[c] = __builtin_amdgcn_mfma_f32_16x16x32_bf16(pa0, bv0, o[c], 0, 0, 0);
      o[c] = __builtin_amdgcn_mfma_f32_16x16x32_bf16(pa1, bv1, o[c], 0, 0, 0);
    }
  }

  // ---- epilogue: normalize, store bf16 attn [B*T, N*H] ----
  #pragma unroll
  for (int r = 0; r < 4; r++){
    const float inv = 1.f / l_run[r];
    const int t = trow[r];
    #pragma unroll
    for (int c = 0; c < 4; c++)
      attn_out[(size_t)(b * TT + t) * 1024 + n * 64 + c * 16 + lcol] = f2bf(o[c][r] * inv);
  }
}

// ---------------- launcher ----------------
extern "C" void kernel_launch(void* const* d_in, const int* in_sizes, int n_in,
                              void* d_out, int out_size, void* d_ws, size_t ws_size,
                              hipStream_t stream){
  const float* x      = (const float*)d_in[0];
  const float* rel    = (const float*)d_in[1];
  const float* memory = (const float*)d_in[2];
  const int*   episode_idx = (const int*)d_in[3];
  const int*   dones  = (const int*)d_in[4];
  const float* Wq  = (const float*)d_in[5];
  const float* Wk  = (const float*)d_in[6];
  const float* Wv  = (const float*)d_in[7];
  const float* Wr  = (const float*)d_in[8];
  const float* u   = (const float*)d_in[9];
  const float* v   = (const float*)d_in[10];
  const float* Wout  = (const float*)d_in[11];
  const float* b_out = (const float*)d_in[12];
  float* out = (float*)d_out;

  char* ws = (char*)d_ws;
  size_t off = 0;
  auto alloc = [&](size_t bytes) -> char* {
    char* p = ws + off;
    off += (bytes + 255) & ~(size_t)255;
    return p;
  };
  short* kv_bf  = (short*)alloc((size_t)NB * SS * FF * 2);
  short* rel_bf = (short*)alloc((size_t)SS * FF * 2);
  short* WqT    = (short*)alloc((size_t)FF * 1024 * 2);
  short* WkT    = (short*)alloc((size_t)FF * 1024 * 2);
  short* WvT    = (short*)alloc((size_t)FF * 1024 * 2);
  short* WrT    = (short*)alloc((size_t)FF * 1024 * 2);
  short* WoT    = (short*)alloc((size_t)FF * 1024 * 2);
  short* qbuf   = (short*)alloc((size_t)NB * TT * 1024 * 2);
  short* kbf    = (short*)alloc((size_t)NB * SS * 1024 * 2);
  short* vTb    = (short*)alloc((size_t)NB * SS * 1024 * 2);
  short* rbf    = (short*)alloc((size_t)SS * 1024 * 2);
  int*   ki     = (int*)  alloc((size_t)NB * SS * 4);
  int2*  ranges = (int2*) alloc((size_t)NB * 64 * 8);
  float* ukT    = (float*)alloc((size_t)NB * NHD * SS * 4);
  float* vrT    = (float*)alloc((size_t)NHD * SS * 4);
  short* attn   = (short*)alloc((size_t)NB * TT * 1024 * 2);
  (void)ws_size; (void)in_sizes; (void)n_in; (void)out_size;

  // pack
  cast_kernel<<<(SS*FF/4 + 255)/256, 256, 0, stream>>>(rel, rel_bf, SS*FF/4);
  build_kv<<<(NB*SS*FF/4)/256, 256, 0, stream>>>(memory, x, kv_bf);
  dim3 tb(32, 8), tg5(32, 32, 5);
  transpose_cast5<<<tg5, tb, 0, stream>>>(Wq, Wk, Wv, Wr, Wout, WqT, WkT, WvT, WrT, WoT);
  scan_kernel<<<NB, TT, 0, stream>>>(episode_idx, dones, ki, ranges);

  // fused projections: z=0 K, z=1 V(transposed), z=2 Q (from kv rows), z=3 R
  proj_gemm<<<dim3(32, 8, 4), 256, 0, stream>>>(kv_bf, rel_bf,
                                                WkT, WvT, WqT, WrT,
                                                kbf, vTb, qbuf, rbf);

  // u·k / v·r column-bias tables
  bias_tables<<<(NB*NHD*SS + NHD*SS + 255)/256, 256, 0, stream>>>(kbf, rbf, u, v, ukT, vrT);

  // attention: one wave per 16-row q-group, valid-interval sweep only
  attn_kernel<<<2048, 64, 0, stream>>>(qbuf, rbf, kbf, vTb, ki, ukT, vrT, ranges, attn);

  // output projection
  out_gemm<<<dim3(16, 8), 256, 0, stream>>>(attn, WoT, b_out, out);
}

// Round 8
// 236.390 us; speedup vs baseline: 3.1645x; 1.0234x over previous
//
#include <hip/hip_runtime.h>
#include <cstdint>
#include <cstddef>

// Problem constants
#define NB 2
#define TT 1024
#define MMEM 1024
#define SS 2048   // M + T
#define FF 1024
#define NHD 16    // heads
#define HD 64     // head dim

typedef __attribute__((ext_vector_type(8))) short bf16x8;
typedef __attribute__((ext_vector_type(4))) float f32x4;

__device__ __forceinline__ float bf2f(short s){
  unsigned u = ((unsigned)(unsigned short)s) << 16;
  float f; __builtin_memcpy(&f, &u, 4); return f;
}
__device__ __forceinline__ short f2bf(float f){
  unsigned u; __builtin_memcpy(&u, &f, 4);
  u += 0x7fffu + ((u >> 16) & 1u);   // RNE
  return (short)(u >> 16);
}

// async global->LDS, 16 B per lane; LDS dest = wave-uniform base + lane*16
typedef const __attribute__((address_space(1))) void gv_t;
typedef __attribute__((address_space(3))) void lv_t;
__device__ __forceinline__ void stage16(const void* g, void* l){
  __builtin_amdgcn_global_load_lds((gv_t*)g, (lv_t*)l, 16, 0, 0);
}

// ---------------- pack / cast kernels ----------------

__global__ void cast_kernel(const float* __restrict__ in, short* __restrict__ out, int n4){
  int i = blockIdx.x * blockDim.x + threadIdx.x;
  if (i >= n4) return;
  float4 v = ((const float4*)in)[i];
  short4 o; o.x = f2bf(v.x); o.y = f2bf(v.y); o.z = f2bf(v.z); o.w = f2bf(v.w);
  ((short4*)out)[i] = o;
}

// kv_in = concat(memory, x) along seq, cast to bf16. layout [B*SS, FF]
__global__ void build_kv(const float* __restrict__ mem, const float* __restrict__ x,
                         short* __restrict__ out){
  int i = blockIdx.x * blockDim.x + threadIdx.x;  // element/4 index
  int idx = i * 4;
  int row = idx >> 10;          // b*SS + s
  int col = idx & 1023;
  int b = row >> 11, s = row & 2047;
  const float* src = (s < MMEM) ? (mem + ((size_t)b*MMEM + s)*FF + col)
                                : (x   + ((size_t)b*TT + (s - MMEM))*FF + col);
  float4 v = *(const float4*)src;
  short4 o; o.x = f2bf(v.x); o.y = f2bf(v.y); o.z = f2bf(v.z); o.w = f2bf(v.w);
  ((short4*)out)[i] = o;
}

// batched: out_z[c][r] = in_z[r][c], 1024x1024, f32 -> bf16
__global__ void transpose_cast5(const float* __restrict__ i0, const float* __restrict__ i1,
                                const float* __restrict__ i2, const float* __restrict__ i3,
                                const float* __restrict__ i4,
                                short* __restrict__ o0, short* __restrict__ o1,
                                short* __restrict__ o2, short* __restrict__ o3,
                                short* __restrict__ o4){
  const float* in; short* out;
  switch (blockIdx.z){
    case 0: in = i0; out = o0; break;
    case 1: in = i1; out = o1; break;
    case 2: in = i2; out = o2; break;
    case 3: in = i3; out = o3; break;
    default: in = i4; out = o4; break;
  }
  __shared__ float tile[32][33];
  int bx = blockIdx.x * 32, by = blockIdx.y * 32;
  int tx = threadIdx.x, ty = threadIdx.y;
  for (int j = ty; j < 32; j += 8)
    tile[j][tx] = in[(size_t)(by + j)*1024 + bx + tx];
  __syncthreads();
  for (int j = ty; j < 32; j += 8)
    out[(size_t)(bx + j)*1024 + by + tx] = f2bf(tile[tx][j]);
}

// ki[b, 0:M] = episode_idx; ki[b, M+t] = episode_idx[b,M-1] + cumsum(dones)[t]
// Also: per 16-row query group g, the valid-key interval [s_lo, s_hi):
// ki is globally nondecreasing (sorted episodes, then monotone qi), so the
// episode-match set {s : ki[s] in [qi[16g], qi[16g+15]]} is contiguous.
// Tiles outside it are fully masked -> exp underflows to exactly 0 -> skippable.
__global__ void scan_kernel(const int* __restrict__ episode_idx, const int* __restrict__ dones,
                            int* __restrict__ ki, int2* __restrict__ ranges){
  __shared__ int buf[TT];
  __shared__ int kis[SS];
  int b = blockIdx.x, t = threadIdx.x;
  buf[t] = dones[b*TT + t];
  kis[t] = episode_idx[b*MMEM + t];
  __syncthreads();
  for (int off = 1; off < TT; off <<= 1){
    int v = (t >= off) ? buf[t - off] : 0;
    __syncthreads();
    buf[t] += v;
    __syncthreads();
  }
  int base = kis[MMEM - 1];
  int q = base + buf[t];
  kis[MMEM + t] = q;
  ki[b*SS + t] = kis[t];
  ki[b*SS + MMEM + t] = q;
  __syncthreads();
  if (t < 64){
    const int qlo = kis[MMEM + t*16];
    const int qhi = kis[MMEM + t*16 + 15];
    int lo = 0, hi = SS;
    while (lo < hi){ int mid = (lo + hi) >> 1; if (kis[mid] < qlo) lo = mid + 1; else hi = mid; }
    const int s_lo = lo;
    lo = 0; hi = SS;
    const int tgt = qhi + 1;
    while (lo < hi){ int mid = (lo + hi) >> 1; if (kis[mid] < tgt) lo = mid + 1; else hi = mid; }
    int s_hi = lo;                              // exclusive
    const int cap = t*16 + 15 + MMEM + 1;       // causal cap (<= SS always)
    if (s_hi > cap) s_hi = cap;
    ranges[(b << 6) + t] = make_int2(s_lo, s_hi);
  }
}

// uk[b,n,s] = sum_h u[n,h]*k[b,s,n,h];  vr[n,j] = sum_h v[n,h]*r[j,n,h]
__global__ void bias_tables(const short* __restrict__ kbf, const short* __restrict__ rbf,
                            const float* __restrict__ u, const float* __restrict__ v,
                            float* __restrict__ uk, float* __restrict__ vr){
  int i = blockIdx.x * blockDim.x + threadIdx.x;
  if (i < NB * NHD * SS){
    int s = i & 2047, n = (i >> 11) & 15, b = i >> 15;
    const short* kp = kbf + (size_t)(b * SS + s) * 1024 + n * 64;
    const float* up = u + n * 64;
    float acc = 0.f;
    #pragma unroll 8
    for (int h = 0; h < 64; h++) acc += bf2f(kp[h]) * up[h];
    uk[(size_t)(b * NHD + n) * SS + s] = acc;
  } else {
    int j = i - NB * NHD * SS;
    if (j >= NHD * SS) return;
    int jj = j & 2047, n = j >> 11;
    const short* rp = rbf + (size_t)jj * 1024 + n * 64;
    const float* vp = v + n * 64;
    float acc = 0.f;
    #pragma unroll 8
    for (int h = 0; h < 64; h++) acc += bf2f(rp[h]) * vp[h];
    vr[(size_t)n * SS + jj] = acc;
  }
}

// ---------------- 128x128 GEMM core, BK=64, XOR-swizzled staging -------------
// C[i,j] = sum_k A[i,k] * BT[j,k]; A,BT row-major bf16, ld = 1024, K = 1024.
// 16 k-iterations (vs 32 at BK=32): halves the 2-barrier drains; 32 MFMA per
// wave per barrier-pair. LDS layout: 16B unit (row, chunk) stored at
// row*128B + ((chunk ^ (row&7))*16B). Staging (global_load_lds, 16B/lane):
// unit u = j*64+lane -> row=u>>3, chunk=(u&7)^(row&7): each 1024B wave-write
// covers 8 full 128B rows (coalesced); fragment ds_read_b128s spread uniformly
// over all 32 banks (2 lanes/bank = free; R7's row-stride layout cost 3.1M
// conflict cycles).
__device__ __forceinline__ void gemm128_core(const short* __restrict__ A,
                                             const short* __restrict__ BT,
                                             int row0, int col0,
                                             short* As, short* Bs,
                                             f32x4 (&acc)[4][4]){
  const int lane = threadIdx.x & 63, wv = threadIdx.x >> 6;
  const int lcol = lane & 15, quad = lane >> 4;
  const int wr = (wv >> 1) * 64, wc = (wv & 1) * 64;
  const int sw = lcol & 7;                 // row&7 for all fragment rows
  const int ch0 = (quad ^ sw) * 8;         // k-half 0 chunk offset (shorts)
  const int ch1 = ((4 + quad) ^ sw) * 8;   // k-half 1

  #pragma unroll
  for (int r = 0; r < 4; r++)
    #pragma unroll
    for (int c = 0; c < 4; c++) acc[r][c] = (f32x4){0.f, 0.f, 0.f, 0.f};

  const short* gA[4]; const short* gB[4];
  short* dA[4]; short* dB[4];
  #pragma unroll
  for (int c = 0; c < 4; c++){
    const int j = wv * 4 + c;
    const int u = j * 64 + lane;
    const int row = u >> 3;
    const int chk = (u & 7) ^ (row & 7);
    gA[c] = A  + (size_t)(row0 + row) * 1024 + chk * 8;
    gB[c] = BT + (size_t)(col0 + row) * 1024 + chk * 8;
    dA[c] = As + j * 512;
    dB[c] = Bs + j * 512;
  }

  #pragma unroll 1
  for (int k0 = 0; k0 < 1024; k0 += 64){
    __syncthreads();
    #pragma unroll
    for (int c = 0; c < 4; c++){
      stage16(gA[c] + k0, dA[c]);
      stage16(gB[c] + k0, dB[c]);
    }
    __syncthreads();
    bf16x8 af[4][2];
    #pragma unroll
    for (int r = 0; r < 4; r++){
      const int rb = (wr + r * 16 + lcol) * 64;
      af[r][0] = *(const bf16x8*)&As[rb + ch0];
      af[r][1] = *(const bf16x8*)&As[rb + ch1];
    }
    #pragma unroll
    for (int c = 0; c < 4; c++){
      const int rb = (wc + c * 16 + lcol) * 64;
      bf16x8 b0 = *(const bf16x8*)&Bs[rb + ch0];
      bf16x8 b1 = *(const bf16x8*)&Bs[rb + ch1];
      #pragma unroll
      for (int r = 0; r < 4; r++){
        acc[r][c] = __builtin_amdgcn_mfma_f32_16x16x32_bf16(af[r][0], b0, acc[r][c], 0, 0, 0);
        acc[r][c] = __builtin_amdgcn_mfma_f32_16x16x32_bf16(af[r][1], b1, acc[r][c], 0, 0, 0);
      }
    }
  }
}

// Fused projection GEMM: blockIdx.z selects job:
//   z=0: kbf = kv @ WkT                      (4096 rows)
//   z=1: vT  = kv @ WvT, per-head transposed (4096 rows)
//   z=2: qb  = x @ WqT   (x read in-place from kv_bf rows [M..S); bx<16)
//   z=3: rbf = rel @ WrT (2048 rows; bx<16)
__global__ __launch_bounds__(256) void proj_gemm(
    const short* __restrict__ kv, const short* __restrict__ relb,
    const short* __restrict__ WkT, const short* __restrict__ WvT,
    const short* __restrict__ WqT, const short* __restrict__ WrT,
    short* __restrict__ kbf, short* __restrict__ vT,
    short* __restrict__ qb, short* __restrict__ rbf){
  const int z = blockIdx.z;
  const int bx = blockIdx.x;
  const short* A; const short* BT;
  int row0 = bx * 128, qbb = 0;
  if (z == 0){ A = kv; BT = WkT; }
  else if (z == 1){ A = kv; BT = WvT; }
  else if (z == 2){
    if (bx >= 16) return;
    qbb = bx >> 3;                       // batch
    A = kv + (size_t)(qbb * SS + MMEM) * 1024;   // x rows live inside kv
    row0 = (bx & 7) * 128;
    BT = WqT;
  }
  else { if (bx >= 16) return; A = relb; BT = WrT; }
  const int col0 = blockIdx.y * 128;

  __shared__ __align__(16) short As[128*64];
  __shared__ __align__(16) short Bs[128*64];
  f32x4 acc[4][4];
  gemm128_core(A, BT, row0, col0, As, Bs, acc);

  const int lane = threadIdx.x & 63, wv = threadIdx.x >> 6;
  const int lcol = lane & 15, quad = lane >> 4;
  const int wr = (wv >> 1) * 64, wc = (wv & 1) * 64;
  #pragma unroll
  for (int c = 0; c < 4; c++){
    const int cc = col0 + wc + c*16 + lcol;
    #pragma unroll
    for (int r = 0; r < 4; r++){
      #pragma unroll
      for (int ri = 0; ri < 4; ri++){
        const int rr = row0 + wr + r*16 + quad*4 + ri;
        float val = acc[r][c][ri];
        if (z == 0){
          kbf[(size_t)rr * 1024 + cc] = f2bf(val);
        } else if (z == 1){
          int b = rr >> 11, s = rr & 2047;
          vT[(size_t)(((b << 4) + (cc >> 6)) * 64 + (cc & 63)) * 2048 + s] = f2bf(val);
        } else if (z == 2){
          qb[((size_t)(qbb * TT) + rr) * 1024 + cc] = f2bf(val);
        } else {
          rbf[(size_t)rr * 1024 + cc] = f2bf(val);
        }
      }
    }
  }
}

// Output projection: out = attn @ WoT + b_out (f32 out, 2048 rows)
__global__ __launch_bounds__(256) void out_gemm(const short* __restrict__ A,
                                                const short* __restrict__ BT,
                                                const float* __restrict__ bias,
                                                float* __restrict__ C){
  const int row0 = blockIdx.x * 128, col0 = blockIdx.y * 128;
  __shared__ __align__(16) short As[128*64];
  __shared__ __align__(16) short Bs[128*64];
  f32x4 acc[4][4];
  gemm128_core(A, BT, row0, col0, As, Bs, acc);

  const int lane = threadIdx.x & 63, wv = threadIdx.x >> 6;
  const int lcol = lane & 15, quad = lane >> 4;
  const int wr = (wv >> 1) * 64, wc = (wv & 1) * 64;
  #pragma unroll
  for (int c = 0; c < 4; c++){
    const int cc = col0 + wc + c*16 + lcol;
    const float bb = bias[cc];
    #pragma unroll
    for (int r = 0; r < 4; r++)
      #pragma unroll
      for (int ri = 0; ri < 4; ri++){
        const int rr = row0 + wr + r*16 + quad*4 + ri;
        C[(size_t)rr * 1024 + cc] = acc[r][c][ri] + bb;
      }
  }
}

// ---------------- flash attention: one wave per 16-row q-group --------------
// grid 2048 x 64 threads. XCD swizzle (L2 working set per XCD ~3.6 MB).
// Each wave sweeps ONLY the valid k-tile interval from ranges[] (episode-mask
// interval + causal cap). Skipped tiles are fully masked -> exact.
__global__ __launch_bounds__(64) void attn_kernel(const short* __restrict__ qb,
                            const short* __restrict__ rbf,
                            const short* __restrict__ kk, const short* __restrict__ vT,
                            const int* __restrict__ ki,
                            const float* __restrict__ uk, const float* __restrict__ vr,
                            const int2* __restrict__ ranges,
                            short* __restrict__ attn_out){
  const int blk = blockIdx.x;
  const int xcd = blk & 7;
  const int idx = blk >> 3;                 // [0,256)
  const int bn  = (xcd << 2) | (idx >> 6);  // 4 (b,n) groups per XCD
  const int t16 = (idx & 63) * 16;
  const int n = bn & 15;
  const int b = bn >> 4;
  const int lane = threadIdx.x & 63;
  const int quad = lane >> 4, lcol = lane & 15;

  __shared__ __align__(16) short pb[16 * 72];

  const short* qp = qb + (size_t)(b * TT + t16 + lcol) * 1024 + n * 64 + quad * 8;
  bf16x8 aq0 = *(const bf16x8*)(qp);
  bf16x8 aq1 = *(const bf16x8*)(qp + 32);

  int trow[4], qi_r[4], sl[4];
  bool hi[4];
  #pragma unroll
  for (int r = 0; r < 4; r++){
    trow[r] = t16 + quad * 4 + r;
    qi_r[r] = ki[b * SS + MMEM + trow[r]];
    const int rt = quad * 4 + r;
    const int off = lcol + 15 - rt;
    sl[r] = quad * 16 + (off & 15);
    hi[r] = off >= 16;
  }

  float m_run[4], l_run[4];
  f32x4 o[4];
  #pragma unroll
  for (int r = 0; r < 4; r++){ m_run[r] = -1e30f; l_run[r] = 0.f; }
  #pragma unroll
  for (int c = 0; c < 4; c++) o[c] = (f32x4){0.f, 0.f, 0.f, 0.f};

  const float scale = 0.125f;
  const size_t vt_base = (size_t)((b * NHD + n) * HD);
  const short* rb_head = rbf + n * 64;
  const float* uk_row = uk + (size_t)(b * NHD + n) * SS;
  const float* vr_row = vr + (size_t)n * SS;

  const int2 rg = ranges[(b << 6) + (t16 >> 4)];
  const int kt0 = rg.x >> 6, kt1 = (rg.y - 1) >> 6;

  for (int kt = kt0; kt <= kt1; kt++){
    const int s0 = kt * 64;
    // ---- S = Q . K^T  (+ uk column bias) ----
    f32x4 sacc[4];
    float ukc[4];
    #pragma unroll
    for (int c = 0; c < 4; c++){
      const short* kp = kk + (size_t)(b * SS + s0 + 16 * c + lcol) * 1024 + n * 64 + quad * 8;
      bf16x8 b0 = *(const bf16x8*)(kp);
      bf16x8 b1 = *(const bf16x8*)(kp + 32);
      f32x4 z = (f32x4){0.f, 0.f, 0.f, 0.f};
      z = __builtin_amdgcn_mfma_f32_16x16x32_bf16(aq0, b0, z, 0, 0, 0);
      z = __builtin_amdgcn_mfma_f32_16x16x32_bf16(aq1, b1, z, 0, 0, 0);
      sacc[c] = z;
      ukc[c] = uk_row[s0 + 16 * c + lcol];
    }
    int ki_c[4];
    #pragma unroll
    for (int c = 0; c < 4; c++) ki_c[c] = ki[b * SS + s0 + 16 * c + lcol];

    // ---- D = Q . R^T (+ vr column bias) over the 80-row window ----
    const int j0 = s0 - t16 + 1008;   // >= 0 always
    f32x4 Dw[5];
    #pragma unroll
    for (int c5 = 0; c5 < 5; c5++){
      int jr = j0 + 16 * c5 + lcol;
      jr = (jr > SS - 1) ? (SS - 1) : jr;   // clamped rows are causally masked
      const short* rp = rb_head + (size_t)jr * 1024 + quad * 8;
      bf16x8 r0 = *(const bf16x8*)(rp);
      bf16x8 r1 = *(const bf16x8*)(rp + 32);
      f32x4 z = (f32x4){0.f, 0.f, 0.f, 0.f};
      z = __builtin_amdgcn_mfma_f32_16x16x32_bf16(aq0, r0, z, 0, 0, 0);
      z = __builtin_amdgcn_mfma_f32_16x16x32_bf16(aq1, r1, z, 0, 0, 0);
      const float vrj = vr_row[jr];
      #pragma unroll
      for (int r = 0; r < 4; r++) z[r] += vrj;
      Dw[c5] = z;
    }

    // ---- bias shift (Toeplitz) + mask + logits ----
    float p[4][4];
    float rowmax[4];
    #pragma unroll
    for (int r = 0; r < 4; r++) rowmax[r] = -1e30f;
    #pragma unroll
    for (int c = 0; c < 4; c++){
      const int s = s0 + 16 * c + lcol;
      #pragma unroll
      for (int r = 0; r < 4; r++){
        const float v0 = __shfl(Dw[c][r], sl[r], 64);
        const float v1 = __shfl(Dw[c + 1][r], sl[r], 64);
        const float bd = hi[r] ? v1 : v0;
        float lg = (sacc[c][r] + ukc[c] + bd) * scale;
        const bool valid = (s <= trow[r] + MMEM) && (ki_c[c] == qi_r[r]);
        lg = valid ? lg : -1e30f;
        p[c][r] = lg;
        rowmax[r] = fmaxf(rowmax[r], lg);
      }
    }
    // ---- online softmax ----
    #pragma unroll
    for (int r = 0; r < 4; r++){
      float vmx = rowmax[r];
      #pragma unroll
      for (int off = 1; off < 16; off <<= 1) vmx = fmaxf(vmx, __shfl_xor(vmx, off, 64));
      float mnew = fmaxf(m_run[r], vmx);
      float alpha = __expf(m_run[r] - mnew);
      m_run[r] = mnew;
      l_run[r] *= alpha;
      #pragma unroll
      for (int c = 0; c < 4; c++) o[c][r] *= alpha;
    }
    float psum[4] = {0.f, 0.f, 0.f, 0.f};
    #pragma unroll
    for (int c = 0; c < 4; c++)
      #pragma unroll
      for (int r = 0; r < 4; r++){
        float pv = __expf(p[c][r] - m_run[r]);
        p[c][r] = pv;
        psum[r] += pv;
      }
    #pragma unroll
    for (int r = 0; r < 4; r++){
      float vs = psum[r];
      #pragma unroll
      for (int off = 1; off < 16; off <<= 1) vs += __shfl_xor(vs, off, 64);
      l_run[r] += vs;
    }
    // ---- P: C-layout -> A-layout via LDS (wave-synchronous) ----
    #pragma unroll
    for (int c = 0; c < 4; c++)
      #pragma unroll
      for (int r = 0; r < 4; r++)
        pb[(quad * 4 + r) * 72 + 16 * c + lcol] = f2bf(p[c][r]);
    bf16x8 pa0 = *(const bf16x8*)(&pb[lcol * 72 + quad * 8]);
    bf16x8 pa1 = *(const bf16x8*)(&pb[lcol * 72 + 32 + quad * 8]);
    // ---- O += P . V ----
    #pragma unroll
    for (int c = 0; c < 4; c++){
      const short* vtp = vT + (vt_base + c * 16 + lcol) * (size_t)SS + s0 + quad * 8;
      bf16x8 bv0 = *(const bf16x8*)(vtp);
      bf16x8 bv1 = *(const bf16x8*)(vtp + 32);
      o[c] = __builtin_amdgcn_mfma_f32_16x16x32_bf16(pa0, bv0, o[c], 0, 0, 0);
      o[c] = __builtin_amdgcn_mfma_f32_16x16x32_bf16(pa1, bv1, o[c], 0, 0, 0);
    }
  }

  // ---- epilogue: normalize, store bf16 attn [B*T, N*H] ----
  #pragma unroll
  for (int r = 0; r < 4; r++){
    const float inv = 1.f / l_run[r];
    const int t = trow[r];
    #pragma unroll
    for (int c = 0; c < 4; c++)
      attn_out[(size_t)(b * TT + t) * 1024 + n * 64 + c * 16 + lcol] = f2bf(o[c][r] * inv);
  }
}

// ---------------- launcher ----------------
extern "C" void kernel_launch(void* const* d_in, const int* in_sizes, int n_in,
                              void* d_out, int out_size, void* d_ws, size_t ws_size,
                              hipStream_t stream){
  const float* x      = (const float*)d_in[0];
  const float* rel    = (const float*)d_in[1];
  const float* memory = (const float*)d_in[2];
  const int*   episode_idx = (const int*)d_in[3];
  const int*   dones  = (const int*)d_in[4];
  const float* Wq  = (const float*)d_in[5];
  const float* Wk  = (const float*)d_in[6];
  const float* Wv  = (const float*)d_in[7];
  const float* Wr  = (const float*)d_in[8];
  const float* u   = (const float*)d_in[9];
  const float* v   = (const float*)d_in[10];
  const float* Wout  = (const float*)d_in[11];
  const float* b_out = (const float*)d_in[12];
  float* out = (float*)d_out;

  char* ws = (char*)d_ws;
  size_t off = 0;
  auto alloc = [&](size_t bytes) -> char* {
    char* p = ws + off;
    off += (bytes + 255) & ~(size_t)255;
    return p;
  };
  short* kv_bf  = (short*)alloc((size_t)NB * SS * FF * 2);
  short* rel_bf = (short*)alloc((size_t)SS * FF * 2);
  short* WqT    = (short*)alloc((size_t)FF * 1024 * 2);
  short* WkT    = (short*)alloc((size_t)FF * 1024 * 2);
  short* WvT    = (short*)alloc((size_t)FF * 1024 * 2);
  short* WrT    = (short*)alloc((size_t)FF * 1024 * 2);
  short* WoT    = (short*)alloc((size_t)FF * 1024 * 2);
  short* qbuf   = (short*)alloc((size_t)NB * TT * 1024 * 2);
  short* kbf    = (short*)alloc((size_t)NB * SS * 1024 * 2);
  short* vTb    = (short*)alloc((size_t)NB * SS * 1024 * 2);
  short* rbf    = (short*)alloc((size_t)SS * 1024 * 2);
  int*   ki     = (int*)  alloc((size_t)NB * SS * 4);
  int2*  ranges = (int2*) alloc((size_t)NB * 64 * 8);
  float* ukT    = (float*)alloc((size_t)NB * NHD * SS * 4);
  float* vrT    = (float*)alloc((size_t)NHD * SS * 4);
  short* attn   = (short*)alloc((size_t)NB * TT * 1024 * 2);
  (void)ws_size; (void)in_sizes; (void)n_in; (void)out_size;

  // pack
  cast_kernel<<<(SS*FF/4 + 255)/256, 256, 0, stream>>>(rel, rel_bf, SS*FF/4);
  build_kv<<<(NB*SS*FF/4)/256, 256, 0, stream>>>(memory, x, kv_bf);
  dim3 tb(32, 8), tg5(32, 32, 5);
  transpose_cast5<<<tg5, tb, 0, stream>>>(Wq, Wk, Wv, Wr, Wout, WqT, WkT, WvT, WrT, WoT);
  scan_kernel<<<NB, TT, 0, stream>>>(episode_idx, dones, ki, ranges);

  // fused projections: z=0 K, z=1 V(transposed), z=2 Q (from kv rows), z=3 R
  proj_gemm<<<dim3(32, 8, 4), 256, 0, stream>>>(kv_bf, rel_bf,
                                                WkT, WvT, WqT, WrT,
                                                kbf, vTb, qbuf, rbf);

  // u·k / v·r column-bias tables
  bias_tables<<<(NB*NHD*SS + NHD*SS + 255)/256, 256, 0, stream>>>(kbf, rbf, u, v, ukT, vrT);

  // attention: one wave per 16-row q-group, valid-interval sweep only
  attn_kernel<<<2048, 64, 0, stream>>>(qbuf, rbf, kbf, vTb, ki, ukT, vrT, ranges, attn);

  // output projection
  out_gemm<<<dim3(16, 8), 256, 0, stream>>>(attn, WoT, b_out, out);
}

// Round 9
// 228.350 us; speedup vs baseline: 3.2760x; 1.0352x over previous
//
#include <hip/hip_runtime.h>
#include <cstdint>
#include <cstddef>

// Problem constants
#define NB 2
#define TT 1024
#define MMEM 1024
#define SS 2048   // M + T
#define FF 1024
#define NHD 16    // heads
#define HD 64     // head dim

typedef __attribute__((ext_vector_type(8))) short bf16x8;
typedef __attribute__((ext_vector_type(4))) float f32x4;

__device__ __forceinline__ float bf2f(short s){
  unsigned u = ((unsigned)(unsigned short)s) << 16;
  float f; __builtin_memcpy(&f, &u, 4); return f;
}
__device__ __forceinline__ short f2bf(float f){
  unsigned u; __builtin_memcpy(&u, &f, 4);
  u += 0x7fffu + ((u >> 16) & 1u);   // RNE
  return (short)(u >> 16);
}

// async global->LDS, 16 B per lane; LDS dest = wave-uniform base + lane*16
typedef const __attribute__((address_space(1))) void gv_t;
typedef __attribute__((address_space(3))) void lv_t;
__device__ __forceinline__ void stage16(const void* g, void* l){
  __builtin_amdgcn_global_load_lds((gv_t*)g, (lv_t*)l, 16, 0, 0);
}

// ---------------- pack / cast kernels ----------------

__global__ void cast_kernel(const float* __restrict__ in, short* __restrict__ out, int n4){
  int i = blockIdx.x * blockDim.x + threadIdx.x;
  if (i >= n4) return;
  float4 v = ((const float4*)in)[i];
  short4 o; o.x = f2bf(v.x); o.y = f2bf(v.y); o.z = f2bf(v.z); o.w = f2bf(v.w);
  ((short4*)out)[i] = o;
}

// kv_in = concat(memory, x) along seq, cast to bf16. layout [B*SS, FF]
__global__ void build_kv(const float* __restrict__ mem, const float* __restrict__ x,
                         short* __restrict__ out){
  int i = blockIdx.x * blockDim.x + threadIdx.x;  // element/4 index
  int idx = i * 4;
  int row = idx >> 10;          // b*SS + s
  int col = idx & 1023;
  int b = row >> 11, s = row & 2047;
  const float* src = (s < MMEM) ? (mem + ((size_t)b*MMEM + s)*FF + col)
                                : (x   + ((size_t)b*TT + (s - MMEM))*FF + col);
  float4 v = *(const float4*)src;
  short4 o; o.x = f2bf(v.x); o.y = f2bf(v.y); o.z = f2bf(v.z); o.w = f2bf(v.w);
  ((short4*)out)[i] = o;
}

// batched: out_z[c][r] = in_z[r][c], 1024x1024, f32 -> bf16
__global__ void transpose_cast5(const float* __restrict__ i0, const float* __restrict__ i1,
                                const float* __restrict__ i2, const float* __restrict__ i3,
                                const float* __restrict__ i4,
                                short* __restrict__ o0, short* __restrict__ o1,
                                short* __restrict__ o2, short* __restrict__ o3,
                                short* __restrict__ o4){
  const float* in; short* out;
  switch (blockIdx.z){
    case 0: in = i0; out = o0; break;
    case 1: in = i1; out = o1; break;
    case 2: in = i2; out = o2; break;
    case 3: in = i3; out = o3; break;
    default: in = i4; out = o4; break;
  }
  __shared__ float tile[32][33];
  int bx = blockIdx.x * 32, by = blockIdx.y * 32;
  int tx = threadIdx.x, ty = threadIdx.y;
  for (int j = ty; j < 32; j += 8)
    tile[j][tx] = in[(size_t)(by + j)*1024 + bx + tx];
  __syncthreads();
  for (int j = ty; j < 32; j += 8)
    out[(size_t)(bx + j)*1024 + by + tx] = f2bf(tile[tx][j]);
}

// ki[b, 0:M] = episode_idx; ki[b, M+t] = episode_idx[b,M-1] + cumsum(dones)[t]
// Also: per 16-row query group g, the valid-key interval [s_lo, s_hi):
// ki is globally nondecreasing, so the episode-match set is contiguous.
// Tiles outside it are fully masked -> exp underflows to exactly 0 -> skippable.
__global__ void scan_kernel(const int* __restrict__ episode_idx, const int* __restrict__ dones,
                            int* __restrict__ ki, int2* __restrict__ ranges){
  __shared__ int buf[TT];
  __shared__ int kis[SS];
  int b = blockIdx.x, t = threadIdx.x;
  buf[t] = dones[b*TT + t];
  kis[t] = episode_idx[b*MMEM + t];
  __syncthreads();
  for (int off = 1; off < TT; off <<= 1){
    int v = (t >= off) ? buf[t - off] : 0;
    __syncthreads();
    buf[t] += v;
    __syncthreads();
  }
  int base = kis[MMEM - 1];
  int q = base + buf[t];
  kis[MMEM + t] = q;
  ki[b*SS + t] = kis[t];
  ki[b*SS + MMEM + t] = q;
  __syncthreads();
  if (t < 64){
    const int qlo = kis[MMEM + t*16];
    const int qhi = kis[MMEM + t*16 + 15];
    int lo = 0, hi = SS;
    while (lo < hi){ int mid = (lo + hi) >> 1; if (kis[mid] < qlo) lo = mid + 1; else hi = mid; }
    const int s_lo = lo;
    lo = 0; hi = SS;
    const int tgt = qhi + 1;
    while (lo < hi){ int mid = (lo + hi) >> 1; if (kis[mid] < tgt) lo = mid + 1; else hi = mid; }
    int s_hi = lo;                              // exclusive
    const int cap = t*16 + 15 + MMEM + 1;       // causal cap (<= SS always)
    if (s_hi > cap) s_hi = cap;
    ranges[(b << 6) + t] = make_int2(s_lo, s_hi);
  }
}

// uk[b,n,s] = sum_h u[n,h]*k[b,s,n,h];  vr[n,j] = sum_h v[n,h]*r[j,n,h]
__global__ void bias_tables(const short* __restrict__ kbf, const short* __restrict__ rbf,
                            const float* __restrict__ u, const float* __restrict__ v,
                            float* __restrict__ uk, float* __restrict__ vr){
  int i = blockIdx.x * blockDim.x + threadIdx.x;
  if (i < NB * NHD * SS){
    int s = i & 2047, n = (i >> 11) & 15, b = i >> 15;
    const short* kp = kbf + (size_t)(b * SS + s) * 1024 + n * 64;
    const float* up = u + n * 64;
    float acc = 0.f;
    #pragma unroll 8
    for (int h = 0; h < 64; h++) acc += bf2f(kp[h]) * up[h];
    uk[(size_t)(b * NHD + n) * SS + s] = acc;
  } else {
    int j = i - NB * NHD * SS;
    if (j >= NHD * SS) return;
    int jj = j & 2047, n = j >> 11;
    const short* rp = rbf + (size_t)jj * 1024 + n * 64;
    const float* vp = v + n * 64;
    float acc = 0.f;
    #pragma unroll 8
    for (int h = 0; h < 64; h++) acc += bf2f(rp[h]) * vp[h];
    vr[(size_t)n * SS + jj] = acc;
  }
}

// ------------- 128x64 GEMM core, BK=64, XOR-swizzled staging ----------------
// C[i,j] = sum_k A[i,k] * BT[j,k]; row-major bf16, ld = 1024, K = 1024.
// Tile halved vs R8 (128x128 -> 128x64) to DOUBLE co-resident blocks:
// R8 measured MfmaUtil 17% with only 3 working blocks/CU — the per-iter
// vmcnt(0) barrier drain had nothing to overlap with. Now: LDS 24 KB ->
// 6 blocks/CU, VGPR ~60 -> 8 waves/SIMD, grid 1536 working blocks = 6/CU.
// Wave quadrants 64x32 (2x2), acc[4][2]; 16 MFMA/wave/iter, 16 iters.
// LDS layout: 16B unit (row, chunk) at row*128B + ((chunk^(row&7))*16B):
// staging coalesced (1024B wave-write = 8 full rows), fragment ds_read_b128
// spread over all 32 banks (R8: conflicts 3.1M -> 0 with this swizzle).
__device__ __forceinline__ void gemm_core_128x64(const short* __restrict__ A,
                                                 const short* __restrict__ BT,
                                                 int row0, int col0,
                                                 short* As, short* Bs,
                                                 f32x4 (&acc)[4][2]){
  const int lane = threadIdx.x & 63, wv = threadIdx.x >> 6;
  const int lcol = lane & 15, quad = lane >> 4;
  const int wr = (wv >> 1) * 64, wc = (wv & 1) * 32;
  const int sw = lcol & 7;                 // row&7 for all fragment rows
  const int ch0 = (quad ^ sw) * 8;         // k-half 0 chunk offset (shorts)
  const int ch1 = ((4 + quad) ^ sw) * 8;   // k-half 1

  #pragma unroll
  for (int r = 0; r < 4; r++)
    #pragma unroll
    for (int c = 0; c < 2; c++) acc[r][c] = (f32x4){0.f, 0.f, 0.f, 0.f};

  const short* gA[4]; short* dA[4];
  #pragma unroll
  for (int c = 0; c < 4; c++){
    const int u = (wv * 4 + c) * 64 + lane;   // A: 128 rows = 1024 units
    const int row = u >> 3;
    const int chk = (u & 7) ^ (row & 7);
    gA[c] = A + (size_t)(row0 + row) * 1024 + chk * 8;
    dA[c] = As + (wv * 4 + c) * 512;
  }
  const short* gB[2]; short* dB[2];
  #pragma unroll
  for (int c = 0; c < 2; c++){
    const int u = (wv * 2 + c) * 64 + lane;   // B: 64 rows = 512 units
    const int row = u >> 3;
    const int chk = (u & 7) ^ (row & 7);
    gB[c] = BT + (size_t)(col0 + row) * 1024 + chk * 8;
    dB[c] = Bs + (wv * 2 + c) * 512;
  }

  #pragma unroll 1
  for (int k0 = 0; k0 < 1024; k0 += 64){
    __syncthreads();
    #pragma unroll
    for (int c = 0; c < 4; c++) stage16(gA[c] + k0, dA[c]);
    #pragma unroll
    for (int c = 0; c < 2; c++) stage16(gB[c] + k0, dB[c]);
    __syncthreads();
    bf16x8 af[4][2];
    #pragma unroll
    for (int r = 0; r < 4; r++){
      const int rb = (wr + r * 16 + lcol) * 64;
      af[r][0] = *(const bf16x8*)&As[rb + ch0];
      af[r][1] = *(const bf16x8*)&As[rb + ch1];
    }
    #pragma unroll
    for (int c = 0; c < 2; c++){
      const int rb = (wc + c * 16 + lcol) * 64;
      bf16x8 b0 = *(const bf16x8*)&Bs[rb + ch0];
      bf16x8 b1 = *(const bf16x8*)&Bs[rb + ch1];
      #pragma unroll
      for (int r = 0; r < 4; r++){
        acc[r][c] = __builtin_amdgcn_mfma_f32_16x16x32_bf16(af[r][0], b0, acc[r][c], 0, 0, 0);
        acc[r][c] = __builtin_amdgcn_mfma_f32_16x16x32_bf16(af[r][1], b1, acc[r][c], 0, 0, 0);
      }
    }
  }
}

// Fused projection GEMM: blockIdx.z selects job:
//   z=0: kbf = kv @ WkT                      (4096 rows)
//   z=1: vT  = kv @ WvT, per-head transposed (4096 rows)
//   z=2: qb  = x @ WqT   (x read in-place from kv_bf rows [M..S); bx<16)
//   z=3: rbf = rel @ WrT (2048 rows; bx<16)
__global__ __launch_bounds__(256) void proj_gemm(
    const short* __restrict__ kv, const short* __restrict__ relb,
    const short* __restrict__ WkT, const short* __restrict__ WvT,
    const short* __restrict__ WqT, const short* __restrict__ WrT,
    short* __restrict__ kbf, short* __restrict__ vT,
    short* __restrict__ qb, short* __restrict__ rbf){
  const int z = blockIdx.z;
  const int bx = blockIdx.x;
  const short* A; const short* BT;
  int row0 = bx * 128, qbb = 0;
  if (z == 0){ A = kv; BT = WkT; }
  else if (z == 1){ A = kv; BT = WvT; }
  else if (z == 2){
    if (bx >= 16) return;
    qbb = bx >> 3;                       // batch
    A = kv + (size_t)(qbb * SS + MMEM) * 1024;   // x rows live inside kv
    row0 = (bx & 7) * 128;
    BT = WqT;
  }
  else { if (bx >= 16) return; A = relb; BT = WrT; }
  const int col0 = blockIdx.y * 64;

  __shared__ __align__(16) short As[128*64];
  __shared__ __align__(16) short Bs[64*64];
  f32x4 acc[4][2];
  gemm_core_128x64(A, BT, row0, col0, As, Bs, acc);

  const int lane = threadIdx.x & 63, wv = threadIdx.x >> 6;
  const int lcol = lane & 15, quad = lane >> 4;
  const int wr = (wv >> 1) * 64, wc = (wv & 1) * 32;
  #pragma unroll
  for (int c = 0; c < 2; c++){
    const int cc = col0 + wc + c*16 + lcol;
    #pragma unroll
    for (int r = 0; r < 4; r++){
      #pragma unroll
      for (int ri = 0; ri < 4; ri++){
        const int rr = row0 + wr + r*16 + quad*4 + ri;
        float val = acc[r][c][ri];
        if (z == 0){
          kbf[(size_t)rr * 1024 + cc] = f2bf(val);
        } else if (z == 1){
          int b = rr >> 11, s = rr & 2047;
          vT[(size_t)(((b << 4) + (cc >> 6)) * 64 + (cc & 63)) * 2048 + s] = f2bf(val);
        } else if (z == 2){
          qb[((size_t)(qbb * TT) + rr) * 1024 + cc] = f2bf(val);
        } else {
          rbf[(size_t)rr * 1024 + cc] = f2bf(val);
        }
      }
    }
  }
}

// Output projection: out = attn @ WoT + b_out (f32 out, 2048 rows)
__global__ __launch_bounds__(256) void out_gemm(const short* __restrict__ A,
                                                const short* __restrict__ BT,
                                                const float* __restrict__ bias,
                                                float* __restrict__ C){
  const int row0 = blockIdx.x * 128, col0 = blockIdx.y * 64;
  __shared__ __align__(16) short As[128*64];
  __shared__ __align__(16) short Bs[64*64];
  f32x4 acc[4][2];
  gemm_core_128x64(A, BT, row0, col0, As, Bs, acc);

  const int lane = threadIdx.x & 63, wv = threadIdx.x >> 6;
  const int lcol = lane & 15, quad = lane >> 4;
  const int wr = (wv >> 1) * 64, wc = (wv & 1) * 32;
  #pragma unroll
  for (int c = 0; c < 2; c++){
    const int cc = col0 + wc + c*16 + lcol;
    const float bb = bias[cc];
    #pragma unroll
    for (int r = 0; r < 4; r++)
      #pragma unroll
      for (int ri = 0; ri < 4; ri++){
        const int rr = row0 + wr + r*16 + quad*4 + ri;
        C[(size_t)rr * 1024 + cc] = acc[r][c][ri] + bb;
      }
  }
}

// ---------------- flash attention: one wave per 16-row q-group --------------
// grid 2048 x 64 threads. XCD swizzle (L2 working set per XCD ~3.6 MB).
// Each wave sweeps ONLY the valid k-tile interval from ranges[] (episode-mask
// interval + causal cap). Skipped tiles are fully masked -> exact.
__global__ __launch_bounds__(64) void attn_kernel(const short* __restrict__ qb,
                            const short* __restrict__ rbf,
                            const short* __restrict__ kk, const short* __restrict__ vT,
                            const int* __restrict__ ki,
                            const float* __restrict__ uk, const float* __restrict__ vr,
                            const int2* __restrict__ ranges,
                            short* __restrict__ attn_out){
  const int blk = blockIdx.x;
  const int xcd = blk & 7;
  const int idx = blk >> 3;                 // [0,256)
  const int bn  = (xcd << 2) | (idx >> 6);  // 4 (b,n) groups per XCD
  const int t16 = (idx & 63) * 16;
  const int n = bn & 15;
  const int b = bn >> 4;
  const int lane = threadIdx.x & 63;
  const int quad = lane >> 4, lcol = lane & 15;

  __shared__ __align__(16) short pb[16 * 72];

  const short* qp = qb + (size_t)(b * TT + t16 + lcol) * 1024 + n * 64 + quad * 8;
  bf16x8 aq0 = *(const bf16x8*)(qp);
  bf16x8 aq1 = *(const bf16x8*)(qp + 32);

  int trow[4], qi_r[4], sl[4];
  bool hi[4];
  #pragma unroll
  for (int r = 0; r < 4; r++){
    trow[r] = t16 + quad * 4 + r;
    qi_r[r] = ki[b * SS + MMEM + trow[r]];
    const int rt = quad * 4 + r;
    const int off = lcol + 15 - rt;
    sl[r] = quad * 16 + (off & 15);
    hi[r] = off >= 16;
  }

  float m_run[4], l_run[4];
  f32x4 o[4];
  #pragma unroll
  for (int r = 0; r < 4; r++){ m_run[r] = -1e30f; l_run[r] = 0.f; }
  #pragma unroll
  for (int c = 0; c < 4; c++) o[c] = (f32x4){0.f, 0.f, 0.f, 0.f};

  const float scale = 0.125f;
  const size_t vt_base = (size_t)((b * NHD + n) * HD);
  const short* rb_head = rbf + n * 64;
  const float* uk_row = uk + (size_t)(b * NHD + n) * SS;
  const float* vr_row = vr + (size_t)n * SS;

  const int2 rg = ranges[(b << 6) + (t16 >> 4)];
  const int kt0 = rg.x >> 6, kt1 = (rg.y - 1) >> 6;

  for (int kt = kt0; kt <= kt1; kt++){
    const int s0 = kt * 64;
    // ---- S = Q . K^T  (+ uk column bias) ----
    f32x4 sacc[4];
    float ukc[4];
    #pragma unroll
    for (int c = 0; c < 4; c++){
      const short* kp = kk + (size_t)(b * SS + s0 + 16 * c + lcol) * 1024 + n * 64 + quad * 8;
      bf16x8 b0 = *(const bf16x8*)(kp);
      bf16x8 b1 = *(const bf16x8*)(kp + 32);
      f32x4 z = (f32x4){0.f, 0.f, 0.f, 0.f};
      z = __builtin_amdgcn_mfma_f32_16x16x32_bf16(aq0, b0, z, 0, 0, 0);
      z = __builtin_amdgcn_mfma_f32_16x16x32_bf16(aq1, b1, z, 0, 0, 0);
      sacc[c] = z;
      ukc[c] = uk_row[s0 + 16 * c + lcol];
    }
    int ki_c[4];
    #pragma unroll
    for (int c = 0; c < 4; c++) ki_c[c] = ki[b * SS + s0 + 16 * c + lcol];

    // ---- D = Q . R^T (+ vr column bias) over the 80-row window ----
    const int j0 = s0 - t16 + 1008;   // >= 0 always
    f32x4 Dw[5];
    #pragma unroll
    for (int c5 = 0; c5 < 5; c5++){
      int jr = j0 + 16 * c5 + lcol;
      jr = (jr > SS - 1) ? (SS - 1) : jr;   // clamped rows are causally masked
      const short* rp = rb_head + (size_t)jr * 1024 + quad * 8;
      bf16x8 r0 = *(const bf16x8*)(rp);
      bf16x8 r1 = *(const bf16x8*)(rp + 32);
      f32x4 z = (f32x4){0.f, 0.f, 0.f, 0.f};
      z = __builtin_amdgcn_mfma_f32_16x16x32_bf16(aq0, r0, z, 0, 0, 0);
      z = __builtin_amdgcn_mfma_f32_16x16x32_bf16(aq1, r1, z, 0, 0, 0);
      const float vrj = vr_row[jr];
      #pragma unroll
      for (int r = 0; r < 4; r++) z[r] += vrj;
      Dw[c5] = z;
    }

    // ---- bias shift (Toeplitz) + mask + logits ----
    float p[4][4];
    float rowmax[4];
    #pragma unroll
    for (int r = 0; r < 4; r++) rowmax[r] = -1e30f;
    #pragma unroll
    for (int c = 0; c < 4; c++){
      const int s = s0 + 16 * c + lcol;
      #pragma unroll
      for (int r = 0; r < 4; r++){
        const float v0 = __shfl(Dw[c][r], sl[r], 64);
        const float v1 = __shfl(Dw[c + 1][r], sl[r], 64);
        const float bd = hi[r] ? v1 : v0;
        float lg = (sacc[c][r] + ukc[c] + bd) * scale;
        const bool valid = (s <= trow[r] + MMEM) && (ki_c[c] == qi_r[r]);
        lg = valid ? lg : -1e30f;
        p[c][r] = lg;
        rowmax[r] = fmaxf(rowmax[r], lg);
      }
    }
    // ---- online softmax ----
    #pragma unroll
    for (int r = 0; r < 4; r++){
      float vmx = rowmax[r];
      #pragma unroll
      for (int off = 1; off < 16; off <<= 1) vmx = fmaxf(vmx, __shfl_xor(vmx, off, 64));
      float mnew = fmaxf(m_run[r], vmx);
      float alpha = __expf(m_run[r] - mnew);
      m_run[r] = mnew;
      l_run[r] *= alpha;
      #pragma unroll
      for (int c = 0; c < 4; c++) o[c][r] *= alpha;
    }
    float psum[4] = {0.f, 0.f, 0.f, 0.f};
    #pragma unroll
    for (int c = 0; c < 4; c++)
      #pragma unroll
      for (int r = 0; r < 4; r++){
        float pv = __expf(p[c][r] - m_run[r]);
        p[c][r] = pv;
        psum[r] += pv;
      }
    #pragma unroll
    for (int r = 0; r < 4; r++){
      float vs = psum[r];
      #pragma unroll
      for (int off = 1; off < 16; off <<= 1) vs += __shfl_xor(vs, off, 64);
      l_run[r] += vs;
    }
    // ---- P: C-layout -> A-layout via LDS (wave-synchronous) ----
    #pragma unroll
    for (int c = 0; c < 4; c++)
      #pragma unroll
      for (int r = 0; r < 4; r++)
        pb[(quad * 4 + r) * 72 + 16 * c + lcol] = f2bf(p[c][r]);
    bf16x8 pa0 = *(const bf16x8*)(&pb[lcol * 72 + quad * 8]);
    bf16x8 pa1 = *(const bf16x8*)(&pb[lcol * 72 + 32 + quad * 8]);
    // ---- O += P . V ----
    #pragma unroll
    for (int c = 0; c < 4; c++){
      const short* vtp = vT + (vt_base + c * 16 + lcol) * (size_t)SS + s0 + quad * 8;
      bf16x8 bv0 = *(const bf16x8*)(vtp);
      bf16x8 bv1 = *(const bf16x8*)(vtp + 32);
      o[c] = __builtin_amdgcn_mfma_f32_16x16x32_bf16(pa0, bv0, o[c], 0, 0, 0);
      o[c] = __builtin_amdgcn_mfma_f32_16x16x32_bf16(pa1, bv1, o[c], 0, 0, 0);
    }
  }

  // ---- epilogue: normalize, store bf16 attn [B*T, N*H] ----
  #pragma unroll
  for (int r = 0; r < 4; r++){
    const float inv = 1.f / l_run[r];
    const int t = trow[r];
    #pragma unroll
    for (int c = 0; c < 4; c++)
      attn_out[(size_t)(b * TT + t) * 1024 + n * 64 + c * 16 + lcol] = f2bf(o[c][r] * inv);
  }
}

// ---------------- launcher ----------------
extern "C" void kernel_launch(void* const* d_in, const int* in_sizes, int n_in,
                              void* d_out, int out_size, void* d_ws, size_t ws_size,
                              hipStream_t stream){
  const float* x      = (const float*)d_in[0];
  const float* rel    = (const float*)d_in[1];
  const float* memory = (const float*)d_in[2];
  const int*   episode_idx = (const int*)d_in[3];
  const int*   dones  = (const int*)d_in[4];
  const float* Wq  = (const float*)d_in[5];
  const float* Wk  = (const float*)d_in[6];
  const float* Wv  = (const float*)d_in[7];
  const float* Wr  = (const float*)d_in[8];
  const float* u   = (const float*)d_in[9];
  const float* v   = (const float*)d_in[10];
  const float* Wout  = (const float*)d_in[11];
  const float* b_out = (const float*)d_in[12];
  float* out = (float*)d_out;

  char* ws = (char*)d_ws;
  size_t off = 0;
  auto alloc = [&](size_t bytes) -> char* {
    char* p = ws + off;
    off += (bytes + 255) & ~(size_t)255;
    return p;
  };
  short* kv_bf  = (short*)alloc((size_t)NB * SS * FF * 2);
  short* rel_bf = (short*)alloc((size_t)SS * FF * 2);
  short* WqT    = (short*)alloc((size_t)FF * 1024 * 2);
  short* WkT    = (short*)alloc((size_t)FF * 1024 * 2);
  short* WvT    = (short*)alloc((size_t)FF * 1024 * 2);
  short* WrT    = (short*)alloc((size_t)FF * 1024 * 2);
  short* WoT    = (short*)alloc((size_t)FF * 1024 * 2);
  short* qbuf   = (short*)alloc((size_t)NB * TT * 1024 * 2);
  short* kbf    = (short*)alloc((size_t)NB * SS * 1024 * 2);
  short* vTb    = (short*)alloc((size_t)NB * SS * 1024 * 2);
  short* rbf    = (short*)alloc((size_t)SS * 1024 * 2);
  int*   ki     = (int*)  alloc((size_t)NB * SS * 4);
  int2*  ranges = (int2*) alloc((size_t)NB * 64 * 8);
  float* ukT    = (float*)alloc((size_t)NB * NHD * SS * 4);
  float* vrT    = (float*)alloc((size_t)NHD * SS * 4);
  short* attn   = (short*)alloc((size_t)NB * TT * 1024 * 2);
  (void)ws_size; (void)in_sizes; (void)n_in; (void)out_size;

  // pack
  cast_kernel<<<(SS*FF/4 + 255)/256, 256, 0, stream>>>(rel, rel_bf, SS*FF/4);
  build_kv<<<(NB*SS*FF/4)/256, 256, 0, stream>>>(memory, x, kv_bf);
  dim3 tb(32, 8), tg5(32, 32, 5);
  transpose_cast5<<<tg5, tb, 0, stream>>>(Wq, Wk, Wv, Wr, Wout, WqT, WkT, WvT, WrT, WoT);
  scan_kernel<<<NB, TT, 0, stream>>>(episode_idx, dones, ki, ranges);

  // fused projections: z=0 K, z=1 V(transposed), z=2 Q (from kv rows), z=3 R
  // 128x64 tiles -> 1536 working blocks (6/CU) for barrier-drain overlap
  proj_gemm<<<dim3(32, 16, 4), 256, 0, stream>>>(kv_bf, rel_bf,
                                                 WkT, WvT, WqT, WrT,
                                                 kbf, vTb, qbuf, rbf);

  // u·k / v·r column-bias tables
  bias_tables<<<(NB*NHD*SS + NHD*SS + 255)/256, 256, 0, stream>>>(kbf, rbf, u, v, ukT, vrT);

  // attention: one wave per 16-row q-group, valid-interval sweep only
  attn_kernel<<<2048, 64, 0, stream>>>(qbuf, rbf, kbf, vTb, ki, ukT, vrT, ranges, attn);

  // output projection (256 blocks -> full GPU; was 128)
  out_gemm<<<dim3(16, 16), 256, 0, stream>>>(attn, WoT, b_out, out);
}